// Round 7
// baseline (217.355 us; speedup 1.0000x reference)
//
#include <hip/hip_runtime.h>
#include <hip/hip_bf16.h>
#include <cstdint>

#define B_  4
#define N_  4096
#define C_  256
#define CD_ 64

typedef unsigned short ushort_t;
typedef unsigned char uchar_t;
typedef __bf16 bf16x8 __attribute__((ext_vector_type(8)));
typedef float f32x4 __attribute__((ext_vector_type(4)));
typedef unsigned int u32x4 __attribute__((ext_vector_type(4)));

typedef const __attribute__((address_space(1))) void* gas_t;
typedef __attribute__((address_space(3))) void* las_t;

// (1/sqrt(256)) * log2(e): folded into K projection so S' = S_true * log2(e)
static constexpr float SCALE_LOG2E = 0.09016844005556021f;
// V' scale 2^13 (undone in gemm epilogue); PT exponent shift -3 cancels via l.
static constexpr float VSCALE = 8192.0f;
static constexpr float VSCALE_INV = 1.0f / 8192.0f;

__device__ __forceinline__ ushort_t f2bf(float x) {
    union { float f; unsigned u; } v; v.f = x;
    unsigned u = v.u;
    unsigned r = (u + 0x7fffu + ((u >> 16) & 1u)) >> 16;  // round-nearest-even
    return (ushort_t)r;
}

__device__ __forceinline__ bf16x8 ld_bf8(const ushort_t* p) {
    return *reinterpret_cast<const bf16x8*>(p);
}

// ---------------------------------------------------------------------------
// R19: proj_q + proj_kv FUSED into one dispatch (bodies verbatim from the
// proven R8 kernels).  The two projections are independent but were
// serialized on the stream, each 512 blocks (2/CU) paying its own tail +
// launch gap.  Fused: grid (32, 8, 4) = 1024 blocks; blockIdx.y>>2 = role
// (0 = Q from x_s2, 1 = K+V from x_dem); LDS is a 36.9 KB union -> still
// 4 blocks/CU.  Role is block-uniform so divergent __syncthreads is safe.
// ---------------------------------------------------------------------------
__global__ __launch_bounds__(256, 4)
void proj_fused(const float* __restrict__ Xq, const float* __restrict__ Wq,
                const float* __restrict__ bq,
                const float* __restrict__ Xkv, const float* __restrict__ Wk,
                const float* __restrict__ bk, const float* __restrict__ Wv,
                const float* __restrict__ bv,
                ushort_t* __restrict__ Qt, ushort_t* __restrict__ Kt,
                ushort_t* __restrict__ Vm) {
    __shared__ ushort_t shm[(128 + 64 + 64) * 72];   // union of both roles
    const int tid = threadIdx.x;
    const int lane = tid & 63, g = lane >> 4, c16 = lane & 15;
    const int w = tid >> 6;
    const int b = blockIdx.z, nb = blockIdx.x * 128;
    const int role = blockIdx.y >> 2;
    const int ob = (blockIdx.y & 3) * 64;

    if (role == 0) {
        // ---------------- Q-role: proj_q body (Cin = 256) ----------------
        ushort_t (*sX)[72] = (ushort_t(*)[72])shm;
        ushort_t (*sW)[72] = (ushort_t(*)[72])(shm + 128 * 72);
        const int wi = w >> 1, wj = w & 1;
        f32x4 acc[4][2];
#pragma unroll
        for (int nt = 0; nt < 4; ++nt)
#pragma unroll
            for (int ot = 0; ot < 2; ++ot) acc[nt][ot] = (f32x4){0.f, 0.f, 0.f, 0.f};

        const int cr = tid >> 5;
        const int n0 = (tid & 31) * 4;

        for (int k0 = 0; k0 < C_; k0 += 64) {
#pragma unroll
            for (int p = 0; p < 8; ++p) {
                const int c = p * 8 + cr;
                float4 xv = *(const float4*)(Xq + ((size_t)b * C_ + k0 + c) * N_ + nb + n0);
                sX[n0 + 0][c] = f2bf(xv.x);
                sX[n0 + 1][c] = f2bf(xv.y);
                sX[n0 + 2][c] = f2bf(xv.z);
                sX[n0 + 3][c] = f2bf(xv.w);
            }
            {
                const int o = tid >> 2, cq = (tid & 3) * 16;
                const float* wsrc = Wq + (size_t)(ob + o) * C_ + k0 + cq;
                alignas(16) ushort_t tmp[16];
#pragma unroll
                for (int q = 0; q < 16; ++q) tmp[q] = f2bf(wsrc[q]);
                *(uint4*)&sW[o][cq]     = *(uint4*)&tmp[0];
                *(uint4*)&sW[o][cq + 8] = *(uint4*)&tmp[8];
            }
            __syncthreads();
#pragma unroll
            for (int ks = 0; ks < 2; ++ks) {
                bf16x8 af[4], bfr[2];
#pragma unroll
                for (int nt = 0; nt < 4; ++nt)
                    af[nt] = *(const bf16x8*)&sX[wi * 64 + nt * 16 + c16][ks * 32 + g * 8];
#pragma unroll
                for (int ot = 0; ot < 2; ++ot)
                    bfr[ot] = *(const bf16x8*)&sW[wj * 32 + ot * 16 + c16][ks * 32 + g * 8];
#pragma unroll
                for (int nt = 0; nt < 4; ++nt)
#pragma unroll
                    for (int ot = 0; ot < 2; ++ot)
                        acc[nt][ot] = __builtin_amdgcn_mfma_f32_16x16x32_bf16(af[nt], bfr[ot], acc[nt][ot], 0, 0, 0);
            }
            __syncthreads();
        }
#pragma unroll
        for (int ot = 0; ot < 2; ++ot) {
            const int o = ob + wj * 32 + ot * 16 + c16;
            const float bia = bq[o];
#pragma unroll
            for (int nt = 0; nt < 4; ++nt) {
#pragma unroll
                for (int r = 0; r < 4; ++r) {
                    const int n = nb + wi * 64 + nt * 16 + g * 4 + r;
                    Qt[((size_t)b * N_ + n) * C_ + o] = f2bf(acc[nt][ot][r] + bia);
                }
            }
        }
    } else {
        // ---------------- KV-role: proj_kv body (Cin = 64) ----------------
        ushort_t (*sX)[72]  = (ushort_t(*)[72])shm;
        ushort_t (*sWk)[72] = (ushort_t(*)[72])(shm + 128 * 72);
        ushort_t (*sWv)[72] = (ushort_t(*)[72])(shm + 192 * 72);
        {
            const int cr = tid >> 5, n0 = (tid & 31) * 4;
#pragma unroll
            for (int p = 0; p < 8; ++p) {
                const int c = p * 8 + cr;
                float4 xv = *(const float4*)(Xkv + ((size_t)b * CD_ + c) * N_ + nb + n0);
                sX[n0 + 0][c] = f2bf(xv.x);
                sX[n0 + 1][c] = f2bf(xv.y);
                sX[n0 + 2][c] = f2bf(xv.z);
                sX[n0 + 3][c] = f2bf(xv.w);
            }
            const int o = tid >> 2, cq = (tid & 3) * 16;
            alignas(16) ushort_t tk[16], tv[16];
            const float* ksrc = Wk + (size_t)(ob + o) * CD_ + cq;
            const float* vsrc = Wv + (size_t)(ob + o) * CD_ + cq;
#pragma unroll
            for (int q = 0; q < 16; ++q) { tk[q] = f2bf(ksrc[q]); tv[q] = f2bf(vsrc[q]); }
            *(uint4*)&sWk[o][cq]     = *(uint4*)&tk[0];
            *(uint4*)&sWk[o][cq + 8] = *(uint4*)&tk[8];
            *(uint4*)&sWv[o][cq]     = *(uint4*)&tv[0];
            *(uint4*)&sWv[o][cq + 8] = *(uint4*)&tv[8];
        }
        __syncthreads();
        // ---- K-part ----
        {
            const int wi = w >> 1, wj = w & 1;
            f32x4 acc[4][2];
#pragma unroll
            for (int nt = 0; nt < 4; ++nt)
#pragma unroll
                for (int ot = 0; ot < 2; ++ot) acc[nt][ot] = (f32x4){0.f, 0.f, 0.f, 0.f};
#pragma unroll
            for (int ks = 0; ks < 2; ++ks) {
                bf16x8 af[4], bfr[2];
#pragma unroll
                for (int nt = 0; nt < 4; ++nt)
                    af[nt] = *(const bf16x8*)&sX[wi * 64 + nt * 16 + c16][ks * 32 + g * 8];
#pragma unroll
                for (int ot = 0; ot < 2; ++ot)
                    bfr[ot] = *(const bf16x8*)&sWk[wj * 32 + ot * 16 + c16][ks * 32 + g * 8];
#pragma unroll
                for (int nt = 0; nt < 4; ++nt)
#pragma unroll
                    for (int ot = 0; ot < 2; ++ot)
                        acc[nt][ot] = __builtin_amdgcn_mfma_f32_16x16x32_bf16(af[nt], bfr[ot], acc[nt][ot], 0, 0, 0);
            }
#pragma unroll
            for (int ot = 0; ot < 2; ++ot) {
                const int o = ob + wj * 32 + ot * 16 + c16;
                const float bia = bk[o];
#pragma unroll
                for (int nt = 0; nt < 4; ++nt)
#pragma unroll
                    for (int r = 0; r < 4; ++r) {
                        const int n = nb + wi * 64 + nt * 16 + g * 4 + r;
                        Kt[((size_t)b * N_ + n) * C_ + o] = f2bf((acc[nt][ot][r] + bia) * SCALE_LOG2E);
                    }
            }
        }
        // ---- V-part ----
        {
            const int ow = w & 1, nw = w >> 1;
            f32x4 acc[2][4];
#pragma unroll
            for (int mt = 0; mt < 2; ++mt)
#pragma unroll
                for (int nt = 0; nt < 4; ++nt) acc[mt][nt] = (f32x4){0.f, 0.f, 0.f, 0.f};
#pragma unroll
            for (int ks = 0; ks < 2; ++ks) {
                bf16x8 af[2], bfr[4];
#pragma unroll
                for (int mt = 0; mt < 2; ++mt)
                    af[mt] = *(const bf16x8*)&sWv[ow * 32 + mt * 16 + c16][ks * 32 + g * 8];
#pragma unroll
                for (int nt = 0; nt < 4; ++nt)
                    bfr[nt] = *(const bf16x8*)&sX[nw * 64 + nt * 16 + c16][ks * 32 + g * 8];
#pragma unroll
                for (int mt = 0; mt < 2; ++mt)
#pragma unroll
                    for (int nt = 0; nt < 4; ++nt)
                        acc[mt][nt] = __builtin_amdgcn_mfma_f32_16x16x32_bf16(af[mt], bfr[nt], acc[mt][nt], 0, 0, 0);
            }
#pragma unroll
            for (int mt = 0; mt < 2; ++mt) {
                const float4 bi4 = *(const float4*)(bv + ob + ow * 32 + mt * 16 + g * 4);
                const float bia[4] = {bi4.x, bi4.y, bi4.z, bi4.w};
#pragma unroll
                for (int nt = 0; nt < 4; ++nt) {
                    const int n = nb + nw * 64 + nt * 16 + c16;
#pragma unroll
                    for (int r = 0; r < 4; ++r) {
                        const int o = ob + ow * 32 + mt * 16 + g * 4 + r;
                        Vm[((size_t)b * C_ + o) * N_ + n] = f2bf(acc[mt][nt][r] + bia[r]);
                    }
                }
            }
        }
    }
}

// ---------------------------------------------------------------------------
// Pass A v8 (R18, kept): R4's proven BK=32 dbuf loop + XCD supertile swizzle
// (R6-verified: FETCH 36.9 -> 24.6 MB; dur at 2-phase structural floor).
// PT streamout NONTEMPORAL (R4-verified: WRITE at 67.6 MB ideal).
// ---------------------------------------------------------------------------
__global__ __launch_bounds__(256, 4)
void stats_kernel(const ushort_t* __restrict__ Kt, const ushort_t* __restrict__ Qt,
                  float* __restrict__ l, uchar_t* __restrict__ PT8,
                  float* __restrict__ lpart) {
    __shared__ ushort_t smem[16384];   // 32 KB: buf t at (t&1)*16K: A 8K + B 8K
    uchar_t* smem8 = (uchar_t*)smem;
    uchar_t* sp8 = smem8;                      // epilogue: [128][144] fp8 tile
    float* lsum = (float*)(smem8 + 18432);     // [2][128] row partials
    const int tid = threadIdx.x;
    const int lane = tid & 63, g = lane >> 4, c16 = lane & 15;
    const int w = tid >> 6, wi = w >> 1, wj = w & 1;
    // ---- XCD supertile decode (bijective): hv -> (b, by, bx) ----
    const int hv = blockIdx.x;           // 0..4095
    const int xcd = hv & 7;              // round-robin XCD slot
    const int slot = hv >> 3;            // 0..511
    const int st = xcd + 8 * (slot >> 6);    // supertile 0..63 (8 per XCD)
    const int within = slot & 63;            // 0..63 inside 8x8 supertile
    const int b = st >> 4;                   // batch
    const int stl = st & 15;                 // supertile within batch (4x4)
    const int by = (stl >> 2) * 8 + (within >> 3);   // ib tile 0..31
    const int bx = (stl & 3) * 8 + (within & 7);     // jb tile 0..31
    const int ib = by * 128, jb = bx * 128;
    f32x4 acc[4][4];
#pragma unroll
    for (int mt = 0; mt < 4; ++mt)
#pragma unroll
        for (int nt = 0; nt < 4; ++nt) acc[mt][nt] = (f32x4){0.f, 0.f, 0.f, 0.f};

    const int srow = tid >> 2;   // 0..63 (row within 64-row half)
    const int sc = tid & 3;      // 16B chunk slot within 64B row

    auto stage = [&](int kc, int dbase) {      // kc: 32-wide K chunk index
#pragma unroll
        for (int q = 0; q < 2; ++q) {
            const int row = q * 64 + srow;
            const int gc = sc ^ ((row >> 1) & 3);
            const ushort_t* srcA = Kt + ((size_t)(b * N_ + ib + row)) * C_ + kc * 32 + gc * 8;
            const ushort_t* srcB = Qt + ((size_t)(b * N_ + jb + row)) * C_ + kc * 32 + gc * 8;
            __builtin_amdgcn_global_load_lds((gas_t)srcA, (las_t)&smem8[dbase + (q * 256 + tid) * 16], 16, 0, 0);
            __builtin_amdgcn_global_load_lds((gas_t)srcB, (las_t)&smem8[dbase + 8192 + (q * 256 + tid) * 16], 16, 0, 0);
        }
    };

    stage(0, 0);
    __syncthreads();                 // pipeline fill
    for (int t = 0; t < 8; ++t) {
        const int dbase = (t & 1) * 16384;
        if (t < 7) stage(t + 1, 16384 - dbase);   // prefetch other buf
        bf16x8 af[4], bf[4];
#pragma unroll
        for (int mt = 0; mt < 4; ++mt) {
            const int row = wi * 64 + mt * 16 + c16;
            af[mt] = *(const bf16x8*)&smem8[dbase + row * 64 + ((g ^ ((row >> 1) & 3)) * 16)];
        }
#pragma unroll
        for (int nt = 0; nt < 4; ++nt) {
            const int row = wj * 64 + nt * 16 + c16;
            bf[nt] = *(const bf16x8*)&smem8[dbase + 8192 + row * 64 + ((g ^ ((row >> 1) & 3)) * 16)];
        }
#pragma unroll
        for (int mt = 0; mt < 4; ++mt)
#pragma unroll
            for (int nt = 0; nt < 4; ++nt)
                acc[mt][nt] = __builtin_amdgcn_mfma_f32_16x16x32_bf16(af[mt], bf[nt], acc[mt][nt], 0, 0, 0);
        __syncthreads();   // waits prefetch (vmcnt) + frees buf for next stage
    }
    const float sh = (PT8 != nullptr) ? 3.0f : 0.0f;
#pragma unroll
    for (int mt = 0; mt < 4; ++mt) {
        float rs[4] = {0.f, 0.f, 0.f, 0.f};
#pragma unroll
        for (int nt = 0; nt < 4; ++nt) {
            float e0 = __builtin_amdgcn_exp2f(acc[mt][nt][0] - sh);
            float e1 = __builtin_amdgcn_exp2f(acc[mt][nt][1] - sh);
            float e2 = __builtin_amdgcn_exp2f(acc[mt][nt][2] - sh);
            float e3 = __builtin_amdgcn_exp2f(acc[mt][nt][3] - sh);
            rs[0] += e0; rs[1] += e1; rs[2] += e2; rs[3] += e3;
            if (PT8 != nullptr) {
                int pk = __builtin_amdgcn_cvt_pk_fp8_f32(e0, e1, 0, false);
                pk = __builtin_amdgcn_cvt_pk_fp8_f32(e2, e3, pk, true);
                const int jl = wj * 64 + nt * 16 + c16;
                const int il = wi * 64 + mt * 16 + g * 4;
                *(int*)&sp8[jl * 144 + il] = pk;
            }
        }
#pragma unroll
        for (int r = 0; r < 4; ++r) {
            float s = rs[r];
            s += __shfl_xor(s, 1, 64);
            s += __shfl_xor(s, 2, 64);
            s += __shfl_xor(s, 4, 64);
            s += __shfl_xor(s, 8, 64);
            if (c16 == 0) {
                if (PT8 != nullptr)
                    lsum[wj * 128 + wi * 64 + mt * 16 + g * 4 + r] = s;
                else
                    atomicAdd(l + (size_t)b * N_ + ib + wi * 64 + mt * 16 + g * 4 + r, s);
            }
        }
    }
    if (PT8 != nullptr) {
        __syncthreads();
        // stream out: 128 rows x 128 B (fp8), NONTEMPORAL (bypass L2 pollution)
        const int chb = tid & 7;     // 16B chunk within row
        const int rb = tid >> 3;     // 32 rows per pass
#pragma unroll
        for (int r = 0; r < 4; ++r) {
            const int jl = r * 32 + rb;
            u32x4 v = *(const u32x4*)&sp8[jl * 144 + chb * 16];
            __builtin_nontemporal_store(v,
                (u32x4*)(PT8 + ((size_t)(b * N_ + jb + jl)) * N_ + ib + chb * 16));
        }
        // per-block row-sum partial: one coalesced 512 B store, no atomics
        if (tid < 128) {
            float tot = lsum[tid] + lsum[128 + tid];
            lpart[((size_t)(b * 32 + bx)) * N_ + ib + tid] = tot;
        }
    }
}

// ---------------------------------------------------------------------------
// l[b][i] = sum_jt lpart[b][jt][i]  (2 MB read, 64 KB write, ~1-2 us)
// grid (N/1024, B), block 256, float4 per thread.
// ---------------------------------------------------------------------------
__global__ void reduce_l_kernel(const float* __restrict__ lpart, float* __restrict__ l) {
    const int b = blockIdx.y;
    const int i = (blockIdx.x * 256 + threadIdx.x) * 4;
    float4 s = {0.f, 0.f, 0.f, 0.f};
#pragma unroll
    for (int jt = 0; jt < 32; ++jt) {
        float4 p = *(const float4*)(lpart + ((size_t)(b * 32 + jt)) * N_ + i);
        s.x += p.x; s.y += p.y; s.z += p.z; s.w += p.w;
    }
    *(float4*)(l + (size_t)b * N_ + i) = s;
}

// ---------------------------------------------------------------------------
// V'' = V * 2^13 * rcp(l') -> fp8 e4m3.  grid (N/2048, C, B), block 256.
// ---------------------------------------------------------------------------
__global__ void scale_v_kernel(const ushort_t* __restrict__ Vm, const float* __restrict__ l,
                               uchar_t* __restrict__ Vs) {
    const int i = (blockIdx.x * 256 + threadIdx.x) * 8;
    const int c = blockIdx.y, b = blockIdx.z;
    float4 l0 = *(const float4*)(l + (size_t)b * N_ + i);
    float4 l1 = *(const float4*)(l + (size_t)b * N_ + i + 4);
    float r[8] = {__builtin_amdgcn_rcpf(l0.x), __builtin_amdgcn_rcpf(l0.y),
                  __builtin_amdgcn_rcpf(l0.z), __builtin_amdgcn_rcpf(l0.w),
                  __builtin_amdgcn_rcpf(l1.x), __builtin_amdgcn_rcpf(l1.y),
                  __builtin_amdgcn_rcpf(l1.z), __builtin_amdgcn_rcpf(l1.w)};
    const size_t off = ((size_t)(b * C_ + c)) * N_ + i;
    uint4 v = *(const uint4*)(Vm + off);
    unsigned vw[4] = {v.x, v.y, v.z, v.w};
    float f[8];
#pragma unroll
    for (int q = 0; q < 4; ++q) {
        union { unsigned u; float fl; } lo, hi;
        lo.u = (vw[q] & 0xffffu) << 16;
        hi.u = vw[q] & 0xffff0000u;
        f[q * 2 + 0] = lo.fl * r[q * 2 + 0] * VSCALE;
        f[q * 2 + 1] = hi.fl * r[q * 2 + 1] * VSCALE;
    }
    int d0 = __builtin_amdgcn_cvt_pk_fp8_f32(f[0], f[1], 0, false);
    d0 = __builtin_amdgcn_cvt_pk_fp8_f32(f[2], f[3], d0, true);
    int d1 = __builtin_amdgcn_cvt_pk_fp8_f32(f[4], f[5], 0, false);
    d1 = __builtin_amdgcn_cvt_pk_fp8_f32(f[6], f[7], d1, true);
    uint2 o; o.x = (unsigned)d0; o.y = (unsigned)d1;
    *(uint2*)(Vs + off) = o;
}

// ---------------------------------------------------------------------------
// Pass B v10 (kept): fp8 single-K GEMM, double-buffered staging, NT fp32
// residual/out streams (R4-verified).
// ---------------------------------------------------------------------------
__global__ __launch_bounds__(512, 4)
void gemm_out2_kernel(const uchar_t* __restrict__ A /*Vs fp8 [B][C][N]*/,
                      const uchar_t* __restrict__ Bm /*PT fp8 [B][N][N]*/,
                      const float* __restrict__ R /*x_s2 as [B][C][N]*/,
                      float* __restrict__ out) {
    __shared__ uchar_t smem[73728];   // 2 x (32 KB A + 4 KB B)
    const int tid = threadIdx.x;
    const int lane = tid & 63, g = lane >> 4, c16 = lane & 15;
    const int w = tid >> 6;
    const int cw = w * 32;              // wave's 32-c band
    const int b = blockIdx.y;
    const int jb = blockIdx.x * 32;

    f32x4 acc[2][2];
#pragma unroll
    for (int mt = 0; mt < 2; ++mt)
#pragma unroll
        for (int nt = 0; nt < 2; ++nt) acc[mt][nt] = (f32x4){0.f, 0.f, 0.f, 0.f};

    const int sch = tid & 7;          // chunk slot within row

    auto stage = [&](int k0, int dbase) {
        // stage A (Vs): 256 rows x 8 chunks = 2048 slots, 4 passes
#pragma unroll
        for (int q = 0; q < 4; ++q) {
            const int slot = q * 512 + tid;
            const int row = slot >> 3;
            const int gc = sch ^ (row & 7);
            const uchar_t* src = A + ((size_t)(b * C_ + row)) * N_ + k0 + gc * 16;
            __builtin_amdgcn_global_load_lds((gas_t)src, (las_t)&smem[dbase + slot * 16], 16, 0, 0);
        }
        // stage B (PT): 32 rows x 8 chunks = 256 slots (threads 0..255)
        if (tid < 256) {
            const int row = tid >> 3;
            const int gc = sch ^ (row & 7);
            const uchar_t* src = Bm + ((size_t)(b * N_ + jb + row)) * N_ + k0 + gc * 16;
            __builtin_amdgcn_global_load_lds((gas_t)src, (las_t)&smem[dbase + 32768 + tid * 16], 16, 0, 0);
        }
    };

    stage(0, 0);
    __syncthreads();                     // pipeline fill
    for (int t = 0; t < 32; ++t) {
        const int dbase = (t & 1) * 36864;
        if (t < 31) stage((t + 1) * 128, 36864 - dbase);   // prefetch other buf
        const uchar_t* sA = &smem[dbase];
        const uchar_t* sB = &smem[dbase + 32768];
#pragma unroll
        for (int ks = 0; ks < 4; ++ks) {    // 4 x K=32
            const int lc = ks * 2 + (g >> 1);       // logical 16B chunk
            const int bo = (g & 1) * 8;             // byte within chunk
            long af[2], bfg[2];
#pragma unroll
            for (int mt = 0; mt < 2; ++mt) {
                const int row = cw + mt * 16 + c16;
                af[mt] = *(const long*)&sA[row * 128 + ((lc ^ (row & 7)) * 16) + bo];
            }
#pragma unroll
            for (int nt = 0; nt < 2; ++nt) {
                const int row = nt * 16 + c16;
                bfg[nt] = *(const long*)&sB[row * 128 + ((lc ^ (row & 7)) * 16) + bo];
            }
#pragma unroll
            for (int mt = 0; mt < 2; ++mt)
#pragma unroll
                for (int nt = 0; nt < 2; ++nt)
                    acc[mt][nt] = __builtin_amdgcn_mfma_f32_16x16x32_fp8_fp8(af[mt], bfg[nt], acc[mt][nt], 0, 0, 0);
        }
        __syncthreads();   // waits prefetch + frees buf for next stage
    }
    // epilogue: out = residual + acc * 2^-13 (nontemporal fp32 stream)
#pragma unroll
    for (int mt = 0; mt < 2; ++mt)
#pragma unroll
        for (int r = 0; r < 4; ++r) {
            const int c = cw + mt * 16 + g * 4 + r;
            const size_t rowoff = ((size_t)(b * C_ + c)) * N_ + jb;
#pragma unroll
            for (int nt = 0; nt < 2; ++nt) {
                const int j = nt * 16 + c16;
                float rv = __builtin_nontemporal_load(&R[rowoff + j]);
                __builtin_nontemporal_store(rv + acc[mt][nt][r] * VSCALE_INV,
                                            &out[rowoff + j]);
            }
        }
}

// ---------------------------------------------------------------------------
// Fallback Pass B (unchanged; used when ws small).  Needs bf16 V (Vm) and
// UNSHIFTED l (stats uses sh=0 + atomics when PT==null).
// ---------------------------------------------------------------------------
__global__ __launch_bounds__(512, 4)
void out_kernel(const ushort_t* __restrict__ Kt, const ushort_t* __restrict__ Qt,
                const ushort_t* __restrict__ V, const float* __restrict__ l,
                float* __restrict__ dout) {
    __shared__ ushort_t sQ[64][264];
    __shared__ ushort_t sP[64][264];
    const int tid = threadIdx.x;
    const int w = tid >> 6, lane = tid & 63, g = lane >> 4, c16 = lane & 15;
    const int b = blockIdx.z;
    const int jb = blockIdx.x * 64;
    const int ibase = blockIdx.y * 2048;
    {
        const int jl = tid >> 3, cp = (tid & 7) * 32;
        const ushort_t* src = Qt + ((size_t)(b * N_ + jb + jl)) * C_ + cp;
        uint4 a0 = *(const uint4*)(src);
        uint4 a1 = *(const uint4*)(src + 8);
        uint4 a2 = *(const uint4*)(src + 16);
        uint4 a3 = *(const uint4*)(src + 24);
        *(uint4*)&sQ[jl][cp + 0]  = a0;
        *(uint4*)&sQ[jl][cp + 8]  = a1;
        *(uint4*)&sQ[jl][cp + 16] = a2;
        *(uint4*)&sQ[jl][cp + 24] = a3;
    }
    f32x4 acc[2][4];
#pragma unroll
    for (int mt = 0; mt < 2; ++mt)
#pragma unroll
        for (int nt = 0; nt < 4; ++nt) acc[mt][nt] = (f32x4){0.f, 0.f, 0.f, 0.f};

    const int bw = w * 32;

    for (int ic = 0; ic < 8; ++ic) {
        const int i0 = ibase + ic * 256;
        float rv[2][4];
#pragma unroll
        for (int mt = 0; mt < 2; ++mt) {
            float4 lr = *(const float4*)(l + (size_t)b * N_ + i0 + bw + mt * 16 + g * 4);
            rv[mt][0] = __builtin_amdgcn_logf(lr.x);
            rv[mt][1] = __builtin_amdgcn_logf(lr.y);
            rv[mt][2] = __builtin_amdgcn_logf(lr.z);
            rv[mt][3] = __builtin_amdgcn_logf(lr.w);
        }
        __syncthreads();
        f32x4 sa[2][4];
#pragma unroll
        for (int mt = 0; mt < 2; ++mt)
#pragma unroll
            for (int nt = 0; nt < 4; ++nt) sa[mt][nt] = (f32x4){0.f, 0.f, 0.f, 0.f};
#pragma unroll
        for (int k = 0; k < 8; ++k) {
            bf16x8 av[2];
#pragma unroll
            for (int mt = 0; mt < 2; ++mt)
                av[mt] = ld_bf8(Kt + ((size_t)(b * N_ + i0 + bw + mt * 16 + c16)) * C_ + k * 32 + g * 8);
#pragma unroll
            for (int nt = 0; nt < 4; ++nt) {
                bf16x8 bv = *(const bf16x8*)&sQ[nt * 16 + c16][k * 32 + g * 8];
#pragma unroll
                for (int mt = 0; mt < 2; ++mt)
                    sa[mt][nt] = __builtin_amdgcn_mfma_f32_16x16x32_bf16(av[mt], bv, sa[mt][nt], 0, 0, 0);
            }
        }
#pragma unroll
        for (int mt = 0; mt < 2; ++mt)
#pragma unroll
            for (int nt = 0; nt < 4; ++nt) {
                const int j = nt * 16 + c16;
                unsigned p0 = f2bf(__builtin_amdgcn_exp2f(sa[mt][nt][0] - rv[mt][0]));
                unsigned p1 = f2bf(__builtin_amdgcn_exp2f(sa[mt][nt][1] - rv[mt][1]));
                unsigned p2 = f2bf(__builtin_amdgcn_exp2f(sa[mt][nt][2] - rv[mt][2]));
                unsigned p3 = f2bf(__builtin_amdgcn_exp2f(sa[mt][nt][3] - rv[mt][3]));
                uint2 pk; pk.x = p0 | (p1 << 16); pk.y = p2 | (p3 << 16);
                *(uint2*)&sP[j][bw + mt * 16 + g * 4] = pk;
            }
        __syncthreads();
#pragma unroll
        for (int ks = 0; ks < 8; ++ks) {
            bf16x8 va[2];
#pragma unroll
            for (int mt = 0; mt < 2; ++mt)
                va[mt] = ld_bf8(V + ((size_t)(b * C_ + bw + mt * 16 + c16)) * N_ + i0 + ks * 32 + g * 8);
#pragma unroll
            for (int nt = 0; nt < 4; ++nt) {
                bf16x8 pb = *(const bf16x8*)&sP[nt * 16 + c16][ks * 32 + g * 8];
#pragma unroll
                for (int mt = 0; mt < 2; ++mt)
                    acc[mt][nt] = __builtin_amdgcn_mfma_f32_16x16x32_bf16(va[mt], pb, acc[mt][nt], 0, 0, 0);
            }
        }
    }
#pragma unroll
    for (int mt = 0; mt < 2; ++mt)
#pragma unroll
        for (int nt = 0; nt < 4; ++nt)
#pragma unroll
            for (int r = 0; r < 4; ++r) {
                const int c = bw + mt * 16 + g * 4 + r;
                const int j = jb + nt * 16 + c16;
                atomicAdd(dout + ((size_t)b * C_ + c) * N_ + j, acc[mt][nt][r]);
            }
}

extern "C" void kernel_launch(void* const* d_in, const int* in_sizes, int n_in,
                              void* d_out, int out_size, void* d_ws, size_t ws_size,
                              hipStream_t stream) {
    const float* x_s2  = (const float*)d_in[0];
    const float* x_dem = (const float*)d_in[1];
    const float* Wq = (const float*)d_in[2];
    const float* bq = (const float*)d_in[3];
    const float* Wk = (const float*)d_in[4];
    const float* bk = (const float*)d_in[5];
    const float* Wv = (const float*)d_in[6];
    const float* bv = (const float*)d_in[7];
    float* out = (float*)d_out;

    const size_t MiB = 1024 * 1024;
    char* ws = (char*)d_ws;
    ushort_t* Qt = (ushort_t*)(ws);               // [B][N][C] bf16, 8 MiB
    ushort_t* Kt = (ushort_t*)(ws + 8  * MiB);    // [B][N][C] bf16, pre-scaled
    ushort_t* Vm = (ushort_t*)(ws + 16 * MiB);    // [B][C][N] bf16, 8 MiB
    uchar_t*  Vs = (uchar_t*) (ws + 24 * MiB);    // [B][C][N] fp8 V'', 4 MiB
    float*    lp = (float*)   (ws + 24 * MiB);    // [B][32][N] partials, 2 MiB
                                                  //   (aliases Vs: dead before
                                                  //    scale_v writes Vs)
    float*    lv = (float*)   (ws + 28 * MiB);    // [B][N] row sums, 64 KiB
    uchar_t*  PT = (uchar_t*) (ws + 29 * MiB);    // [B][N(j)][N(i)] fp8, 64 MiB
    const bool bigws = ws_size >= 93 * MiB;

    if (!bigws) {
        // fallback path: atomic l accumulation + residual-prefilled out
        hipMemsetAsync(lv, 0, (size_t)B_ * N_ * sizeof(float), stream);
        hipMemcpyAsync(out, x_s2, (size_t)B_ * C_ * N_ * sizeof(float),
                       hipMemcpyDeviceToDevice, stream);
    }

    proj_fused<<<dim3(N_ / 128, 8, B_), 256, 0, stream>>>(x_s2, Wq, bq,
                                                          x_dem, Wk, bk, Wv, bv,
                                                          Qt, Kt, Vm);
    stats_kernel<<<dim3(4096), 256, 0, stream>>>(Kt, Qt, lv,
                                                 bigws ? PT : (uchar_t*)nullptr,
                                                 lp);
    if (bigws) {
        reduce_l_kernel<<<dim3(N_ / 1024, B_), 256, 0, stream>>>(lp, lv);
        scale_v_kernel<<<dim3(N_ / 2048, C_, B_), 256, 0, stream>>>(Vm, lv, Vs);
        gemm_out2_kernel<<<dim3(N_ / 32, B_), 512, 0, stream>>>(Vs, PT, x_s2, out);
    } else {
        out_kernel<<<dim3(N_ / 64, 2, B_), 512, 0, stream>>>(Kt, Qt, Vm, lv, out);
    }
}

// Round 8
// 208.154 us; speedup vs baseline: 1.0442x; 1.0442x over previous
//
#include <hip/hip_runtime.h>
#include <hip/hip_bf16.h>
#include <cstdint>

#define B_  4
#define N_  4096
#define C_  256
#define CD_ 64

typedef unsigned short ushort_t;
typedef unsigned char uchar_t;
typedef __bf16 bf16x8 __attribute__((ext_vector_type(8)));
typedef float f32x4 __attribute__((ext_vector_type(4)));
typedef unsigned int u32x4 __attribute__((ext_vector_type(4)));

typedef const __attribute__((address_space(1))) void* gas_t;
typedef __attribute__((address_space(3))) void* las_t;

// (1/sqrt(256)) * log2(e): folded into K projection so S' = S_true * log2(e)
static constexpr float SCALE_LOG2E = 0.09016844005556021f;
// V' scale 2^13 (undone in gemm epilogue); PT exponent shift -3 cancels via l.
static constexpr float VSCALE = 8192.0f;
static constexpr float VSCALE_INV = 1.0f / 8192.0f;

__device__ __forceinline__ ushort_t f2bf(float x) {
    union { float f; unsigned u; } v; v.f = x;
    unsigned u = v.u;
    unsigned r = (u + 0x7fffu + ((u >> 16) & 1u)) >> 16;  // round-nearest-even
    return (ushort_t)r;
}

__device__ __forceinline__ bf16x8 ld_bf8(const ushort_t* p) {
    return *reinterpret_cast<const bf16x8*>(p);
}

// ---------------------------------------------------------------------------
// MFMA projection -> TRANSPOSED layout dst[b][n][o]  (proven R8; R7's fusion
// REVERTED: 36.9 KB LDS union dropped proj_q 5->4 blocks/CU and serialized
// the Q-role critical path -> +9 us total.  Separate launches re-proven.)
// ---------------------------------------------------------------------------
__global__ __launch_bounds__(256, 4)
void proj_q_mfma(const float* __restrict__ X, const float* __restrict__ W,
                 const float* __restrict__ bias, ushort_t* __restrict__ dst,
                 int Cin, float outScale) {
    __shared__ ushort_t sX[128][72];   // [n][c] bf16
    __shared__ ushort_t sW[64][72];    // [o][c] bf16
    const int tid = threadIdx.x;
    const int lane = tid & 63, g = lane >> 4, c16 = lane & 15;
    const int w = tid >> 6, wi = w >> 1, wj = w & 1;   // n-half, o-half
    const int b = blockIdx.z, nb = blockIdx.x * 128, ob = blockIdx.y * 64;
    f32x4 acc[4][2];
#pragma unroll
    for (int nt = 0; nt < 4; ++nt)
#pragma unroll
        for (int ot = 0; ot < 2; ++ot) acc[nt][ot] = (f32x4){0.f, 0.f, 0.f, 0.f};

    const int cr = tid >> 5;
    const int n0 = (tid & 31) * 4;

    for (int k0 = 0; k0 < Cin; k0 += 64) {
#pragma unroll
        for (int p = 0; p < 8; ++p) {
            const int c = p * 8 + cr;
            float4 xv = *(const float4*)(X + ((size_t)b * Cin + k0 + c) * N_ + nb + n0);
            sX[n0 + 0][c] = f2bf(xv.x);
            sX[n0 + 1][c] = f2bf(xv.y);
            sX[n0 + 2][c] = f2bf(xv.z);
            sX[n0 + 3][c] = f2bf(xv.w);
        }
        {
            const int o = tid >> 2, cq = (tid & 3) * 16;
            const float* wsrc = W + (size_t)(ob + o) * Cin + k0 + cq;
            alignas(16) ushort_t tmp[16];
#pragma unroll
            for (int q = 0; q < 16; ++q) tmp[q] = f2bf(wsrc[q]);
            *(uint4*)&sW[o][cq]     = *(uint4*)&tmp[0];
            *(uint4*)&sW[o][cq + 8] = *(uint4*)&tmp[8];
        }
        __syncthreads();
#pragma unroll
        for (int ks = 0; ks < 2; ++ks) {
            bf16x8 af[4], bfr[2];
#pragma unroll
            for (int nt = 0; nt < 4; ++nt)
                af[nt] = *(const bf16x8*)&sX[wi * 64 + nt * 16 + c16][ks * 32 + g * 8];
#pragma unroll
            for (int ot = 0; ot < 2; ++ot)
                bfr[ot] = *(const bf16x8*)&sW[wj * 32 + ot * 16 + c16][ks * 32 + g * 8];
#pragma unroll
            for (int nt = 0; nt < 4; ++nt)
#pragma unroll
                for (int ot = 0; ot < 2; ++ot)
                    acc[nt][ot] = __builtin_amdgcn_mfma_f32_16x16x32_bf16(af[nt], bfr[ot], acc[nt][ot], 0, 0, 0);
        }
        __syncthreads();
    }
#pragma unroll
    for (int ot = 0; ot < 2; ++ot) {
        const int o = ob + wj * 32 + ot * 16 + c16;
        const float bia = bias[o];
#pragma unroll
        for (int nt = 0; nt < 4; ++nt) {
#pragma unroll
            for (int r = 0; r < 4; ++r) {
                const int n = nb + wi * 64 + nt * 16 + g * 4 + r;
                dst[((size_t)b * N_ + n) * C_ + o] = f2bf((acc[nt][ot][r] + bia) * outScale);
            }
        }
    }
}

// ---------------------------------------------------------------------------
// Fused K+V MFMA projection from x_dem (proven R8)
// ---------------------------------------------------------------------------
__global__ __launch_bounds__(256, 4)
void proj_kv_mfma(const float* __restrict__ X, const float* __restrict__ Wk,
                  const float* __restrict__ bk, const float* __restrict__ Wv,
                  const float* __restrict__ bv, ushort_t* __restrict__ Kt,
                  ushort_t* __restrict__ Vm) {
    __shared__ ushort_t sX[128][72];   // [n][c]
    __shared__ ushort_t sWk[64][72];   // [o][c]
    __shared__ ushort_t sWv[64][72];
    const int tid = threadIdx.x;
    const int lane = tid & 63, g = lane >> 4, c16 = lane & 15;
    const int w = tid >> 6;
    const int b = blockIdx.z, nb = blockIdx.x * 128, ob = blockIdx.y * 64;

    {
        const int cr = tid >> 5, n0 = (tid & 31) * 4;
#pragma unroll
        for (int p = 0; p < 8; ++p) {
            const int c = p * 8 + cr;
            float4 xv = *(const float4*)(X + ((size_t)b * CD_ + c) * N_ + nb + n0);
            sX[n0 + 0][c] = f2bf(xv.x);
            sX[n0 + 1][c] = f2bf(xv.y);
            sX[n0 + 2][c] = f2bf(xv.z);
            sX[n0 + 3][c] = f2bf(xv.w);
        }
        const int o = tid >> 2, cq = (tid & 3) * 16;
        alignas(16) ushort_t tk[16], tv[16];
        const float* ksrc = Wk + (size_t)(ob + o) * CD_ + cq;
        const float* vsrc = Wv + (size_t)(ob + o) * CD_ + cq;
#pragma unroll
        for (int q = 0; q < 16; ++q) { tk[q] = f2bf(ksrc[q]); tv[q] = f2bf(vsrc[q]); }
        *(uint4*)&sWk[o][cq]     = *(uint4*)&tk[0];
        *(uint4*)&sWk[o][cq + 8] = *(uint4*)&tk[8];
        *(uint4*)&sWv[o][cq]     = *(uint4*)&tv[0];
        *(uint4*)&sWv[o][cq + 8] = *(uint4*)&tv[8];
    }
    __syncthreads();
    // ---- K-part ----
    {
        const int wi = w >> 1, wj = w & 1;
        f32x4 acc[4][2];
#pragma unroll
        for (int nt = 0; nt < 4; ++nt)
#pragma unroll
            for (int ot = 0; ot < 2; ++ot) acc[nt][ot] = (f32x4){0.f, 0.f, 0.f, 0.f};
#pragma unroll
        for (int ks = 0; ks < 2; ++ks) {
            bf16x8 af[4], bfr[2];
#pragma unroll
            for (int nt = 0; nt < 4; ++nt)
                af[nt] = *(const bf16x8*)&sX[wi * 64 + nt * 16 + c16][ks * 32 + g * 8];
#pragma unroll
            for (int ot = 0; ot < 2; ++ot)
                bfr[ot] = *(const bf16x8*)&sWk[wj * 32 + ot * 16 + c16][ks * 32 + g * 8];
#pragma unroll
            for (int nt = 0; nt < 4; ++nt)
#pragma unroll
                for (int ot = 0; ot < 2; ++ot)
                    acc[nt][ot] = __builtin_amdgcn_mfma_f32_16x16x32_bf16(af[nt], bfr[ot], acc[nt][ot], 0, 0, 0);
        }
#pragma unroll
        for (int ot = 0; ot < 2; ++ot) {
            const int o = ob + wj * 32 + ot * 16 + c16;
            const float bia = bk[o];
#pragma unroll
            for (int nt = 0; nt < 4; ++nt)
#pragma unroll
                for (int r = 0; r < 4; ++r) {
                    const int n = nb + wi * 64 + nt * 16 + g * 4 + r;
                    Kt[((size_t)b * N_ + n) * C_ + o] = f2bf((acc[nt][ot][r] + bia) * SCALE_LOG2E);
                }
        }
    }
    // ---- V-part ----
    {
        const int ow = w & 1, nw = w >> 1;
        f32x4 acc[2][4];
#pragma unroll
        for (int mt = 0; mt < 2; ++mt)
#pragma unroll
            for (int nt = 0; nt < 4; ++nt) acc[mt][nt] = (f32x4){0.f, 0.f, 0.f, 0.f};
#pragma unroll
        for (int ks = 0; ks < 2; ++ks) {
            bf16x8 af[2], bfr[4];
#pragma unroll
            for (int mt = 0; mt < 2; ++mt)
                af[mt] = *(const bf16x8*)&sWv[ow * 32 + mt * 16 + c16][ks * 32 + g * 8];
#pragma unroll
            for (int nt = 0; nt < 4; ++nt)
                bfr[nt] = *(const bf16x8*)&sX[nw * 64 + nt * 16 + c16][ks * 32 + g * 8];
#pragma unroll
            for (int mt = 0; mt < 2; ++mt)
#pragma unroll
                for (int nt = 0; nt < 4; ++nt)
                    acc[mt][nt] = __builtin_amdgcn_mfma_f32_16x16x32_bf16(af[mt], bfr[nt], acc[mt][nt], 0, 0, 0);
        }
#pragma unroll
        for (int mt = 0; mt < 2; ++mt) {
            const float4 bi4 = *(const float4*)(bv + ob + ow * 32 + mt * 16 + g * 4);
            const float bia[4] = {bi4.x, bi4.y, bi4.z, bi4.w};
#pragma unroll
            for (int nt = 0; nt < 4; ++nt) {
                const int n = nb + nw * 64 + nt * 16 + c16;
#pragma unroll
                for (int r = 0; r < 4; ++r) {
                    const int o = ob + ow * 32 + mt * 16 + g * 4 + r;
                    Vm[((size_t)b * C_ + o) * N_ + n] = f2bf(acc[mt][nt][r] + bia[r]);
                }
            }
        }
    }
}

// ---------------------------------------------------------------------------
// Pass A v8 (R18, kept): R4's proven BK=32 dbuf loop + XCD supertile swizzle
// (R6-verified: FETCH 36.9 -> 24.6 MB; dur at 2-phase structural floor).
// PT streamout NONTEMPORAL (R4-verified: WRITE at 67.6 MB ideal).
// ---------------------------------------------------------------------------
__global__ __launch_bounds__(256, 4)
void stats_kernel(const ushort_t* __restrict__ Kt, const ushort_t* __restrict__ Qt,
                  float* __restrict__ l, uchar_t* __restrict__ PT8,
                  float* __restrict__ lpart) {
    __shared__ ushort_t smem[16384];   // 32 KB: buf t at (t&1)*16K: A 8K + B 8K
    uchar_t* smem8 = (uchar_t*)smem;
    uchar_t* sp8 = smem8;                      // epilogue: [128][144] fp8 tile
    float* lsum = (float*)(smem8 + 18432);     // [2][128] row partials
    const int tid = threadIdx.x;
    const int lane = tid & 63, g = lane >> 4, c16 = lane & 15;
    const int w = tid >> 6, wi = w >> 1, wj = w & 1;
    // ---- XCD supertile decode (bijective): hv -> (b, by, bx) ----
    const int hv = blockIdx.x;           // 0..4095
    const int xcd = hv & 7;              // round-robin XCD slot
    const int slot = hv >> 3;            // 0..511
    const int st = xcd + 8 * (slot >> 6);    // supertile 0..63 (8 per XCD)
    const int within = slot & 63;            // 0..63 inside 8x8 supertile
    const int b = st >> 4;                   // batch
    const int stl = st & 15;                 // supertile within batch (4x4)
    const int by = (stl >> 2) * 8 + (within >> 3);   // ib tile 0..31
    const int bx = (stl & 3) * 8 + (within & 7);     // jb tile 0..31
    const int ib = by * 128, jb = bx * 128;
    f32x4 acc[4][4];
#pragma unroll
    for (int mt = 0; mt < 4; ++mt)
#pragma unroll
        for (int nt = 0; nt < 4; ++nt) acc[mt][nt] = (f32x4){0.f, 0.f, 0.f, 0.f};

    const int srow = tid >> 2;   // 0..63 (row within 64-row half)
    const int sc = tid & 3;      // 16B chunk slot within 64B row

    auto stage = [&](int kc, int dbase) {      // kc: 32-wide K chunk index
#pragma unroll
        for (int q = 0; q < 2; ++q) {
            const int row = q * 64 + srow;
            const int gc = sc ^ ((row >> 1) & 3);
            const ushort_t* srcA = Kt + ((size_t)(b * N_ + ib + row)) * C_ + kc * 32 + gc * 8;
            const ushort_t* srcB = Qt + ((size_t)(b * N_ + jb + row)) * C_ + kc * 32 + gc * 8;
            __builtin_amdgcn_global_load_lds((gas_t)srcA, (las_t)&smem8[dbase + (q * 256 + tid) * 16], 16, 0, 0);
            __builtin_amdgcn_global_load_lds((gas_t)srcB, (las_t)&smem8[dbase + 8192 + (q * 256 + tid) * 16], 16, 0, 0);
        }
    };

    stage(0, 0);
    __syncthreads();                 // pipeline fill
    for (int t = 0; t < 8; ++t) {
        const int dbase = (t & 1) * 16384;
        if (t < 7) stage(t + 1, 16384 - dbase);   // prefetch other buf
        bf16x8 af[4], bf[4];
#pragma unroll
        for (int mt = 0; mt < 4; ++mt) {
            const int row = wi * 64 + mt * 16 + c16;
            af[mt] = *(const bf16x8*)&smem8[dbase + row * 64 + ((g ^ ((row >> 1) & 3)) * 16)];
        }
#pragma unroll
        for (int nt = 0; nt < 4; ++nt) {
            const int row = wj * 64 + nt * 16 + c16;
            bf[nt] = *(const bf16x8*)&smem8[dbase + 8192 + row * 64 + ((g ^ ((row >> 1) & 3)) * 16)];
        }
#pragma unroll
        for (int mt = 0; mt < 4; ++mt)
#pragma unroll
            for (int nt = 0; nt < 4; ++nt)
                acc[mt][nt] = __builtin_amdgcn_mfma_f32_16x16x32_bf16(af[mt], bf[nt], acc[mt][nt], 0, 0, 0);
        __syncthreads();   // waits prefetch (vmcnt) + frees buf for next stage
    }
    const float sh = (PT8 != nullptr) ? 3.0f : 0.0f;
#pragma unroll
    for (int mt = 0; mt < 4; ++mt) {
        float rs[4] = {0.f, 0.f, 0.f, 0.f};
#pragma unroll
        for (int nt = 0; nt < 4; ++nt) {
            float e0 = __builtin_amdgcn_exp2f(acc[mt][nt][0] - sh);
            float e1 = __builtin_amdgcn_exp2f(acc[mt][nt][1] - sh);
            float e2 = __builtin_amdgcn_exp2f(acc[mt][nt][2] - sh);
            float e3 = __builtin_amdgcn_exp2f(acc[mt][nt][3] - sh);
            rs[0] += e0; rs[1] += e1; rs[2] += e2; rs[3] += e3;
            if (PT8 != nullptr) {
                int pk = __builtin_amdgcn_cvt_pk_fp8_f32(e0, e1, 0, false);
                pk = __builtin_amdgcn_cvt_pk_fp8_f32(e2, e3, pk, true);
                const int jl = wj * 64 + nt * 16 + c16;
                const int il = wi * 64 + mt * 16 + g * 4;
                *(int*)&sp8[jl * 144 + il] = pk;
            }
        }
#pragma unroll
        for (int r = 0; r < 4; ++r) {
            float s = rs[r];
            s += __shfl_xor(s, 1, 64);
            s += __shfl_xor(s, 2, 64);
            s += __shfl_xor(s, 4, 64);
            s += __shfl_xor(s, 8, 64);
            if (c16 == 0) {
                if (PT8 != nullptr)
                    lsum[wj * 128 + wi * 64 + mt * 16 + g * 4 + r] = s;
                else
                    atomicAdd(l + (size_t)b * N_ + ib + wi * 64 + mt * 16 + g * 4 + r, s);
            }
        }
    }
    if (PT8 != nullptr) {
        __syncthreads();
        // stream out: 128 rows x 128 B (fp8), NONTEMPORAL (bypass L2 pollution)
        const int chb = tid & 7;     // 16B chunk within row
        const int rb = tid >> 3;     // 32 rows per pass
#pragma unroll
        for (int r = 0; r < 4; ++r) {
            const int jl = r * 32 + rb;
            u32x4 v = *(const u32x4*)&sp8[jl * 144 + chb * 16];
            __builtin_nontemporal_store(v,
                (u32x4*)(PT8 + ((size_t)(b * N_ + jb + jl)) * N_ + ib + chb * 16));
        }
        // per-block row-sum partial: one coalesced 512 B store, no atomics
        if (tid < 128) {
            float tot = lsum[tid] + lsum[128 + tid];
            lpart[((size_t)(b * 32 + bx)) * N_ + ib + tid] = tot;
        }
    }
}

// ---------------------------------------------------------------------------
// l[b][i] = sum_jt lpart[b][jt][i]  (2 MB read, 64 KB write, ~1-2 us)
// grid (N/1024, B), block 256, float4 per thread.
// ---------------------------------------------------------------------------
__global__ void reduce_l_kernel(const float* __restrict__ lpart, float* __restrict__ l) {
    const int b = blockIdx.y;
    const int i = (blockIdx.x * 256 + threadIdx.x) * 4;
    float4 s = {0.f, 0.f, 0.f, 0.f};
#pragma unroll
    for (int jt = 0; jt < 32; ++jt) {
        float4 p = *(const float4*)(lpart + ((size_t)(b * 32 + jt)) * N_ + i);
        s.x += p.x; s.y += p.y; s.z += p.z; s.w += p.w;
    }
    *(float4*)(l + (size_t)b * N_ + i) = s;
}

// ---------------------------------------------------------------------------
// V'' = V * 2^13 * rcp(l') -> fp8 e4m3.  grid (N/2048, C, B), block 256.
// ---------------------------------------------------------------------------
__global__ void scale_v_kernel(const ushort_t* __restrict__ Vm, const float* __restrict__ l,
                               uchar_t* __restrict__ Vs) {
    const int i = (blockIdx.x * 256 + threadIdx.x) * 8;
    const int c = blockIdx.y, b = blockIdx.z;
    float4 l0 = *(const float4*)(l + (size_t)b * N_ + i);
    float4 l1 = *(const float4*)(l + (size_t)b * N_ + i + 4);
    float r[8] = {__builtin_amdgcn_rcpf(l0.x), __builtin_amdgcn_rcpf(l0.y),
                  __builtin_amdgcn_rcpf(l0.z), __builtin_amdgcn_rcpf(l0.w),
                  __builtin_amdgcn_rcpf(l1.x), __builtin_amdgcn_rcpf(l1.y),
                  __builtin_amdgcn_rcpf(l1.z), __builtin_amdgcn_rcpf(l1.w)};
    const size_t off = ((size_t)(b * C_ + c)) * N_ + i;
    uint4 v = *(const uint4*)(Vm + off);
    unsigned vw[4] = {v.x, v.y, v.z, v.w};
    float f[8];
#pragma unroll
    for (int q = 0; q < 4; ++q) {
        union { unsigned u; float fl; } lo, hi;
        lo.u = (vw[q] & 0xffffu) << 16;
        hi.u = vw[q] & 0xffff0000u;
        f[q * 2 + 0] = lo.fl * r[q * 2 + 0] * VSCALE;
        f[q * 2 + 1] = hi.fl * r[q * 2 + 1] * VSCALE;
    }
    int d0 = __builtin_amdgcn_cvt_pk_fp8_f32(f[0], f[1], 0, false);
    d0 = __builtin_amdgcn_cvt_pk_fp8_f32(f[2], f[3], d0, true);
    int d1 = __builtin_amdgcn_cvt_pk_fp8_f32(f[4], f[5], 0, false);
    d1 = __builtin_amdgcn_cvt_pk_fp8_f32(f[6], f[7], d1, true);
    uint2 o; o.x = (unsigned)d0; o.y = (unsigned)d1;
    *(uint2*)(Vs + off) = o;
}

// ---------------------------------------------------------------------------
// Pass B v11: fp8 single-K GEMM, double-buffered staging, NT fp32 streams
// (R4-verified).  R20: PT staging loads carry CPol NT (aux=2) — PT is a
// 64 MB read-once stream; default-policy allocation was evicting the hot
// Vs panel (1 MB/batch, re-read by every j-block through L2).
// ---------------------------------------------------------------------------
__global__ __launch_bounds__(512, 4)
void gemm_out2_kernel(const uchar_t* __restrict__ A /*Vs fp8 [B][C][N]*/,
                      const uchar_t* __restrict__ Bm /*PT fp8 [B][N][N]*/,
                      const float* __restrict__ R /*x_s2 as [B][C][N]*/,
                      float* __restrict__ out) {
    __shared__ uchar_t smem[73728];   // 2 x (32 KB A + 4 KB B)
    const int tid = threadIdx.x;
    const int lane = tid & 63, g = lane >> 4, c16 = lane & 15;
    const int w = tid >> 6;
    const int cw = w * 32;              // wave's 32-c band
    const int b = blockIdx.y;
    const int jb = blockIdx.x * 32;

    f32x4 acc[2][2];
#pragma unroll
    for (int mt = 0; mt < 2; ++mt)
#pragma unroll
        for (int nt = 0; nt < 2; ++nt) acc[mt][nt] = (f32x4){0.f, 0.f, 0.f, 0.f};

    const int sch = tid & 7;          // chunk slot within row

    auto stage = [&](int k0, int dbase) {
        // stage A (Vs): 256 rows x 8 chunks = 2048 slots, 4 passes
#pragma unroll
        for (int q = 0; q < 4; ++q) {
            const int slot = q * 512 + tid;
            const int row = slot >> 3;
            const int gc = sch ^ (row & 7);
            const uchar_t* src = A + ((size_t)(b * C_ + row)) * N_ + k0 + gc * 16;
            __builtin_amdgcn_global_load_lds((gas_t)src, (las_t)&smem[dbase + slot * 16], 16, 0, 0);
        }
        // stage B (PT): 32 rows x 8 chunks = 256 slots (threads 0..255)
        // aux=2 -> CPol NT: read-once stream, evict-first (protect Vs in L2)
        if (tid < 256) {
            const int row = tid >> 3;
            const int gc = sch ^ (row & 7);
            const uchar_t* src = Bm + ((size_t)(b * N_ + jb + row)) * N_ + k0 + gc * 16;
            __builtin_amdgcn_global_load_lds((gas_t)src, (las_t)&smem[dbase + 32768 + tid * 16], 16, 0, 2);
        }
    };

    stage(0, 0);
    __syncthreads();                     // pipeline fill
    for (int t = 0; t < 32; ++t) {
        const int dbase = (t & 1) * 36864;
        if (t < 31) stage((t + 1) * 128, 36864 - dbase);   // prefetch other buf
        const uchar_t* sA = &smem[dbase];
        const uchar_t* sB = &smem[dbase + 32768];
#pragma unroll
        for (int ks = 0; ks < 4; ++ks) {    // 4 x K=32
            const int lc = ks * 2 + (g >> 1);       // logical 16B chunk
            const int bo = (g & 1) * 8;             // byte within chunk
            long af[2], bfg[2];
#pragma unroll
            for (int mt = 0; mt < 2; ++mt) {
                const int row = cw + mt * 16 + c16;
                af[mt] = *(const long*)&sA[row * 128 + ((lc ^ (row & 7)) * 16) + bo];
            }
#pragma unroll
            for (int nt = 0; nt < 2; ++nt) {
                const int row = nt * 16 + c16;
                bfg[nt] = *(const long*)&sB[row * 128 + ((lc ^ (row & 7)) * 16) + bo];
            }
#pragma unroll
            for (int mt = 0; mt < 2; ++mt)
#pragma unroll
                for (int nt = 0; nt < 2; ++nt)
                    acc[mt][nt] = __builtin_amdgcn_mfma_f32_16x16x32_fp8_fp8(af[mt], bfg[nt], acc[mt][nt], 0, 0, 0);
        }
        __syncthreads();   // waits prefetch + frees buf for next stage
    }
    // epilogue: out = residual + acc * 2^-13 (nontemporal fp32 stream)
#pragma unroll
    for (int mt = 0; mt < 2; ++mt)
#pragma unroll
        for (int r = 0; r < 4; ++r) {
            const int c = cw + mt * 16 + g * 4 + r;
            const size_t rowoff = ((size_t)(b * C_ + c)) * N_ + jb;
#pragma unroll
            for (int nt = 0; nt < 2; ++nt) {
                const int j = nt * 16 + c16;
                float rv = __builtin_nontemporal_load(&R[rowoff + j]);
                __builtin_nontemporal_store(rv + acc[mt][nt][r] * VSCALE_INV,
                                            &out[rowoff + j]);
            }
        }
}

// ---------------------------------------------------------------------------
// Fallback Pass B (unchanged; used when ws small).  Needs bf16 V (Vm) and
// UNSHIFTED l (stats uses sh=0 + atomics when PT==null).
// ---------------------------------------------------------------------------
__global__ __launch_bounds__(512, 4)
void out_kernel(const ushort_t* __restrict__ Kt, const ushort_t* __restrict__ Qt,
                const ushort_t* __restrict__ V, const float* __restrict__ l,
                float* __restrict__ dout) {
    __shared__ ushort_t sQ[64][264];
    __shared__ ushort_t sP[64][264];
    const int tid = threadIdx.x;
    const int w = tid >> 6, lane = tid & 63, g = lane >> 4, c16 = lane & 15;
    const int b = blockIdx.z;
    const int jb = blockIdx.x * 64;
    const int ibase = blockIdx.y * 2048;
    {
        const int jl = tid >> 3, cp = (tid & 7) * 32;
        const ushort_t* src = Qt + ((size_t)(b * N_ + jb + jl)) * C_ + cp;
        uint4 a0 = *(const uint4*)(src);
        uint4 a1 = *(const uint4*)(src + 8);
        uint4 a2 = *(const uint4*)(src + 16);
        uint4 a3 = *(const uint4*)(src + 24);
        *(uint4*)&sQ[jl][cp + 0]  = a0;
        *(uint4*)&sQ[jl][cp + 8]  = a1;
        *(uint4*)&sQ[jl][cp + 16] = a2;
        *(uint4*)&sQ[jl][cp + 24] = a3;
    }
    f32x4 acc[2][4];
#pragma unroll
    for (int mt = 0; mt < 2; ++mt)
#pragma unroll
        for (int nt = 0; nt < 4; ++nt) acc[mt][nt] = (f32x4){0.f, 0.f, 0.f, 0.f};

    const int bw = w * 32;

    for (int ic = 0; ic < 8; ++ic) {
        const int i0 = ibase + ic * 256;
        float rv[2][4];
#pragma unroll
        for (int mt = 0; mt < 2; ++mt) {
            float4 lr = *(const float4*)(l + (size_t)b * N_ + i0 + bw + mt * 16 + g * 4);
            rv[mt][0] = __builtin_amdgcn_logf(lr.x);
            rv[mt][1] = __builtin_amdgcn_logf(lr.y);
            rv[mt][2] = __builtin_amdgcn_logf(lr.z);
            rv[mt][3] = __builtin_amdgcn_logf(lr.w);
        }
        __syncthreads();
        f32x4 sa[2][4];
#pragma unroll
        for (int mt = 0; mt < 2; ++mt)
#pragma unroll
            for (int nt = 0; nt < 4; ++nt) sa[mt][nt] = (f32x4){0.f, 0.f, 0.f, 0.f};
#pragma unroll
        for (int k = 0; k < 8; ++k) {
            bf16x8 av[2];
#pragma unroll
            for (int mt = 0; mt < 2; ++mt)
                av[mt] = ld_bf8(Kt + ((size_t)(b * N_ + i0 + bw + mt * 16 + c16)) * C_ + k * 32 + g * 8);
#pragma unroll
            for (int nt = 0; nt < 4; ++nt) {
                bf16x8 bv = *(const bf16x8*)&sQ[nt * 16 + c16][k * 32 + g * 8];
#pragma unroll
                for (int mt = 0; mt < 2; ++mt)
                    sa[mt][nt] = __builtin_amdgcn_mfma_f32_16x16x32_bf16(av[mt], bv, sa[mt][nt], 0, 0, 0);
            }
        }
#pragma unroll
        for (int mt = 0; mt < 2; ++mt)
#pragma unroll
            for (int nt = 0; nt < 4; ++nt) {
                const int j = nt * 16 + c16;
                unsigned p0 = f2bf(__builtin_amdgcn_exp2f(sa[mt][nt][0] - rv[mt][0]));
                unsigned p1 = f2bf(__builtin_amdgcn_exp2f(sa[mt][nt][1] - rv[mt][1]));
                unsigned p2 = f2bf(__builtin_amdgcn_exp2f(sa[mt][nt][2] - rv[mt][2]));
                unsigned p3 = f2bf(__builtin_amdgcn_exp2f(sa[mt][nt][3] - rv[mt][3]));
                uint2 pk; pk.x = p0 | (p1 << 16); pk.y = p2 | (p3 << 16);
                *(uint2*)&sP[j][bw + mt * 16 + g * 4] = pk;
            }
        __syncthreads();
#pragma unroll
        for (int ks = 0; ks < 8; ++ks) {
            bf16x8 va[2];
#pragma unroll
            for (int mt = 0; mt < 2; ++mt)
                va[mt] = ld_bf8(V + ((size_t)(b * C_ + bw + mt * 16 + c16)) * N_ + i0 + ks * 32 + g * 8);
#pragma unroll
            for (int nt = 0; nt < 4; ++nt) {
                bf16x8 pb = *(const bf16x8*)&sP[nt * 16 + c16][ks * 32 + g * 8];
#pragma unroll
                for (int mt = 0; mt < 2; ++mt)
                    acc[mt][nt] = __builtin_amdgcn_mfma_f32_16x16x32_bf16(va[mt], pb, acc[mt][nt], 0, 0, 0);
            }
        }
    }
#pragma unroll
    for (int mt = 0; mt < 2; ++mt)
#pragma unroll
        for (int nt = 0; nt < 4; ++nt)
#pragma unroll
            for (int r = 0; r < 4; ++r) {
                const int c = bw + mt * 16 + g * 4 + r;
                const int j = jb + nt * 16 + c16;
                atomicAdd(dout + ((size_t)b * C_ + c) * N_ + j, acc[mt][nt][r]);
            }
}

extern "C" void kernel_launch(void* const* d_in, const int* in_sizes, int n_in,
                              void* d_out, int out_size, void* d_ws, size_t ws_size,
                              hipStream_t stream) {
    const float* x_s2  = (const float*)d_in[0];
    const float* x_dem = (const float*)d_in[1];
    const float* Wq = (const float*)d_in[2];
    const float* bq = (const float*)d_in[3];
    const float* Wk = (const float*)d_in[4];
    const float* bk = (const float*)d_in[5];
    const float* Wv = (const float*)d_in[6];
    const float* bv = (const float*)d_in[7];
    float* out = (float*)d_out;

    const size_t MiB = 1024 * 1024;
    char* ws = (char*)d_ws;
    ushort_t* Qt = (ushort_t*)(ws);               // [B][N][C] bf16, 8 MiB
    ushort_t* Kt = (ushort_t*)(ws + 8  * MiB);    // [B][N][C] bf16, pre-scaled
    ushort_t* Vm = (ushort_t*)(ws + 16 * MiB);    // [B][C][N] bf16, 8 MiB
    uchar_t*  Vs = (uchar_t*) (ws + 24 * MiB);    // [B][C][N] fp8 V'', 4 MiB
    float*    lp = (float*)   (ws + 24 * MiB);    // [B][32][N] partials, 2 MiB
                                                  //   (aliases Vs: dead before
                                                  //    scale_v writes Vs)
    float*    lv = (float*)   (ws + 28 * MiB);    // [B][N] row sums, 64 KiB
    uchar_t*  PT = (uchar_t*) (ws + 29 * MiB);    // [B][N(j)][N(i)] fp8, 64 MiB
    const bool bigws = ws_size >= 93 * MiB;

    if (!bigws) {
        // fallback path: atomic l accumulation + residual-prefilled out
        hipMemsetAsync(lv, 0, (size_t)B_ * N_ * sizeof(float), stream);
        hipMemcpyAsync(out, x_s2, (size_t)B_ * C_ * N_ * sizeof(float),
                       hipMemcpyDeviceToDevice, stream);
    }

    proj_q_mfma<<<dim3(N_ / 128, C_ / 64, B_), 256, 0, stream>>>(x_s2, Wq, bq, Qt, C_, 1.0f);
    proj_kv_mfma<<<dim3(N_ / 128, C_ / 64, B_), 256, 0, stream>>>(x_dem, Wk, bk, Wv, bv, Kt, Vm);
    stats_kernel<<<dim3(4096), 256, 0, stream>>>(Kt, Qt, lv,
                                                 bigws ? PT : (uchar_t*)nullptr,
                                                 lp);
    if (bigws) {
        reduce_l_kernel<<<dim3(N_ / 1024, B_), 256, 0, stream>>>(lp, lv);
        scale_v_kernel<<<dim3(N_ / 2048, C_, B_), 256, 0, stream>>>(Vm, lv, Vs);
        gemm_out2_kernel<<<dim3(N_ / 32, B_), 512, 0, stream>>>(Vs, PT, x_s2, out);
    } else {
        out_kernel<<<dim3(N_ / 64, 2, B_), 512, 0, stream>>>(Kt, Qt, Vm, lv, out);
    }
}

// Round 9
// 206.925 us; speedup vs baseline: 1.0504x; 1.0059x over previous
//
#include <hip/hip_runtime.h>
#include <hip/hip_bf16.h>
#include <cstdint>

#define B_  4
#define N_  4096
#define C_  256
#define CD_ 64

typedef unsigned short ushort_t;
typedef unsigned char uchar_t;
typedef __bf16 bf16x8 __attribute__((ext_vector_type(8)));
typedef float f32x4 __attribute__((ext_vector_type(4)));
typedef unsigned int u32x4 __attribute__((ext_vector_type(4)));

typedef const __attribute__((address_space(1))) void* gas_t;
typedef __attribute__((address_space(3))) void* las_t;

// (1/sqrt(256)) * log2(e): folded into K projection so S' = S_true * log2(e)
static constexpr float SCALE_LOG2E = 0.09016844005556021f;
// V' scale 2^13 (undone in gemm epilogue); PT exponent shift -3 cancels via l.
static constexpr float VSCALE = 8192.0f;
static constexpr float VSCALE_INV = 1.0f / 8192.0f;

__device__ __forceinline__ ushort_t f2bf(float x) {
    union { float f; unsigned u; } v; v.f = x;
    unsigned u = v.u;
    unsigned r = (u + 0x7fffu + ((u >> 16) & 1u)) >> 16;  // round-nearest-even
    return (ushort_t)r;
}

__device__ __forceinline__ bf16x8 ld_bf8(const ushort_t* p) {
    return *reinterpret_cast<const bf16x8*>(p);
}

// ---------------------------------------------------------------------------
// MFMA projection -> TRANSPOSED layout dst[b][n][o]  (proven R8)
// ---------------------------------------------------------------------------
__global__ __launch_bounds__(256, 4)
void proj_q_mfma(const float* __restrict__ X, const float* __restrict__ W,
                 const float* __restrict__ bias, ushort_t* __restrict__ dst,
                 int Cin, float outScale) {
    __shared__ ushort_t sX[128][72];   // [n][c] bf16
    __shared__ ushort_t sW[64][72];    // [o][c] bf16
    const int tid = threadIdx.x;
    const int lane = tid & 63, g = lane >> 4, c16 = lane & 15;
    const int w = tid >> 6, wi = w >> 1, wj = w & 1;   // n-half, o-half
    const int b = blockIdx.z, nb = blockIdx.x * 128, ob = blockIdx.y * 64;
    f32x4 acc[4][2];
#pragma unroll
    for (int nt = 0; nt < 4; ++nt)
#pragma unroll
        for (int ot = 0; ot < 2; ++ot) acc[nt][ot] = (f32x4){0.f, 0.f, 0.f, 0.f};

    const int cr = tid >> 5;
    const int n0 = (tid & 31) * 4;

    for (int k0 = 0; k0 < Cin; k0 += 64) {
#pragma unroll
        for (int p = 0; p < 8; ++p) {
            const int c = p * 8 + cr;
            float4 xv = *(const float4*)(X + ((size_t)b * Cin + k0 + c) * N_ + nb + n0);
            sX[n0 + 0][c] = f2bf(xv.x);
            sX[n0 + 1][c] = f2bf(xv.y);
            sX[n0 + 2][c] = f2bf(xv.z);
            sX[n0 + 3][c] = f2bf(xv.w);
        }
        {
            const int o = tid >> 2, cq = (tid & 3) * 16;
            const float* wsrc = W + (size_t)(ob + o) * Cin + k0 + cq;
            alignas(16) ushort_t tmp[16];
#pragma unroll
            for (int q = 0; q < 16; ++q) tmp[q] = f2bf(wsrc[q]);
            *(uint4*)&sW[o][cq]     = *(uint4*)&tmp[0];
            *(uint4*)&sW[o][cq + 8] = *(uint4*)&tmp[8];
        }
        __syncthreads();
#pragma unroll
        for (int ks = 0; ks < 2; ++ks) {
            bf16x8 af[4], bfr[2];
#pragma unroll
            for (int nt = 0; nt < 4; ++nt)
                af[nt] = *(const bf16x8*)&sX[wi * 64 + nt * 16 + c16][ks * 32 + g * 8];
#pragma unroll
            for (int ot = 0; ot < 2; ++ot)
                bfr[ot] = *(const bf16x8*)&sW[wj * 32 + ot * 16 + c16][ks * 32 + g * 8];
#pragma unroll
            for (int nt = 0; nt < 4; ++nt)
#pragma unroll
                for (int ot = 0; ot < 2; ++ot)
                    acc[nt][ot] = __builtin_amdgcn_mfma_f32_16x16x32_bf16(af[nt], bfr[ot], acc[nt][ot], 0, 0, 0);
        }
        __syncthreads();
    }
#pragma unroll
    for (int ot = 0; ot < 2; ++ot) {
        const int o = ob + wj * 32 + ot * 16 + c16;
        const float bia = bias[o];
#pragma unroll
        for (int nt = 0; nt < 4; ++nt) {
#pragma unroll
            for (int r = 0; r < 4; ++r) {
                const int n = nb + wi * 64 + nt * 16 + g * 4 + r;
                dst[((size_t)b * N_ + n) * C_ + o] = f2bf((acc[nt][ot][r] + bia) * outScale);
            }
        }
    }
}

// ---------------------------------------------------------------------------
// Fused K+V MFMA projection from x_dem (proven R8)
// ---------------------------------------------------------------------------
__global__ __launch_bounds__(256, 4)
void proj_kv_mfma(const float* __restrict__ X, const float* __restrict__ Wk,
                  const float* __restrict__ bk, const float* __restrict__ Wv,
                  const float* __restrict__ bv, ushort_t* __restrict__ Kt,
                  ushort_t* __restrict__ Vm) {
    __shared__ ushort_t sX[128][72];   // [n][c]
    __shared__ ushort_t sWk[64][72];   // [o][c]
    __shared__ ushort_t sWv[64][72];
    const int tid = threadIdx.x;
    const int lane = tid & 63, g = lane >> 4, c16 = lane & 15;
    const int w = tid >> 6;
    const int b = blockIdx.z, nb = blockIdx.x * 128, ob = blockIdx.y * 64;

    {
        const int cr = tid >> 5, n0 = (tid & 31) * 4;
#pragma unroll
        for (int p = 0; p < 8; ++p) {
            const int c = p * 8 + cr;
            float4 xv = *(const float4*)(X + ((size_t)b * CD_ + c) * N_ + nb + n0);
            sX[n0 + 0][c] = f2bf(xv.x);
            sX[n0 + 1][c] = f2bf(xv.y);
            sX[n0 + 2][c] = f2bf(xv.z);
            sX[n0 + 3][c] = f2bf(xv.w);
        }
        const int o = tid >> 2, cq = (tid & 3) * 16;
        alignas(16) ushort_t tk[16], tv[16];
        const float* ksrc = Wk + (size_t)(ob + o) * CD_ + cq;
        const float* vsrc = Wv + (size_t)(ob + o) * CD_ + cq;
#pragma unroll
        for (int q = 0; q < 16; ++q) { tk[q] = f2bf(ksrc[q]); tv[q] = f2bf(vsrc[q]); }
        *(uint4*)&sWk[o][cq]     = *(uint4*)&tk[0];
        *(uint4*)&sWk[o][cq + 8] = *(uint4*)&tk[8];
        *(uint4*)&sWv[o][cq]     = *(uint4*)&tv[0];
        *(uint4*)&sWv[o][cq + 8] = *(uint4*)&tv[8];
    }
    __syncthreads();
    // ---- K-part ----
    {
        const int wi = w >> 1, wj = w & 1;
        f32x4 acc[4][2];
#pragma unroll
        for (int nt = 0; nt < 4; ++nt)
#pragma unroll
            for (int ot = 0; ot < 2; ++ot) acc[nt][ot] = (f32x4){0.f, 0.f, 0.f, 0.f};
#pragma unroll
        for (int ks = 0; ks < 2; ++ks) {
            bf16x8 af[4], bfr[2];
#pragma unroll
            for (int nt = 0; nt < 4; ++nt)
                af[nt] = *(const bf16x8*)&sX[wi * 64 + nt * 16 + c16][ks * 32 + g * 8];
#pragma unroll
            for (int ot = 0; ot < 2; ++ot)
                bfr[ot] = *(const bf16x8*)&sWk[wj * 32 + ot * 16 + c16][ks * 32 + g * 8];
#pragma unroll
            for (int nt = 0; nt < 4; ++nt)
#pragma unroll
                for (int ot = 0; ot < 2; ++ot)
                    acc[nt][ot] = __builtin_amdgcn_mfma_f32_16x16x32_bf16(af[nt], bfr[ot], acc[nt][ot], 0, 0, 0);
        }
#pragma unroll
        for (int ot = 0; ot < 2; ++ot) {
            const int o = ob + wj * 32 + ot * 16 + c16;
            const float bia = bk[o];
#pragma unroll
            for (int nt = 0; nt < 4; ++nt)
#pragma unroll
                for (int r = 0; r < 4; ++r) {
                    const int n = nb + wi * 64 + nt * 16 + g * 4 + r;
                    Kt[((size_t)b * N_ + n) * C_ + o] = f2bf((acc[nt][ot][r] + bia) * SCALE_LOG2E);
                }
        }
    }
    // ---- V-part ----
    {
        const int ow = w & 1, nw = w >> 1;
        f32x4 acc[2][4];
#pragma unroll
        for (int mt = 0; mt < 2; ++mt)
#pragma unroll
            for (int nt = 0; nt < 4; ++nt) acc[mt][nt] = (f32x4){0.f, 0.f, 0.f, 0.f};
#pragma unroll
        for (int ks = 0; ks < 2; ++ks) {
            bf16x8 af[2], bfr[4];
#pragma unroll
            for (int mt = 0; mt < 2; ++mt)
                af[mt] = *(const bf16x8*)&sWv[ow * 32 + mt * 16 + c16][ks * 32 + g * 8];
#pragma unroll
            for (int nt = 0; nt < 4; ++nt)
                bfr[nt] = *(const bf16x8*)&sX[nw * 64 + nt * 16 + c16][ks * 32 + g * 8];
#pragma unroll
            for (int mt = 0; mt < 2; ++mt)
#pragma unroll
                for (int nt = 0; nt < 4; ++nt)
                    acc[mt][nt] = __builtin_amdgcn_mfma_f32_16x16x32_bf16(af[mt], bfr[nt], acc[mt][nt], 0, 0, 0);
        }
#pragma unroll
        for (int mt = 0; mt < 2; ++mt) {
            const float4 bi4 = *(const float4*)(bv + ob + ow * 32 + mt * 16 + g * 4);
            const float bia[4] = {bi4.x, bi4.y, bi4.z, bi4.w};
#pragma unroll
            for (int nt = 0; nt < 4; ++nt) {
                const int n = nb + nw * 64 + nt * 16 + c16;
#pragma unroll
                for (int r = 0; r < 4; ++r) {
                    const int o = ob + ow * 32 + mt * 16 + g * 4 + r;
                    Vm[((size_t)b * C_ + o) * N_ + n] = f2bf(acc[mt][nt][r] + bia[r]);
                }
            }
        }
    }
}

// ---------------------------------------------------------------------------
// Pass A v9 (R21): REVERT to R4's plain 2D grid — best measured composition
// (204.9 us total).  R6/R8's XCD supertile swizzle cut FETCH 36.9->24.6 MB
// but was time-null-to-negative (208.1 twice vs 204.9): stats is at the
// 2-phase structural floor (m233), not fetch-latency-bound, and the
// supertile decode perturbs dispatch locality.  Keeps: BK=32 dbuf loop (R4),
// NT PT streamout (R4: WRITE at 67.6 MB ideal), non-atomic lpart (R1).
// ---------------------------------------------------------------------------
__global__ __launch_bounds__(256, 4)
void stats_kernel(const ushort_t* __restrict__ Kt, const ushort_t* __restrict__ Qt,
                  float* __restrict__ l, uchar_t* __restrict__ PT8,
                  float* __restrict__ lpart) {
    __shared__ ushort_t smem[16384];   // 32 KB: buf t at (t&1)*16K: A 8K + B 8K
    uchar_t* smem8 = (uchar_t*)smem;
    uchar_t* sp8 = smem8;                      // epilogue: [128][144] fp8 tile
    float* lsum = (float*)(smem8 + 18432);     // [2][128] row partials
    const int tid = threadIdx.x;
    const int lane = tid & 63, g = lane >> 4, c16 = lane & 15;
    const int w = tid >> 6, wi = w >> 1, wj = w & 1;
    const int b = blockIdx.z;
    const int ib = blockIdx.y * 128, jb = blockIdx.x * 128;
    f32x4 acc[4][4];
#pragma unroll
    for (int mt = 0; mt < 4; ++mt)
#pragma unroll
        for (int nt = 0; nt < 4; ++nt) acc[mt][nt] = (f32x4){0.f, 0.f, 0.f, 0.f};

    const int srow = tid >> 2;   // 0..63 (row within 64-row half)
    const int sc = tid & 3;      // 16B chunk slot within 64B row

    auto stage = [&](int kc, int dbase) {      // kc: 32-wide K chunk index
#pragma unroll
        for (int q = 0; q < 2; ++q) {
            const int row = q * 64 + srow;
            const int gc = sc ^ ((row >> 1) & 3);
            const ushort_t* srcA = Kt + ((size_t)(b * N_ + ib + row)) * C_ + kc * 32 + gc * 8;
            const ushort_t* srcB = Qt + ((size_t)(b * N_ + jb + row)) * C_ + kc * 32 + gc * 8;
            __builtin_amdgcn_global_load_lds((gas_t)srcA, (las_t)&smem8[dbase + (q * 256 + tid) * 16], 16, 0, 0);
            __builtin_amdgcn_global_load_lds((gas_t)srcB, (las_t)&smem8[dbase + 8192 + (q * 256 + tid) * 16], 16, 0, 0);
        }
    };

    stage(0, 0);
    __syncthreads();                 // pipeline fill
    for (int t = 0; t < 8; ++t) {
        const int dbase = (t & 1) * 16384;
        if (t < 7) stage(t + 1, 16384 - dbase);   // prefetch other buf
        bf16x8 af[4], bf[4];
#pragma unroll
        for (int mt = 0; mt < 4; ++mt) {
            const int row = wi * 64 + mt * 16 + c16;
            af[mt] = *(const bf16x8*)&smem8[dbase + row * 64 + ((g ^ ((row >> 1) & 3)) * 16)];
        }
#pragma unroll
        for (int nt = 0; nt < 4; ++nt) {
            const int row = wj * 64 + nt * 16 + c16;
            bf[nt] = *(const bf16x8*)&smem8[dbase + 8192 + row * 64 + ((g ^ ((row >> 1) & 3)) * 16)];
        }
#pragma unroll
        for (int mt = 0; mt < 4; ++mt)
#pragma unroll
            for (int nt = 0; nt < 4; ++nt)
                acc[mt][nt] = __builtin_amdgcn_mfma_f32_16x16x32_bf16(af[mt], bf[nt], acc[mt][nt], 0, 0, 0);
        __syncthreads();   // waits prefetch (vmcnt) + frees buf for next stage
    }
    const float sh = (PT8 != nullptr) ? 3.0f : 0.0f;
#pragma unroll
    for (int mt = 0; mt < 4; ++mt) {
        float rs[4] = {0.f, 0.f, 0.f, 0.f};
#pragma unroll
        for (int nt = 0; nt < 4; ++nt) {
            float e0 = __builtin_amdgcn_exp2f(acc[mt][nt][0] - sh);
            float e1 = __builtin_amdgcn_exp2f(acc[mt][nt][1] - sh);
            float e2 = __builtin_amdgcn_exp2f(acc[mt][nt][2] - sh);
            float e3 = __builtin_amdgcn_exp2f(acc[mt][nt][3] - sh);
            rs[0] += e0; rs[1] += e1; rs[2] += e2; rs[3] += e3;
            if (PT8 != nullptr) {
                int pk = __builtin_amdgcn_cvt_pk_fp8_f32(e0, e1, 0, false);
                pk = __builtin_amdgcn_cvt_pk_fp8_f32(e2, e3, pk, true);
                const int jl = wj * 64 + nt * 16 + c16;
                const int il = wi * 64 + mt * 16 + g * 4;
                *(int*)&sp8[jl * 144 + il] = pk;
            }
        }
#pragma unroll
        for (int r = 0; r < 4; ++r) {
            float s = rs[r];
            s += __shfl_xor(s, 1, 64);
            s += __shfl_xor(s, 2, 64);
            s += __shfl_xor(s, 4, 64);
            s += __shfl_xor(s, 8, 64);
            if (c16 == 0) {
                if (PT8 != nullptr)
                    lsum[wj * 128 + wi * 64 + mt * 16 + g * 4 + r] = s;
                else
                    atomicAdd(l + (size_t)b * N_ + ib + wi * 64 + mt * 16 + g * 4 + r, s);
            }
        }
    }
    if (PT8 != nullptr) {
        __syncthreads();
        // stream out: 128 rows x 128 B (fp8), NONTEMPORAL (bypass L2 pollution)
        const int chb = tid & 7;     // 16B chunk within row
        const int rb = tid >> 3;     // 32 rows per pass
#pragma unroll
        for (int r = 0; r < 4; ++r) {
            const int jl = r * 32 + rb;
            u32x4 v = *(const u32x4*)&sp8[jl * 144 + chb * 16];
            __builtin_nontemporal_store(v,
                (u32x4*)(PT8 + ((size_t)(b * N_ + jb + jl)) * N_ + ib + chb * 16));
        }
        // per-block row-sum partial: one coalesced 512 B store, no atomics
        if (tid < 128) {
            float tot = lsum[tid] + lsum[128 + tid];
            lpart[((size_t)(b * 32 + (jb >> 7))) * N_ + ib + tid] = tot;
        }
    }
}

// ---------------------------------------------------------------------------
// l[b][i] = sum_jt lpart[b][jt][i]  (2 MB read, 64 KB write, ~1-2 us)
// grid (N/1024, B), block 256, float4 per thread.
// ---------------------------------------------------------------------------
__global__ void reduce_l_kernel(const float* __restrict__ lpart, float* __restrict__ l) {
    const int b = blockIdx.y;
    const int i = (blockIdx.x * 256 + threadIdx.x) * 4;
    float4 s = {0.f, 0.f, 0.f, 0.f};
#pragma unroll
    for (int jt = 0; jt < 32; ++jt) {
        float4 p = *(const float4*)(lpart + ((size_t)(b * 32 + jt)) * N_ + i);
        s.x += p.x; s.y += p.y; s.z += p.z; s.w += p.w;
    }
    *(float4*)(l + (size_t)b * N_ + i) = s;
}

// ---------------------------------------------------------------------------
// V'' = V * 2^13 * rcp(l') -> fp8 e4m3.  grid (N/2048, C, B), block 256.
// ---------------------------------------------------------------------------
__global__ void scale_v_kernel(const ushort_t* __restrict__ Vm, const float* __restrict__ l,
                               uchar_t* __restrict__ Vs) {
    const int i = (blockIdx.x * 256 + threadIdx.x) * 8;
    const int c = blockIdx.y, b = blockIdx.z;
    float4 l0 = *(const float4*)(l + (size_t)b * N_ + i);
    float4 l1 = *(const float4*)(l + (size_t)b * N_ + i + 4);
    float r[8] = {__builtin_amdgcn_rcpf(l0.x), __builtin_amdgcn_rcpf(l0.y),
                  __builtin_amdgcn_rcpf(l0.z), __builtin_amdgcn_rcpf(l0.w),
                  __builtin_amdgcn_rcpf(l1.x), __builtin_amdgcn_rcpf(l1.y),
                  __builtin_amdgcn_rcpf(l1.z), __builtin_amdgcn_rcpf(l1.w)};
    const size_t off = ((size_t)(b * C_ + c)) * N_ + i;
    uint4 v = *(const uint4*)(Vm + off);
    unsigned vw[4] = {v.x, v.y, v.z, v.w};
    float f[8];
#pragma unroll
    for (int q = 0; q < 4; ++q) {
        union { unsigned u; float fl; } lo, hi;
        lo.u = (vw[q] & 0xffffu) << 16;
        hi.u = vw[q] & 0xffff0000u;
        f[q * 2 + 0] = lo.fl * r[q * 2 + 0] * VSCALE;
        f[q * 2 + 1] = hi.fl * r[q * 2 + 1] * VSCALE;
    }
    int d0 = __builtin_amdgcn_cvt_pk_fp8_f32(f[0], f[1], 0, false);
    d0 = __builtin_amdgcn_cvt_pk_fp8_f32(f[2], f[3], d0, true);
    int d1 = __builtin_amdgcn_cvt_pk_fp8_f32(f[4], f[5], 0, false);
    d1 = __builtin_amdgcn_cvt_pk_fp8_f32(f[6], f[7], d1, true);
    uint2 o; o.x = (unsigned)d0; o.y = (unsigned)d1;
    *(uint2*)(Vs + off) = o;
}

// ---------------------------------------------------------------------------
// Pass B v11 (kept): fp8 single-K GEMM, double-buffered staging, NT fp32
// streams (R4-verified), PT staging CPol NT (R8: neutral, harmless).
// ---------------------------------------------------------------------------
__global__ __launch_bounds__(512, 4)
void gemm_out2_kernel(const uchar_t* __restrict__ A /*Vs fp8 [B][C][N]*/,
                      const uchar_t* __restrict__ Bm /*PT fp8 [B][N][N]*/,
                      const float* __restrict__ R /*x_s2 as [B][C][N]*/,
                      float* __restrict__ out) {
    __shared__ uchar_t smem[73728];   // 2 x (32 KB A + 4 KB B)
    const int tid = threadIdx.x;
    const int lane = tid & 63, g = lane >> 4, c16 = lane & 15;
    const int w = tid >> 6;
    const int cw = w * 32;              // wave's 32-c band
    const int b = blockIdx.y;
    const int jb = blockIdx.x * 32;

    f32x4 acc[2][2];
#pragma unroll
    for (int mt = 0; mt < 2; ++mt)
#pragma unroll
        for (int nt = 0; nt < 2; ++nt) acc[mt][nt] = (f32x4){0.f, 0.f, 0.f, 0.f};

    const int sch = tid & 7;          // chunk slot within row

    auto stage = [&](int k0, int dbase) {
        // stage A (Vs): 256 rows x 8 chunks = 2048 slots, 4 passes
#pragma unroll
        for (int q = 0; q < 4; ++q) {
            const int slot = q * 512 + tid;
            const int row = slot >> 3;
            const int gc = sch ^ (row & 7);
            const uchar_t* src = A + ((size_t)(b * C_ + row)) * N_ + k0 + gc * 16;
            __builtin_amdgcn_global_load_lds((gas_t)src, (las_t)&smem[dbase + slot * 16], 16, 0, 0);
        }
        // stage B (PT): 32 rows x 8 chunks = 256 slots (threads 0..255)
        // aux=2 -> CPol NT: read-once stream, evict-first
        if (tid < 256) {
            const int row = tid >> 3;
            const int gc = sch ^ (row & 7);
            const uchar_t* src = Bm + ((size_t)(b * N_ + jb + row)) * N_ + k0 + gc * 16;
            __builtin_amdgcn_global_load_lds((gas_t)src, (las_t)&smem[dbase + 32768 + tid * 16], 16, 0, 2);
        }
    };

    stage(0, 0);
    __syncthreads();                     // pipeline fill
    for (int t = 0; t < 32; ++t) {
        const int dbase = (t & 1) * 36864;
        if (t < 31) stage((t + 1) * 128, 36864 - dbase);   // prefetch other buf
        const uchar_t* sA = &smem[dbase];
        const uchar_t* sB = &smem[dbase + 32768];
#pragma unroll
        for (int ks = 0; ks < 4; ++ks) {    // 4 x K=32
            const int lc = ks * 2 + (g >> 1);       // logical 16B chunk
            const int bo = (g & 1) * 8;             // byte within chunk
            long af[2], bfg[2];
#pragma unroll
            for (int mt = 0; mt < 2; ++mt) {
                const int row = cw + mt * 16 + c16;
                af[mt] = *(const long*)&sA[row * 128 + ((lc ^ (row & 7)) * 16) + bo];
            }
#pragma unroll
            for (int nt = 0; nt < 2; ++nt) {
                const int row = nt * 16 + c16;
                bfg[nt] = *(const long*)&sB[row * 128 + ((lc ^ (row & 7)) * 16) + bo];
            }
#pragma unroll
            for (int mt = 0; mt < 2; ++mt)
#pragma unroll
                for (int nt = 0; nt < 2; ++nt)
                    acc[mt][nt] = __builtin_amdgcn_mfma_f32_16x16x32_fp8_fp8(af[mt], bfg[nt], acc[mt][nt], 0, 0, 0);
        }
        __syncthreads();   // waits prefetch + frees buf for next stage
    }
    // epilogue: out = residual + acc * 2^-13 (nontemporal fp32 stream)
#pragma unroll
    for (int mt = 0; mt < 2; ++mt)
#pragma unroll
        for (int r = 0; r < 4; ++r) {
            const int c = cw + mt * 16 + g * 4 + r;
            const size_t rowoff = ((size_t)(b * C_ + c)) * N_ + jb;
#pragma unroll
            for (int nt = 0; nt < 2; ++nt) {
                const int j = nt * 16 + c16;
                float rv = __builtin_nontemporal_load(&R[rowoff + j]);
                __builtin_nontemporal_store(rv + acc[mt][nt][r] * VSCALE_INV,
                                            &out[rowoff + j]);
            }
        }
}

// ---------------------------------------------------------------------------
// Fallback Pass B (unchanged; used when ws small).  Needs bf16 V (Vm) and
// UNSHIFTED l (stats uses sh=0 + atomics when PT==null).
// ---------------------------------------------------------------------------
__global__ __launch_bounds__(512, 4)
void out_kernel(const ushort_t* __restrict__ Kt, const ushort_t* __restrict__ Qt,
                const ushort_t* __restrict__ V, const float* __restrict__ l,
                float* __restrict__ dout) {
    __shared__ ushort_t sQ[64][264];
    __shared__ ushort_t sP[64][264];
    const int tid = threadIdx.x;
    const int w = tid >> 6, lane = tid & 63, g = lane >> 4, c16 = lane & 15;
    const int b = blockIdx.z;
    const int jb = blockIdx.x * 64;
    const int ibase = blockIdx.y * 2048;
    {
        const int jl = tid >> 3, cp = (tid & 7) * 32;
        const ushort_t* src = Qt + ((size_t)(b * N_ + jb + jl)) * C_ + cp;
        uint4 a0 = *(const uint4*)(src);
        uint4 a1 = *(const uint4*)(src + 8);
        uint4 a2 = *(const uint4*)(src + 16);
        uint4 a3 = *(const uint4*)(src + 24);
        *(uint4*)&sQ[jl][cp + 0]  = a0;
        *(uint4*)&sQ[jl][cp + 8]  = a1;
        *(uint4*)&sQ[jl][cp + 16] = a2;
        *(uint4*)&sQ[jl][cp + 24] = a3;
    }
    f32x4 acc[2][4];
#pragma unroll
    for (int mt = 0; mt < 2; ++mt)
#pragma unroll
        for (int nt = 0; nt < 4; ++nt) acc[mt][nt] = (f32x4){0.f, 0.f, 0.f, 0.f};

    const int bw = w * 32;

    for (int ic = 0; ic < 8; ++ic) {
        const int i0 = ibase + ic * 256;
        float rv[2][4];
#pragma unroll
        for (int mt = 0; mt < 2; ++mt) {
            float4 lr = *(const float4*)(l + (size_t)b * N_ + i0 + bw + mt * 16 + g * 4);
            rv[mt][0] = __builtin_amdgcn_logf(lr.x);
            rv[mt][1] = __builtin_amdgcn_logf(lr.y);
            rv[mt][2] = __builtin_amdgcn_logf(lr.z);
            rv[mt][3] = __builtin_amdgcn_logf(lr.w);
        }
        __syncthreads();
        f32x4 sa[2][4];
#pragma unroll
        for (int mt = 0; mt < 2; ++mt)
#pragma unroll
            for (int nt = 0; nt < 4; ++nt) sa[mt][nt] = (f32x4){0.f, 0.f, 0.f, 0.f};
#pragma unroll
        for (int k = 0; k < 8; ++k) {
            bf16x8 av[2];
#pragma unroll
            for (int mt = 0; mt < 2; ++mt)
                av[mt] = ld_bf8(Kt + ((size_t)(b * N_ + i0 + bw + mt * 16 + c16)) * C_ + k * 32 + g * 8);
#pragma unroll
            for (int nt = 0; nt < 4; ++nt) {
                bf16x8 bv = *(const bf16x8*)&sQ[nt * 16 + c16][k * 32 + g * 8];
#pragma unroll
                for (int mt = 0; mt < 2; ++mt)
                    sa[mt][nt] = __builtin_amdgcn_mfma_f32_16x16x32_bf16(av[mt], bv, sa[mt][nt], 0, 0, 0);
            }
        }
#pragma unroll
        for (int mt = 0; mt < 2; ++mt)
#pragma unroll
            for (int nt = 0; nt < 4; ++nt) {
                const int j = nt * 16 + c16;
                unsigned p0 = f2bf(__builtin_amdgcn_exp2f(sa[mt][nt][0] - rv[mt][0]));
                unsigned p1 = f2bf(__builtin_amdgcn_exp2f(sa[mt][nt][1] - rv[mt][1]));
                unsigned p2 = f2bf(__builtin_amdgcn_exp2f(sa[mt][nt][2] - rv[mt][2]));
                unsigned p3 = f2bf(__builtin_amdgcn_exp2f(sa[mt][nt][3] - rv[mt][3]));
                uint2 pk; pk.x = p0 | (p1 << 16); pk.y = p2 | (p3 << 16);
                *(uint2*)&sP[j][bw + mt * 16 + g * 4] = pk;
            }
        __syncthreads();
#pragma unroll
        for (int ks = 0; ks < 8; ++ks) {
            bf16x8 va[2];
#pragma unroll
            for (int mt = 0; mt < 2; ++mt)
                va[mt] = ld_bf8(V + ((size_t)(b * C_ + bw + mt * 16 + c16)) * N_ + i0 + ks * 32 + g * 8);
#pragma unroll
            for (int nt = 0; nt < 4; ++nt) {
                bf16x8 pb = *(const bf16x8*)&sP[nt * 16 + c16][ks * 32 + g * 8];
#pragma unroll
                for (int mt = 0; mt < 2; ++mt)
                    acc[mt][nt] = __builtin_amdgcn_mfma_f32_16x16x32_bf16(va[mt], pb, acc[mt][nt], 0, 0, 0);
            }
        }
    }
#pragma unroll
    for (int mt = 0; mt < 2; ++mt)
#pragma unroll
        for (int nt = 0; nt < 4; ++nt)
#pragma unroll
            for (int r = 0; r < 4; ++r) {
                const int c = bw + mt * 16 + g * 4 + r;
                const int j = jb + nt * 16 + c16;
                atomicAdd(dout + ((size_t)b * C_ + c) * N_ + j, acc[mt][nt][r]);
            }
}

extern "C" void kernel_launch(void* const* d_in, const int* in_sizes, int n_in,
                              void* d_out, int out_size, void* d_ws, size_t ws_size,
                              hipStream_t stream) {
    const float* x_s2  = (const float*)d_in[0];
    const float* x_dem = (const float*)d_in[1];
    const float* Wq = (const float*)d_in[2];
    const float* bq = (const float*)d_in[3];
    const float* Wk = (const float*)d_in[4];
    const float* bk = (const float*)d_in[5];
    const float* Wv = (const float*)d_in[6];
    const float* bv = (const float*)d_in[7];
    float* out = (float*)d_out;

    const size_t MiB = 1024 * 1024;
    char* ws = (char*)d_ws;
    ushort_t* Qt = (ushort_t*)(ws);               // [B][N][C] bf16, 8 MiB
    ushort_t* Kt = (ushort_t*)(ws + 8  * MiB);    // [B][N][C] bf16, pre-scaled
    ushort_t* Vm = (ushort_t*)(ws + 16 * MiB);    // [B][C][N] bf16, 8 MiB
    uchar_t*  Vs = (uchar_t*) (ws + 24 * MiB);    // [B][C][N] fp8 V'', 4 MiB
    float*    lp = (float*)   (ws + 24 * MiB);    // [B][32][N] partials, 2 MiB
                                                  //   (aliases Vs: dead before
                                                  //    scale_v writes Vs)
    float*    lv = (float*)   (ws + 28 * MiB);    // [B][N] row sums, 64 KiB
    uchar_t*  PT = (uchar_t*) (ws + 29 * MiB);    // [B][N(j)][N(i)] fp8, 64 MiB
    const bool bigws = ws_size >= 93 * MiB;

    if (!bigws) {
        // fallback path: atomic l accumulation + residual-prefilled out
        hipMemsetAsync(lv, 0, (size_t)B_ * N_ * sizeof(float), stream);
        hipMemcpyAsync(out, x_s2, (size_t)B_ * C_ * N_ * sizeof(float),
                       hipMemcpyDeviceToDevice, stream);
    }

    proj_q_mfma<<<dim3(N_ / 128, C_ / 64, B_), 256, 0, stream>>>(x_s2, Wq, bq, Qt, C_, 1.0f);
    proj_kv_mfma<<<dim3(N_ / 128, C_ / 64, B_), 256, 0, stream>>>(x_dem, Wk, bk, Wv, bv, Kt, Vm);
    stats_kernel<<<dim3(N_ / 128, N_ / 128, B_), 256, 0, stream>>>(Kt, Qt, lv,
                                                                   bigws ? PT : (uchar_t*)nullptr,
                                                                   lp);
    if (bigws) {
        reduce_l_kernel<<<dim3(N_ / 1024, B_), 256, 0, stream>>>(lp, lv);
        scale_v_kernel<<<dim3(N_ / 2048, C_, B_), 256, 0, stream>>>(Vm, lv, Vs);
        gemm_out2_kernel<<<dim3(N_ / 32, B_), 512, 0, stream>>>(Vs, PT, x_s2, out);
    } else {
        out_kernel<<<dim3(N_ / 64, 2, B_), 512, 0, stream>>>(Kt, Qt, Vm, lv, out);
    }
}

// Round 10
// 198.658 us; speedup vs baseline: 1.0941x; 1.0416x over previous
//
#include <hip/hip_runtime.h>
#include <hip/hip_bf16.h>
#include <cstdint>

#define B_  4
#define N_  4096
#define C_  256
#define CD_ 64

typedef unsigned short ushort_t;
typedef unsigned char uchar_t;
typedef __bf16 bf16x8 __attribute__((ext_vector_type(8)));
typedef float f32x4 __attribute__((ext_vector_type(4)));
typedef unsigned int u32x4 __attribute__((ext_vector_type(4)));

typedef const __attribute__((address_space(1))) void* gas_t;
typedef __attribute__((address_space(3))) void* las_t;

// (1/sqrt(256)) * log2(e): folded into K projection so S' = S_true * log2(e)
static constexpr float SCALE_LOG2E = 0.09016844005556021f;
// R22 fp8 split: K' = k*(log2e/4), Q' = q/4  ->  K'.Q' = k.q*log2e/16 exactly.
static constexpr float SCALE_K8 = 0.3606737602222408f;   // log2e/4
static constexpr float SCALE_Q8 = 0.25f;
// V' scale 2^13 (undone in gemm epilogue); PT exponent shift -3 cancels via l.
static constexpr float VSCALE = 8192.0f;
static constexpr float VSCALE_INV = 1.0f / 8192.0f;

__device__ __forceinline__ ushort_t f2bf(float x) {
    union { float f; unsigned u; } v; v.f = x;
    unsigned u = v.u;
    unsigned r = (u + 0x7fffu + ((u >> 16) & 1u)) >> 16;  // round-nearest-even
    return (ushort_t)r;
}

__device__ __forceinline__ uchar_t f2fp8(float x) {
    return (uchar_t)(__builtin_amdgcn_cvt_pk_fp8_f32(x, x, 0, false) & 0xff);
}

__device__ __forceinline__ bf16x8 ld_bf8(const ushort_t* p) {
    return *reinterpret_cast<const bf16x8*>(p);
}

// ---------------------------------------------------------------------------
// MFMA projection -> TRANSPOSED layout (proven R8).  R22: when dst8 != null
// (big-ws path) the epilogue emits fp8 e4m3 at scale 0.25 (Q' = q/4) for the
// fp8 QK^T; bf16 path kept verbatim for the fallback.
// ---------------------------------------------------------------------------
__global__ __launch_bounds__(256, 4)
void proj_q_mfma(const float* __restrict__ X, const float* __restrict__ W,
                 const float* __restrict__ bias, ushort_t* __restrict__ dst,
                 uchar_t* __restrict__ dst8, int Cin) {
    __shared__ ushort_t sX[128][72];   // [n][c] bf16
    __shared__ ushort_t sW[64][72];    // [o][c] bf16
    const int tid = threadIdx.x;
    const int lane = tid & 63, g = lane >> 4, c16 = lane & 15;
    const int w = tid >> 6, wi = w >> 1, wj = w & 1;   // n-half, o-half
    const int b = blockIdx.z, nb = blockIdx.x * 128, ob = blockIdx.y * 64;
    f32x4 acc[4][2];
#pragma unroll
    for (int nt = 0; nt < 4; ++nt)
#pragma unroll
        for (int ot = 0; ot < 2; ++ot) acc[nt][ot] = (f32x4){0.f, 0.f, 0.f, 0.f};

    const int cr = tid >> 5;
    const int n0 = (tid & 31) * 4;

    for (int k0 = 0; k0 < Cin; k0 += 64) {
#pragma unroll
        for (int p = 0; p < 8; ++p) {
            const int c = p * 8 + cr;
            float4 xv = *(const float4*)(X + ((size_t)b * Cin + k0 + c) * N_ + nb + n0);
            sX[n0 + 0][c] = f2bf(xv.x);
            sX[n0 + 1][c] = f2bf(xv.y);
            sX[n0 + 2][c] = f2bf(xv.z);
            sX[n0 + 3][c] = f2bf(xv.w);
        }
        {
            const int o = tid >> 2, cq = (tid & 3) * 16;
            const float* wsrc = W + (size_t)(ob + o) * Cin + k0 + cq;
            alignas(16) ushort_t tmp[16];
#pragma unroll
            for (int q = 0; q < 16; ++q) tmp[q] = f2bf(wsrc[q]);
            *(uint4*)&sW[o][cq]     = *(uint4*)&tmp[0];
            *(uint4*)&sW[o][cq + 8] = *(uint4*)&tmp[8];
        }
        __syncthreads();
#pragma unroll
        for (int ks = 0; ks < 2; ++ks) {
            bf16x8 af[4], bfr[2];
#pragma unroll
            for (int nt = 0; nt < 4; ++nt)
                af[nt] = *(const bf16x8*)&sX[wi * 64 + nt * 16 + c16][ks * 32 + g * 8];
#pragma unroll
            for (int ot = 0; ot < 2; ++ot)
                bfr[ot] = *(const bf16x8*)&sW[wj * 32 + ot * 16 + c16][ks * 32 + g * 8];
#pragma unroll
            for (int nt = 0; nt < 4; ++nt)
#pragma unroll
                for (int ot = 0; ot < 2; ++ot)
                    acc[nt][ot] = __builtin_amdgcn_mfma_f32_16x16x32_bf16(af[nt], bfr[ot], acc[nt][ot], 0, 0, 0);
        }
        __syncthreads();
    }
#pragma unroll
    for (int ot = 0; ot < 2; ++ot) {
        const int o = ob + wj * 32 + ot * 16 + c16;
        const float bia = bias[o];
#pragma unroll
        for (int nt = 0; nt < 4; ++nt) {
#pragma unroll
            for (int r = 0; r < 4; ++r) {
                const int n = nb + wi * 64 + nt * 16 + g * 4 + r;
                const float v = acc[nt][ot][r] + bia;
                if (dst8 != nullptr)
                    dst8[((size_t)b * N_ + n) * C_ + o] = f2fp8(v * SCALE_Q8);
                else
                    dst[((size_t)b * N_ + n) * C_ + o] = f2bf(v);
            }
        }
    }
}

// ---------------------------------------------------------------------------
// Fused K+V MFMA projection from x_dem (proven R8).  R22: when Kt8 != null
// the K-part emits fp8 at scale log2e/4; V always bf16 (scale_v + fallback).
// ---------------------------------------------------------------------------
__global__ __launch_bounds__(256, 4)
void proj_kv_mfma(const float* __restrict__ X, const float* __restrict__ Wk,
                  const float* __restrict__ bk, const float* __restrict__ Wv,
                  const float* __restrict__ bv, ushort_t* __restrict__ Kt,
                  uchar_t* __restrict__ Kt8, ushort_t* __restrict__ Vm) {
    __shared__ ushort_t sX[128][72];   // [n][c]
    __shared__ ushort_t sWk[64][72];   // [o][c]
    __shared__ ushort_t sWv[64][72];
    const int tid = threadIdx.x;
    const int lane = tid & 63, g = lane >> 4, c16 = lane & 15;
    const int w = tid >> 6;
    const int b = blockIdx.z, nb = blockIdx.x * 128, ob = blockIdx.y * 64;

    {
        const int cr = tid >> 5, n0 = (tid & 31) * 4;
#pragma unroll
        for (int p = 0; p < 8; ++p) {
            const int c = p * 8 + cr;
            float4 xv = *(const float4*)(X + ((size_t)b * CD_ + c) * N_ + nb + n0);
            sX[n0 + 0][c] = f2bf(xv.x);
            sX[n0 + 1][c] = f2bf(xv.y);
            sX[n0 + 2][c] = f2bf(xv.z);
            sX[n0 + 3][c] = f2bf(xv.w);
        }
        const int o = tid >> 2, cq = (tid & 3) * 16;
        alignas(16) ushort_t tk[16], tv[16];
        const float* ksrc = Wk + (size_t)(ob + o) * CD_ + cq;
        const float* vsrc = Wv + (size_t)(ob + o) * CD_ + cq;
#pragma unroll
        for (int q = 0; q < 16; ++q) { tk[q] = f2bf(ksrc[q]); tv[q] = f2bf(vsrc[q]); }
        *(uint4*)&sWk[o][cq]     = *(uint4*)&tk[0];
        *(uint4*)&sWk[o][cq + 8] = *(uint4*)&tk[8];
        *(uint4*)&sWv[o][cq]     = *(uint4*)&tv[0];
        *(uint4*)&sWv[o][cq + 8] = *(uint4*)&tv[8];
    }
    __syncthreads();
    // ---- K-part ----
    {
        const int wi = w >> 1, wj = w & 1;
        f32x4 acc[4][2];
#pragma unroll
        for (int nt = 0; nt < 4; ++nt)
#pragma unroll
            for (int ot = 0; ot < 2; ++ot) acc[nt][ot] = (f32x4){0.f, 0.f, 0.f, 0.f};
#pragma unroll
        for (int ks = 0; ks < 2; ++ks) {
            bf16x8 af[4], bfr[2];
#pragma unroll
            for (int nt = 0; nt < 4; ++nt)
                af[nt] = *(const bf16x8*)&sX[wi * 64 + nt * 16 + c16][ks * 32 + g * 8];
#pragma unroll
            for (int ot = 0; ot < 2; ++ot)
                bfr[ot] = *(const bf16x8*)&sWk[wj * 32 + ot * 16 + c16][ks * 32 + g * 8];
#pragma unroll
            for (int nt = 0; nt < 4; ++nt)
#pragma unroll
                for (int ot = 0; ot < 2; ++ot)
                    acc[nt][ot] = __builtin_amdgcn_mfma_f32_16x16x32_bf16(af[nt], bfr[ot], acc[nt][ot], 0, 0, 0);
        }
#pragma unroll
        for (int ot = 0; ot < 2; ++ot) {
            const int o = ob + wj * 32 + ot * 16 + c16;
            const float bia = bk[o];
#pragma unroll
            for (int nt = 0; nt < 4; ++nt)
#pragma unroll
                for (int r = 0; r < 4; ++r) {
                    const int n = nb + wi * 64 + nt * 16 + g * 4 + r;
                    const float v = acc[nt][ot][r] + bia;
                    if (Kt8 != nullptr)
                        Kt8[((size_t)b * N_ + n) * C_ + o] = f2fp8(v * SCALE_K8);
                    else
                        Kt[((size_t)b * N_ + n) * C_ + o] = f2bf(v * SCALE_LOG2E);
                }
        }
    }
    // ---- V-part ----
    {
        const int ow = w & 1, nw = w >> 1;
        f32x4 acc[2][4];
#pragma unroll
        for (int mt = 0; mt < 2; ++mt)
#pragma unroll
            for (int nt = 0; nt < 4; ++nt) acc[mt][nt] = (f32x4){0.f, 0.f, 0.f, 0.f};
#pragma unroll
        for (int ks = 0; ks < 2; ++ks) {
            bf16x8 af[2], bfr[4];
#pragma unroll
            for (int mt = 0; mt < 2; ++mt)
                af[mt] = *(const bf16x8*)&sWv[ow * 32 + mt * 16 + c16][ks * 32 + g * 8];
#pragma unroll
            for (int nt = 0; nt < 4; ++nt)
                bfr[nt] = *(const bf16x8*)&sX[nw * 64 + nt * 16 + c16][ks * 32 + g * 8];
#pragma unroll
            for (int mt = 0; mt < 2; ++mt)
#pragma unroll
                for (int nt = 0; nt < 4; ++nt)
                    acc[mt][nt] = __builtin_amdgcn_mfma_f32_16x16x32_bf16(af[mt], bfr[nt], acc[mt][nt], 0, 0, 0);
        }
#pragma unroll
        for (int mt = 0; mt < 2; ++mt) {
            const float4 bi4 = *(const float4*)(bv + ob + ow * 32 + mt * 16 + g * 4);
            const float bia[4] = {bi4.x, bi4.y, bi4.z, bi4.w};
#pragma unroll
            for (int nt = 0; nt < 4; ++nt) {
                const int n = nb + nw * 64 + nt * 16 + c16;
#pragma unroll
                for (int r = 0; r < 4; ++r) {
                    const int o = ob + ow * 32 + mt * 16 + g * 4 + r;
                    Vm[((size_t)b * C_ + o) * N_ + n] = f2bf(acc[mt][nt][r] + bia[r]);
                }
            }
        }
    }
}

// ---------------------------------------------------------------------------
// Pass A v10 (R22): fp8 QK^T.  Same proven R4 skeleton (32 KB dbuf, same
// swizzle family, one barrier cadence) but: BK=64 per stage (4 iters, 32
// MFMA/barrier), ds_read_b64 fragments (gemm_out2's proven lc/bo pattern),
// mfma fp8_fp8 at bf16 rate.  Halves LDS read bytes, staging bytes, and
// barrier count.  Epilogue (exp2 sh=3, lsum, NT PT streamout, lpart)
// byte-identical to R4.  Big-ws path only.
// ---------------------------------------------------------------------------
__global__ __launch_bounds__(256, 4)
void stats_fp8_kernel(const uchar_t* __restrict__ Kt8, const uchar_t* __restrict__ Qt8,
                      uchar_t* __restrict__ PT8, float* __restrict__ lpart) {
    __shared__ uchar_t smem8[32768];   // 2 x (8 KB A + 8 KB B); epilogue reuse
    uchar_t* sp8 = smem8;                      // epilogue: [128][144] fp8 tile
    float* lsum = (float*)(smem8 + 18432);     // [2][128] row partials
    const int tid = threadIdx.x;
    const int lane = tid & 63, g = lane >> 4, c16 = lane & 15;
    const int w = tid >> 6, wi = w >> 1, wj = w & 1;
    const int b = blockIdx.z;
    const int ib = blockIdx.y * 128, jb = blockIdx.x * 128;
    f32x4 acc[4][4];
#pragma unroll
    for (int mt = 0; mt < 4; ++mt)
#pragma unroll
        for (int nt = 0; nt < 4; ++nt) acc[mt][nt] = (f32x4){0.f, 0.f, 0.f, 0.f};

    const int srow = tid >> 2;   // 0..63 (row within 64-row half)
    const int sc = tid & 3;      // 16B chunk slot within 64B row

    auto stage = [&](int kc, int dbase) {      // kc: 64-wide K chunk index
#pragma unroll
        for (int q = 0; q < 2; ++q) {
            const int row = q * 64 + srow;
            const int gc = sc ^ ((row >> 1) & 3);
            const uchar_t* srcA = Kt8 + ((size_t)(b * N_ + ib + row)) * C_ + kc * 64 + gc * 16;
            const uchar_t* srcB = Qt8 + ((size_t)(b * N_ + jb + row)) * C_ + kc * 64 + gc * 16;
            __builtin_amdgcn_global_load_lds((gas_t)srcA, (las_t)&smem8[dbase + (q * 256 + tid) * 16], 16, 0, 0);
            __builtin_amdgcn_global_load_lds((gas_t)srcB, (las_t)&smem8[dbase + 8192 + (q * 256 + tid) * 16], 16, 0, 0);
        }
    };

    stage(0, 0);
    __syncthreads();                 // pipeline fill
    for (int t = 0; t < 4; ++t) {
        const int dbase = (t & 1) * 16384;
        if (t < 3) stage(t + 1, 16384 - dbase);   // prefetch other buf
#pragma unroll
        for (int ks = 0; ks < 2; ++ks) {          // two K=32 sub-chunks of 64
            const int sp = ks * 2 + (g >> 1);     // logical 16B slot in row
            const int bo = (g & 1) * 8;           // byte within slot
            long af[4], bf[4];
#pragma unroll
            for (int mt = 0; mt < 4; ++mt) {
                const int row = wi * 64 + mt * 16 + c16;
                af[mt] = *(const long*)&smem8[dbase + row * 64 + ((sp ^ ((row >> 1) & 3)) * 16) + bo];
            }
#pragma unroll
            for (int nt = 0; nt < 4; ++nt) {
                const int row = wj * 64 + nt * 16 + c16;
                bf[nt] = *(const long*)&smem8[dbase + 8192 + row * 64 + ((sp ^ ((row >> 1) & 3)) * 16) + bo];
            }
#pragma unroll
            for (int mt = 0; mt < 4; ++mt)
#pragma unroll
                for (int nt = 0; nt < 4; ++nt)
                    acc[mt][nt] = __builtin_amdgcn_mfma_f32_16x16x32_fp8_fp8(af[mt], bf[nt], acc[mt][nt], 0, 0, 0);
        }
        __syncthreads();   // waits prefetch (vmcnt) + frees buf for next stage
    }
    const float sh = 3.0f;
#pragma unroll
    for (int mt = 0; mt < 4; ++mt) {
        float rs[4] = {0.f, 0.f, 0.f, 0.f};
#pragma unroll
        for (int nt = 0; nt < 4; ++nt) {
            float e0 = __builtin_amdgcn_exp2f(acc[mt][nt][0] - sh);
            float e1 = __builtin_amdgcn_exp2f(acc[mt][nt][1] - sh);
            float e2 = __builtin_amdgcn_exp2f(acc[mt][nt][2] - sh);
            float e3 = __builtin_amdgcn_exp2f(acc[mt][nt][3] - sh);
            rs[0] += e0; rs[1] += e1; rs[2] += e2; rs[3] += e3;
            int pk = __builtin_amdgcn_cvt_pk_fp8_f32(e0, e1, 0, false);
            pk = __builtin_amdgcn_cvt_pk_fp8_f32(e2, e3, pk, true);
            const int jl = wj * 64 + nt * 16 + c16;
            const int il = wi * 64 + mt * 16 + g * 4;
            *(int*)&sp8[jl * 144 + il] = pk;
        }
#pragma unroll
        for (int r = 0; r < 4; ++r) {
            float s = rs[r];
            s += __shfl_xor(s, 1, 64);
            s += __shfl_xor(s, 2, 64);
            s += __shfl_xor(s, 4, 64);
            s += __shfl_xor(s, 8, 64);
            if (c16 == 0)
                lsum[wj * 128 + wi * 64 + mt * 16 + g * 4 + r] = s;
        }
    }
    __syncthreads();
    // stream out: 128 rows x 128 B (fp8), NONTEMPORAL (bypass L2 pollution)
    {
        const int chb = tid & 7;     // 16B chunk within row
        const int rb = tid >> 3;     // 32 rows per pass
#pragma unroll
        for (int r = 0; r < 4; ++r) {
            const int jl = r * 32 + rb;
            u32x4 v = *(const u32x4*)&sp8[jl * 144 + chb * 16];
            __builtin_nontemporal_store(v,
                (u32x4*)(PT8 + ((size_t)(b * N_ + jb + jl)) * N_ + ib + chb * 16));
        }
        // per-block row-sum partial: one coalesced 512 B store, no atomics
        if (tid < 128) {
            float tot = lsum[tid] + lsum[128 + tid];
            lpart[((size_t)(b * 32 + (jb >> 7))) * N_ + ib + tid] = tot;
        }
    }
}

// ---------------------------------------------------------------------------
// Fallback Pass A (bf16, R4 structure, atomic l path) — used when ws small.
// ---------------------------------------------------------------------------
__global__ __launch_bounds__(256, 4)
void stats_kernel(const ushort_t* __restrict__ Kt, const ushort_t* __restrict__ Qt,
                  float* __restrict__ l) {
    __shared__ ushort_t smem[16384];
    uchar_t* smem8 = (uchar_t*)smem;
    const int tid = threadIdx.x;
    const int lane = tid & 63, g = lane >> 4, c16 = lane & 15;
    const int w = tid >> 6, wi = w >> 1, wj = w & 1;
    const int b = blockIdx.z;
    const int ib = blockIdx.y * 128, jb = blockIdx.x * 128;
    f32x4 acc[4][4];
#pragma unroll
    for (int mt = 0; mt < 4; ++mt)
#pragma unroll
        for (int nt = 0; nt < 4; ++nt) acc[mt][nt] = (f32x4){0.f, 0.f, 0.f, 0.f};

    const int srow = tid >> 2;
    const int sc = tid & 3;

    auto stage = [&](int kc, int dbase) {
#pragma unroll
        for (int q = 0; q < 2; ++q) {
            const int row = q * 64 + srow;
            const int gc = sc ^ ((row >> 1) & 3);
            const ushort_t* srcA = Kt + ((size_t)(b * N_ + ib + row)) * C_ + kc * 32 + gc * 8;
            const ushort_t* srcB = Qt + ((size_t)(b * N_ + jb + row)) * C_ + kc * 32 + gc * 8;
            __builtin_amdgcn_global_load_lds((gas_t)srcA, (las_t)&smem8[dbase + (q * 256 + tid) * 16], 16, 0, 0);
            __builtin_amdgcn_global_load_lds((gas_t)srcB, (las_t)&smem8[dbase + 8192 + (q * 256 + tid) * 16], 16, 0, 0);
        }
    };

    stage(0, 0);
    __syncthreads();
    for (int t = 0; t < 8; ++t) {
        const int dbase = (t & 1) * 16384;
        if (t < 7) stage(t + 1, 16384 - dbase);
        bf16x8 af[4], bf[4];
#pragma unroll
        for (int mt = 0; mt < 4; ++mt) {
            const int row = wi * 64 + mt * 16 + c16;
            af[mt] = *(const bf16x8*)&smem8[dbase + row * 64 + ((g ^ ((row >> 1) & 3)) * 16)];
        }
#pragma unroll
        for (int nt = 0; nt < 4; ++nt) {
            const int row = wj * 64 + nt * 16 + c16;
            bf[nt] = *(const bf16x8*)&smem8[dbase + 8192 + row * 64 + ((g ^ ((row >> 1) & 3)) * 16)];
        }
#pragma unroll
        for (int mt = 0; mt < 4; ++mt)
#pragma unroll
            for (int nt = 0; nt < 4; ++nt)
                acc[mt][nt] = __builtin_amdgcn_mfma_f32_16x16x32_bf16(af[mt], bf[nt], acc[mt][nt], 0, 0, 0);
        __syncthreads();
    }
#pragma unroll
    for (int mt = 0; mt < 4; ++mt) {
        float rs[4] = {0.f, 0.f, 0.f, 0.f};
#pragma unroll
        for (int nt = 0; nt < 4; ++nt) {
            rs[0] += __builtin_amdgcn_exp2f(acc[mt][nt][0]);
            rs[1] += __builtin_amdgcn_exp2f(acc[mt][nt][1]);
            rs[2] += __builtin_amdgcn_exp2f(acc[mt][nt][2]);
            rs[3] += __builtin_amdgcn_exp2f(acc[mt][nt][3]);
        }
#pragma unroll
        for (int r = 0; r < 4; ++r) {
            float s = rs[r];
            s += __shfl_xor(s, 1, 64);
            s += __shfl_xor(s, 2, 64);
            s += __shfl_xor(s, 4, 64);
            s += __shfl_xor(s, 8, 64);
            if (c16 == 0)
                atomicAdd(l + (size_t)b * N_ + ib + wi * 64 + mt * 16 + g * 4 + r, s);
        }
    }
}

// ---------------------------------------------------------------------------
// l[b][i] = sum_jt lpart[b][jt][i]  (2 MB read, 64 KB write, ~1-2 us)
// ---------------------------------------------------------------------------
__global__ void reduce_l_kernel(const float* __restrict__ lpart, float* __restrict__ l) {
    const int b = blockIdx.y;
    const int i = (blockIdx.x * 256 + threadIdx.x) * 4;
    float4 s = {0.f, 0.f, 0.f, 0.f};
#pragma unroll
    for (int jt = 0; jt < 32; ++jt) {
        float4 p = *(const float4*)(lpart + ((size_t)(b * 32 + jt)) * N_ + i);
        s.x += p.x; s.y += p.y; s.z += p.z; s.w += p.w;
    }
    *(float4*)(l + (size_t)b * N_ + i) = s;
}

// ---------------------------------------------------------------------------
// V'' = V * 2^13 * rcp(l') -> fp8 e4m3.  grid (N/2048, C, B), block 256.
// ---------------------------------------------------------------------------
__global__ void scale_v_kernel(const ushort_t* __restrict__ Vm, const float* __restrict__ l,
                               uchar_t* __restrict__ Vs) {
    const int i = (blockIdx.x * 256 + threadIdx.x) * 8;
    const int c = blockIdx.y, b = blockIdx.z;
    float4 l0 = *(const float4*)(l + (size_t)b * N_ + i);
    float4 l1 = *(const float4*)(l + (size_t)b * N_ + i + 4);
    float r[8] = {__builtin_amdgcn_rcpf(l0.x), __builtin_amdgcn_rcpf(l0.y),
                  __builtin_amdgcn_rcpf(l0.z), __builtin_amdgcn_rcpf(l0.w),
                  __builtin_amdgcn_rcpf(l1.x), __builtin_amdgcn_rcpf(l1.y),
                  __builtin_amdgcn_rcpf(l1.z), __builtin_amdgcn_rcpf(l1.w)};
    const size_t off = ((size_t)(b * C_ + c)) * N_ + i;
    uint4 v = *(const uint4*)(Vm + off);
    unsigned vw[4] = {v.x, v.y, v.z, v.w};
    float f[8];
#pragma unroll
    for (int q = 0; q < 4; ++q) {
        union { unsigned u; float fl; } lo, hi;
        lo.u = (vw[q] & 0xffffu) << 16;
        hi.u = vw[q] & 0xffff0000u;
        f[q * 2 + 0] = lo.fl * r[q * 2 + 0] * VSCALE;
        f[q * 2 + 1] = hi.fl * r[q * 2 + 1] * VSCALE;
    }
    int d0 = __builtin_amdgcn_cvt_pk_fp8_f32(f[0], f[1], 0, false);
    d0 = __builtin_amdgcn_cvt_pk_fp8_f32(f[2], f[3], d0, true);
    int d1 = __builtin_amdgcn_cvt_pk_fp8_f32(f[4], f[5], 0, false);
    d1 = __builtin_amdgcn_cvt_pk_fp8_f32(f[6], f[7], d1, true);
    uint2 o; o.x = (unsigned)d0; o.y = (unsigned)d1;
    *(uint2*)(Vs + off) = o;
}

// ---------------------------------------------------------------------------
// Pass B v11 (kept): fp8 single-K GEMM, double-buffered staging, NT fp32
// streams (R4-verified), PT staging CPol NT (R8: neutral, harmless).
// ---------------------------------------------------------------------------
__global__ __launch_bounds__(512, 4)
void gemm_out2_kernel(const uchar_t* __restrict__ A /*Vs fp8 [B][C][N]*/,
                      const uchar_t* __restrict__ Bm /*PT fp8 [B][N][N]*/,
                      const float* __restrict__ R /*x_s2 as [B][C][N]*/,
                      float* __restrict__ out) {
    __shared__ uchar_t smem[73728];   // 2 x (32 KB A + 4 KB B)
    const int tid = threadIdx.x;
    const int lane = tid & 63, g = lane >> 4, c16 = lane & 15;
    const int w = tid >> 6;
    const int cw = w * 32;              // wave's 32-c band
    const int b = blockIdx.y;
    const int jb = blockIdx.x * 32;

    f32x4 acc[2][2];
#pragma unroll
    for (int mt = 0; mt < 2; ++mt)
#pragma unroll
        for (int nt = 0; nt < 2; ++nt) acc[mt][nt] = (f32x4){0.f, 0.f, 0.f, 0.f};

    const int sch = tid & 7;          // chunk slot within row

    auto stage = [&](int k0, int dbase) {
#pragma unroll
        for (int q = 0; q < 4; ++q) {
            const int slot = q * 512 + tid;
            const int row = slot >> 3;
            const int gc = sch ^ (row & 7);
            const uchar_t* src = A + ((size_t)(b * C_ + row)) * N_ + k0 + gc * 16;
            __builtin_amdgcn_global_load_lds((gas_t)src, (las_t)&smem[dbase + slot * 16], 16, 0, 0);
        }
        if (tid < 256) {
            const int row = tid >> 3;
            const int gc = sch ^ (row & 7);
            const uchar_t* src = Bm + ((size_t)(b * N_ + jb + row)) * N_ + k0 + gc * 16;
            __builtin_amdgcn_global_load_lds((gas_t)src, (las_t)&smem[dbase + 32768 + tid * 16], 16, 0, 2);
        }
    };

    stage(0, 0);
    __syncthreads();                     // pipeline fill
    for (int t = 0; t < 32; ++t) {
        const int dbase = (t & 1) * 36864;
        if (t < 31) stage((t + 1) * 128, 36864 - dbase);   // prefetch other buf
        const uchar_t* sA = &smem[dbase];
        const uchar_t* sB = &smem[dbase + 32768];
#pragma unroll
        for (int ks = 0; ks < 4; ++ks) {    // 4 x K=32
            const int lc = ks * 2 + (g >> 1);       // logical 16B chunk
            const int bo = (g & 1) * 8;             // byte within chunk
            long af[2], bfg[2];
#pragma unroll
            for (int mt = 0; mt < 2; ++mt) {
                const int row = cw + mt * 16 + c16;
                af[mt] = *(const long*)&sA[row * 128 + ((lc ^ (row & 7)) * 16) + bo];
            }
#pragma unroll
            for (int nt = 0; nt < 2; ++nt) {
                const int row = nt * 16 + c16;
                bfg[nt] = *(const long*)&sB[row * 128 + ((lc ^ (row & 7)) * 16) + bo];
            }
#pragma unroll
            for (int mt = 0; mt < 2; ++mt)
#pragma unroll
                for (int nt = 0; nt < 2; ++nt)
                    acc[mt][nt] = __builtin_amdgcn_mfma_f32_16x16x32_fp8_fp8(af[mt], bfg[nt], acc[mt][nt], 0, 0, 0);
        }
        __syncthreads();   // waits prefetch + frees buf for next stage
    }
    // epilogue: out = residual + acc * 2^-13 (nontemporal fp32 stream)
#pragma unroll
    for (int mt = 0; mt < 2; ++mt)
#pragma unroll
        for (int r = 0; r < 4; ++r) {
            const int c = cw + mt * 16 + g * 4 + r;
            const size_t rowoff = ((size_t)(b * C_ + c)) * N_ + jb;
#pragma unroll
            for (int nt = 0; nt < 2; ++nt) {
                const int j = nt * 16 + c16;
                float rv = __builtin_nontemporal_load(&R[rowoff + j]);
                __builtin_nontemporal_store(rv + acc[mt][nt][r] * VSCALE_INV,
                                            &out[rowoff + j]);
            }
        }
}

// ---------------------------------------------------------------------------
// Fallback Pass B (unchanged; used when ws small).  Needs bf16 Kt/Qt/Vm and
// UNSHIFTED l (fallback stats uses sh=0 + atomics).
// ---------------------------------------------------------------------------
__global__ __launch_bounds__(512, 4)
void out_kernel(const ushort_t* __restrict__ Kt, const ushort_t* __restrict__ Qt,
                const ushort_t* __restrict__ V, const float* __restrict__ l,
                float* __restrict__ dout) {
    __shared__ ushort_t sQ[64][264];
    __shared__ ushort_t sP[64][264];
    const int tid = threadIdx.x;
    const int w = tid >> 6, lane = tid & 63, g = lane >> 4, c16 = lane & 15;
    const int b = blockIdx.z;
    const int jb = blockIdx.x * 64;
    const int ibase = blockIdx.y * 2048;
    {
        const int jl = tid >> 3, cp = (tid & 7) * 32;
        const ushort_t* src = Qt + ((size_t)(b * N_ + jb + jl)) * C_ + cp;
        uint4 a0 = *(const uint4*)(src);
        uint4 a1 = *(const uint4*)(src + 8);
        uint4 a2 = *(const uint4*)(src + 16);
        uint4 a3 = *(const uint4*)(src + 24);
        *(uint4*)&sQ[jl][cp + 0]  = a0;
        *(uint4*)&sQ[jl][cp + 8]  = a1;
        *(uint4*)&sQ[jl][cp + 16] = a2;
        *(uint4*)&sQ[jl][cp + 24] = a3;
    }
    f32x4 acc[2][4];
#pragma unroll
    for (int mt = 0; mt < 2; ++mt)
#pragma unroll
        for (int nt = 0; nt < 4; ++nt) acc[mt][nt] = (f32x4){0.f, 0.f, 0.f, 0.f};

    const int bw = w * 32;

    for (int ic = 0; ic < 8; ++ic) {
        const int i0 = ibase + ic * 256;
        float rv[2][4];
#pragma unroll
        for (int mt = 0; mt < 2; ++mt) {
            float4 lr = *(const float4*)(l + (size_t)b * N_ + i0 + bw + mt * 16 + g * 4);
            rv[mt][0] = __builtin_amdgcn_logf(lr.x);
            rv[mt][1] = __builtin_amdgcn_logf(lr.y);
            rv[mt][2] = __builtin_amdgcn_logf(lr.z);
            rv[mt][3] = __builtin_amdgcn_logf(lr.w);
        }
        __syncthreads();
        f32x4 sa[2][4];
#pragma unroll
        for (int mt = 0; mt < 2; ++mt)
#pragma unroll
            for (int nt = 0; nt < 4; ++nt) sa[mt][nt] = (f32x4){0.f, 0.f, 0.f, 0.f};
#pragma unroll
        for (int k = 0; k < 8; ++k) {
            bf16x8 av[2];
#pragma unroll
            for (int mt = 0; mt < 2; ++mt)
                av[mt] = ld_bf8(Kt + ((size_t)(b * N_ + i0 + bw + mt * 16 + c16)) * C_ + k * 32 + g * 8);
#pragma unroll
            for (int nt = 0; nt < 4; ++nt) {
                bf16x8 bv = *(const bf16x8*)&sQ[nt * 16 + c16][k * 32 + g * 8];
#pragma unroll
                for (int mt = 0; mt < 2; ++mt)
                    sa[mt][nt] = __builtin_amdgcn_mfma_f32_16x16x32_bf16(av[mt], bv, sa[mt][nt], 0, 0, 0);
            }
        }
#pragma unroll
        for (int mt = 0; mt < 2; ++mt)
#pragma unroll
            for (int nt = 0; nt < 4; ++nt) {
                const int j = nt * 16 + c16;
                unsigned p0 = f2bf(__builtin_amdgcn_exp2f(sa[mt][nt][0] - rv[mt][0]));
                unsigned p1 = f2bf(__builtin_amdgcn_exp2f(sa[mt][nt][1] - rv[mt][1]));
                unsigned p2 = f2bf(__builtin_amdgcn_exp2f(sa[mt][nt][2] - rv[mt][2]));
                unsigned p3 = f2bf(__builtin_amdgcn_exp2f(sa[mt][nt][3] - rv[mt][3]));
                uint2 pk; pk.x = p0 | (p1 << 16); pk.y = p2 | (p3 << 16);
                *(uint2*)&sP[j][bw + mt * 16 + g * 4] = pk;
            }
        __syncthreads();
#pragma unroll
        for (int ks = 0; ks < 8; ++ks) {
            bf16x8 va[2];
#pragma unroll
            for (int mt = 0; mt < 2; ++mt)
                va[mt] = ld_bf8(V + ((size_t)(b * C_ + bw + mt * 16 + c16)) * N_ + i0 + ks * 32 + g * 8);
#pragma unroll
            for (int nt = 0; nt < 4; ++nt) {
                bf16x8 pb = *(const bf16x8*)&sP[nt * 16 + c16][ks * 32 + g * 8];
#pragma unroll
                for (int mt = 0; mt < 2; ++mt)
                    acc[mt][nt] = __builtin_amdgcn_mfma_f32_16x16x32_bf16(va[mt], pb, acc[mt][nt], 0, 0, 0);
            }
        }
    }
#pragma unroll
    for (int mt = 0; mt < 2; ++mt)
#pragma unroll
        for (int nt = 0; nt < 4; ++nt)
#pragma unroll
            for (int r = 0; r < 4; ++r) {
                const int c = bw + mt * 16 + g * 4 + r;
                const int j = jb + nt * 16 + c16;
                atomicAdd(dout + ((size_t)b * C_ + c) * N_ + j, acc[mt][nt][r]);
            }
}

extern "C" void kernel_launch(void* const* d_in, const int* in_sizes, int n_in,
                              void* d_out, int out_size, void* d_ws, size_t ws_size,
                              hipStream_t stream) {
    const float* x_s2  = (const float*)d_in[0];
    const float* x_dem = (const float*)d_in[1];
    const float* Wq = (const float*)d_in[2];
    const float* bq = (const float*)d_in[3];
    const float* Wk = (const float*)d_in[4];
    const float* bk = (const float*)d_in[5];
    const float* Wv = (const float*)d_in[6];
    const float* bv = (const float*)d_in[7];
    float* out = (float*)d_out;

    const size_t MiB = 1024 * 1024;
    char* ws = (char*)d_ws;
    ushort_t* Qt = (ushort_t*)(ws);               // [B][N][C] bf16 (fallback) /
    uchar_t*  Qt8 = (uchar_t*)(ws);               //   fp8 Q' (bigws), same slot
    ushort_t* Kt = (ushort_t*)(ws + 8  * MiB);    // [B][N][C] bf16 (fallback) /
    uchar_t*  Kt8 = (uchar_t*)(ws + 8 * MiB);     //   fp8 K' (bigws), same slot
    ushort_t* Vm = (ushort_t*)(ws + 16 * MiB);    // [B][C][N] bf16, 8 MiB
    uchar_t*  Vs = (uchar_t*) (ws + 24 * MiB);    // [B][C][N] fp8 V'', 4 MiB
    float*    lp = (float*)   (ws + 24 * MiB);    // [B][32][N] partials, 2 MiB
                                                  //   (aliases Vs: dead before
                                                  //    scale_v writes Vs)
    float*    lv = (float*)   (ws + 28 * MiB);    // [B][N] row sums, 64 KiB
    uchar_t*  PT = (uchar_t*) (ws + 29 * MiB);    // [B][N(j)][N(i)] fp8, 64 MiB
    const bool bigws = ws_size >= 93 * MiB;

    if (!bigws) {
        hipMemsetAsync(lv, 0, (size_t)B_ * N_ * sizeof(float), stream);
        hipMemcpyAsync(out, x_s2, (size_t)B_ * C_ * N_ * sizeof(float),
                       hipMemcpyDeviceToDevice, stream);
    }

    proj_q_mfma<<<dim3(N_ / 128, C_ / 64, B_), 256, 0, stream>>>(
        x_s2, Wq, bq, Qt, bigws ? Qt8 : (uchar_t*)nullptr, C_);
    proj_kv_mfma<<<dim3(N_ / 128, C_ / 64, B_), 256, 0, stream>>>(
        x_dem, Wk, bk, Wv, bv, Kt, bigws ? Kt8 : (uchar_t*)nullptr, Vm);
    if (bigws) {
        stats_fp8_kernel<<<dim3(N_ / 128, N_ / 128, B_), 256, 0, stream>>>(Kt8, Qt8, PT, lp);
        reduce_l_kernel<<<dim3(N_ / 1024, B_), 256, 0, stream>>>(lp, lv);
        scale_v_kernel<<<dim3(N_ / 2048, C_, B_), 256, 0, stream>>>(Vm, lv, Vs);
        gemm_out2_kernel<<<dim3(N_ / 32, B_), 512, 0, stream>>>(Vs, PT, x_s2, out);
    } else {
        stats_kernel<<<dim3(N_ / 128, N_ / 128, B_), 256, 0, stream>>>(Kt, Qt, lv);
        out_kernel<<<dim3(N_ / 64, 2, B_), 512, 0, stream>>>(Kt, Qt, Vm, lv, out);
    }
}

// Round 11
// 193.741 us; speedup vs baseline: 1.1219x; 1.0254x over previous
//
#include <hip/hip_runtime.h>
#include <hip/hip_bf16.h>
#include <cstdint>

#define B_  4
#define N_  4096
#define C_  256
#define CD_ 64

typedef unsigned short ushort_t;
typedef unsigned char uchar_t;
typedef __bf16 bf16x8 __attribute__((ext_vector_type(8)));
typedef float f32x4 __attribute__((ext_vector_type(4)));
typedef unsigned int u32x4 __attribute__((ext_vector_type(4)));
typedef long longx2 __attribute__((ext_vector_type(2)));

typedef const __attribute__((address_space(1))) void* gas_t;
typedef __attribute__((address_space(3))) void* las_t;

// (1/sqrt(256)) * log2(e): folded into K projection so S' = S_true * log2(e)
static constexpr float SCALE_LOG2E = 0.09016844005556021f;
// R22 fp8 split: K' = k*(log2e/4), Q' = q/4  ->  K'.Q' = k.q*log2e/16 exactly.
static constexpr float SCALE_K8 = 0.3606737602222408f;   // log2e/4
static constexpr float SCALE_Q8 = 0.25f;
// V' scale 2^13 (undone in gemm epilogue); PT exponent shift -3 cancels via l.
static constexpr float VSCALE = 8192.0f;
static constexpr float VSCALE_INV = 1.0f / 8192.0f;

__device__ __forceinline__ ushort_t f2bf(float x) {
    union { float f; unsigned u; } v; v.f = x;
    unsigned u = v.u;
    unsigned r = (u + 0x7fffu + ((u >> 16) & 1u)) >> 16;  // round-nearest-even
    return (ushort_t)r;
}

__device__ __forceinline__ uchar_t f2fp8(float x) {
    return (uchar_t)(__builtin_amdgcn_cvt_pk_fp8_f32(x, x, 0, false) & 0xff);
}

__device__ __forceinline__ bf16x8 ld_bf8(const ushort_t* p) {
    return *reinterpret_cast<const bf16x8*>(p);
}

// R23 slot permutations (dot products invariant under common k-permutation):
// 128B group, 16 slots of 8B: chunk L=p*4+g holds slots (2p*4+g, (2p+1)*4+g)
// -> one b128 read per lane covers two K=32 MFMA steps, conflict-free.
__device__ __forceinline__ int perm16(int s) {   // slot 0..15 -> byte pos
    return (((s & 3) | ((s >> 1) & 4)) << 4) | ((s & 4) << 1);
}
// 64B group, 8 slots of 8B: chunk g holds slots (g, g+4).
__device__ __forceinline__ int perm8(int s) {    // slot 0..7 -> byte pos
    return ((s & 3) << 4) | ((s & 4) << 1);
}

// ---------------------------------------------------------------------------
// MFMA projection -> TRANSPOSED layout (proven R8).  R22: fp8 epilogue for
// big-ws; R23: fp8 column o stored at perm8 position within each 64B group
// (matches stats_fp8's b128 reads).  bf16 fallback path untouched.
// ---------------------------------------------------------------------------
__global__ __launch_bounds__(256, 4)
void proj_q_mfma(const float* __restrict__ X, const float* __restrict__ W,
                 const float* __restrict__ bias, ushort_t* __restrict__ dst,
                 uchar_t* __restrict__ dst8, int Cin) {
    __shared__ ushort_t sX[128][72];   // [n][c] bf16
    __shared__ ushort_t sW[64][72];    // [o][c] bf16
    const int tid = threadIdx.x;
    const int lane = tid & 63, g = lane >> 4, c16 = lane & 15;
    const int w = tid >> 6, wi = w >> 1, wj = w & 1;   // n-half, o-half
    const int b = blockIdx.z, nb = blockIdx.x * 128, ob = blockIdx.y * 64;
    f32x4 acc[4][2];
#pragma unroll
    for (int nt = 0; nt < 4; ++nt)
#pragma unroll
        for (int ot = 0; ot < 2; ++ot) acc[nt][ot] = (f32x4){0.f, 0.f, 0.f, 0.f};

    const int cr = tid >> 5;
    const int n0 = (tid & 31) * 4;

    for (int k0 = 0; k0 < Cin; k0 += 64) {
#pragma unroll
        for (int p = 0; p < 8; ++p) {
            const int c = p * 8 + cr;
            float4 xv = *(const float4*)(X + ((size_t)b * Cin + k0 + c) * N_ + nb + n0);
            sX[n0 + 0][c] = f2bf(xv.x);
            sX[n0 + 1][c] = f2bf(xv.y);
            sX[n0 + 2][c] = f2bf(xv.z);
            sX[n0 + 3][c] = f2bf(xv.w);
        }
        {
            const int o = tid >> 2, cq = (tid & 3) * 16;
            const float* wsrc = W + (size_t)(ob + o) * Cin + k0 + cq;
            alignas(16) ushort_t tmp[16];
#pragma unroll
            for (int q = 0; q < 16; ++q) tmp[q] = f2bf(wsrc[q]);
            *(uint4*)&sW[o][cq]     = *(uint4*)&tmp[0];
            *(uint4*)&sW[o][cq + 8] = *(uint4*)&tmp[8];
        }
        __syncthreads();
#pragma unroll
        for (int ks = 0; ks < 2; ++ks) {
            bf16x8 af[4], bfr[2];
#pragma unroll
            for (int nt = 0; nt < 4; ++nt)
                af[nt] = *(const bf16x8*)&sX[wi * 64 + nt * 16 + c16][ks * 32 + g * 8];
#pragma unroll
            for (int ot = 0; ot < 2; ++ot)
                bfr[ot] = *(const bf16x8*)&sW[wj * 32 + ot * 16 + c16][ks * 32 + g * 8];
#pragma unroll
            for (int nt = 0; nt < 4; ++nt)
#pragma unroll
                for (int ot = 0; ot < 2; ++ot)
                    acc[nt][ot] = __builtin_amdgcn_mfma_f32_16x16x32_bf16(af[nt], bfr[ot], acc[nt][ot], 0, 0, 0);
        }
        __syncthreads();
    }
#pragma unroll
    for (int ot = 0; ot < 2; ++ot) {
        const int o = ob + wj * 32 + ot * 16 + c16;
        const float bia = bias[o];
        const int o_p = (o & ~63) | perm8((o >> 3) & 7) | (o & 7);
#pragma unroll
        for (int nt = 0; nt < 4; ++nt) {
#pragma unroll
            for (int r = 0; r < 4; ++r) {
                const int n = nb + wi * 64 + nt * 16 + g * 4 + r;
                const float v = acc[nt][ot][r] + bia;
                if (dst8 != nullptr)
                    dst8[((size_t)b * N_ + n) * C_ + o_p] = f2fp8(v * SCALE_Q8);
                else
                    dst[((size_t)b * N_ + n) * C_ + o] = f2bf(v);
            }
        }
    }
}

// ---------------------------------------------------------------------------
// Fused K+V MFMA projection from x_dem (proven R8).  R22/R23: fp8 K path
// with perm8 column placement; V always bf16.
// ---------------------------------------------------------------------------
__global__ __launch_bounds__(256, 4)
void proj_kv_mfma(const float* __restrict__ X, const float* __restrict__ Wk,
                  const float* __restrict__ bk, const float* __restrict__ Wv,
                  const float* __restrict__ bv, ushort_t* __restrict__ Kt,
                  uchar_t* __restrict__ Kt8, ushort_t* __restrict__ Vm) {
    __shared__ ushort_t sX[128][72];   // [n][c]
    __shared__ ushort_t sWk[64][72];   // [o][c]
    __shared__ ushort_t sWv[64][72];
    const int tid = threadIdx.x;
    const int lane = tid & 63, g = lane >> 4, c16 = lane & 15;
    const int w = tid >> 6;
    const int b = blockIdx.z, nb = blockIdx.x * 128, ob = blockIdx.y * 64;

    {
        const int cr = tid >> 5, n0 = (tid & 31) * 4;
#pragma unroll
        for (int p = 0; p < 8; ++p) {
            const int c = p * 8 + cr;
            float4 xv = *(const float4*)(X + ((size_t)b * CD_ + c) * N_ + nb + n0);
            sX[n0 + 0][c] = f2bf(xv.x);
            sX[n0 + 1][c] = f2bf(xv.y);
            sX[n0 + 2][c] = f2bf(xv.z);
            sX[n0 + 3][c] = f2bf(xv.w);
        }
        const int o = tid >> 2, cq = (tid & 3) * 16;
        alignas(16) ushort_t tk[16], tv[16];
        const float* ksrc = Wk + (size_t)(ob + o) * CD_ + cq;
        const float* vsrc = Wv + (size_t)(ob + o) * CD_ + cq;
#pragma unroll
        for (int q = 0; q < 16; ++q) { tk[q] = f2bf(ksrc[q]); tv[q] = f2bf(vsrc[q]); }
        *(uint4*)&sWk[o][cq]     = *(uint4*)&tk[0];
        *(uint4*)&sWk[o][cq + 8] = *(uint4*)&tk[8];
        *(uint4*)&sWv[o][cq]     = *(uint4*)&tv[0];
        *(uint4*)&sWv[o][cq + 8] = *(uint4*)&tv[8];
    }
    __syncthreads();
    // ---- K-part ----
    {
        const int wi = w >> 1, wj = w & 1;
        f32x4 acc[4][2];
#pragma unroll
        for (int nt = 0; nt < 4; ++nt)
#pragma unroll
            for (int ot = 0; ot < 2; ++ot) acc[nt][ot] = (f32x4){0.f, 0.f, 0.f, 0.f};
#pragma unroll
        for (int ks = 0; ks < 2; ++ks) {
            bf16x8 af[4], bfr[2];
#pragma unroll
            for (int nt = 0; nt < 4; ++nt)
                af[nt] = *(const bf16x8*)&sX[wi * 64 + nt * 16 + c16][ks * 32 + g * 8];
#pragma unroll
            for (int ot = 0; ot < 2; ++ot)
                bfr[ot] = *(const bf16x8*)&sWk[wj * 32 + ot * 16 + c16][ks * 32 + g * 8];
#pragma unroll
            for (int nt = 0; nt < 4; ++nt)
#pragma unroll
                for (int ot = 0; ot < 2; ++ot)
                    acc[nt][ot] = __builtin_amdgcn_mfma_f32_16x16x32_bf16(af[nt], bfr[ot], acc[nt][ot], 0, 0, 0);
        }
#pragma unroll
        for (int ot = 0; ot < 2; ++ot) {
            const int o = ob + wj * 32 + ot * 16 + c16;
            const float bia = bk[o];
            const int o_p = (o & ~63) | perm8((o >> 3) & 7) | (o & 7);
#pragma unroll
            for (int nt = 0; nt < 4; ++nt)
#pragma unroll
                for (int r = 0; r < 4; ++r) {
                    const int n = nb + wi * 64 + nt * 16 + g * 4 + r;
                    const float v = acc[nt][ot][r] + bia;
                    if (Kt8 != nullptr)
                        Kt8[((size_t)b * N_ + n) * C_ + o_p] = f2fp8(v * SCALE_K8);
                    else
                        Kt[((size_t)b * N_ + n) * C_ + o] = f2bf(v * SCALE_LOG2E);
                }
        }
    }
    // ---- V-part ----
    {
        const int ow = w & 1, nw = w >> 1;
        f32x4 acc[2][4];
#pragma unroll
        for (int mt = 0; mt < 2; ++mt)
#pragma unroll
            for (int nt = 0; nt < 4; ++nt) acc[mt][nt] = (f32x4){0.f, 0.f, 0.f, 0.f};
#pragma unroll
        for (int ks = 0; ks < 2; ++ks) {
            bf16x8 af[2], bfr[4];
#pragma unroll
            for (int mt = 0; mt < 2; ++mt)
                af[mt] = *(const bf16x8*)&sWv[ow * 32 + mt * 16 + c16][ks * 32 + g * 8];
#pragma unroll
            for (int nt = 0; nt < 4; ++nt)
                bfr[nt] = *(const bf16x8*)&sX[nw * 64 + nt * 16 + c16][ks * 32 + g * 8];
#pragma unroll
            for (int mt = 0; mt < 2; ++mt)
#pragma unroll
                for (int nt = 0; nt < 4; ++nt)
                    acc[mt][nt] = __builtin_amdgcn_mfma_f32_16x16x32_bf16(af[mt], bfr[nt], acc[mt][nt], 0, 0, 0);
        }
#pragma unroll
        for (int mt = 0; mt < 2; ++mt) {
            const float4 bi4 = *(const float4*)(bv + ob + ow * 32 + mt * 16 + g * 4);
            const float bia[4] = {bi4.x, bi4.y, bi4.z, bi4.w};
#pragma unroll
            for (int nt = 0; nt < 4; ++nt) {
                const int n = nb + nw * 64 + nt * 16 + c16;
#pragma unroll
                for (int r = 0; r < 4; ++r) {
                    const int o = ob + ow * 32 + mt * 16 + g * 4 + r;
                    Vm[((size_t)b * C_ + o) * N_ + n] = f2bf(acc[mt][nt][r] + bia[r]);
                }
            }
        }
    }
}

// ---------------------------------------------------------------------------
// Pass A v11 (R23): fp8 QK^T, b128 LDS reads.  Kt8/Qt8 columns are perm8-
// permuted so one b128 per lane covers BOTH K=32 steps of a 64-k stage:
// chunk g = slots (g, g+4); read at chunk (g ^ ((row>>1)&3)).  8 b128/wave/t
// (was 16 b64), conflict-free phases.  Skeleton/epilogue from proven R22.
// ---------------------------------------------------------------------------
__global__ __launch_bounds__(256, 4)
void stats_fp8_kernel(const uchar_t* __restrict__ Kt8, const uchar_t* __restrict__ Qt8,
                      uchar_t* __restrict__ PT8, float* __restrict__ lpart) {
    __shared__ uchar_t smem8[32768];   // 2 x (8 KB A + 8 KB B); epilogue reuse
    uchar_t* sp8 = smem8;                      // epilogue: [128][144] fp8 tile
    float* lsum = (float*)(smem8 + 18432);     // [2][128] row partials
    const int tid = threadIdx.x;
    const int lane = tid & 63, g = lane >> 4, c16 = lane & 15;
    const int w = tid >> 6, wi = w >> 1, wj = w & 1;
    const int b = blockIdx.z;
    const int ib = blockIdx.y * 128, jb = blockIdx.x * 128;
    f32x4 acc[4][4];
#pragma unroll
    for (int mt = 0; mt < 4; ++mt)
#pragma unroll
        for (int nt = 0; nt < 4; ++nt) acc[mt][nt] = (f32x4){0.f, 0.f, 0.f, 0.f};

    const int srow = tid >> 2;   // 0..63 (row within 64-row half)
    const int sc = tid & 3;      // 16B chunk slot within 64B row

    auto stage = [&](int kc, int dbase) {      // kc: 64-wide K chunk index
#pragma unroll
        for (int q = 0; q < 2; ++q) {
            const int row = q * 64 + srow;
            const int gc = sc ^ ((row >> 1) & 3);
            const uchar_t* srcA = Kt8 + ((size_t)(b * N_ + ib + row)) * C_ + kc * 64 + gc * 16;
            const uchar_t* srcB = Qt8 + ((size_t)(b * N_ + jb + row)) * C_ + kc * 64 + gc * 16;
            __builtin_amdgcn_global_load_lds((gas_t)srcA, (las_t)&smem8[dbase + (q * 256 + tid) * 16], 16, 0, 0);
            __builtin_amdgcn_global_load_lds((gas_t)srcB, (las_t)&smem8[dbase + 8192 + (q * 256 + tid) * 16], 16, 0, 0);
        }
    };

    stage(0, 0);
    __syncthreads();                 // pipeline fill
    for (int t = 0; t < 4; ++t) {
        const int dbase = (t & 1) * 16384;
        if (t < 3) stage(t + 1, 16384 - dbase);   // prefetch other buf
        longx2 a2[4], b2[4];
#pragma unroll
        for (int mt = 0; mt < 4; ++mt) {
            const int row = wi * 64 + mt * 16 + c16;
            a2[mt] = *(const longx2*)&smem8[dbase + row * 64 + ((g ^ ((row >> 1) & 3)) * 16)];
        }
#pragma unroll
        for (int nt = 0; nt < 4; ++nt) {
            const int row = wj * 64 + nt * 16 + c16;
            b2[nt] = *(const longx2*)&smem8[dbase + 8192 + row * 64 + ((g ^ ((row >> 1) & 3)) * 16)];
        }
#pragma unroll
        for (int ks = 0; ks < 2; ++ks)
#pragma unroll
            for (int mt = 0; mt < 4; ++mt)
#pragma unroll
                for (int nt = 0; nt < 4; ++nt)
                    acc[mt][nt] = __builtin_amdgcn_mfma_f32_16x16x32_fp8_fp8(a2[mt][ks], b2[nt][ks], acc[mt][nt], 0, 0, 0);
        __syncthreads();   // waits prefetch (vmcnt) + frees buf for next stage
    }
    const float sh = 3.0f;
#pragma unroll
    for (int mt = 0; mt < 4; ++mt) {
        float rs[4] = {0.f, 0.f, 0.f, 0.f};
#pragma unroll
        for (int nt = 0; nt < 4; ++nt) {
            float e0 = __builtin_amdgcn_exp2f(acc[mt][nt][0] - sh);
            float e1 = __builtin_amdgcn_exp2f(acc[mt][nt][1] - sh);
            float e2 = __builtin_amdgcn_exp2f(acc[mt][nt][2] - sh);
            float e3 = __builtin_amdgcn_exp2f(acc[mt][nt][3] - sh);
            rs[0] += e0; rs[1] += e1; rs[2] += e2; rs[3] += e3;
            int pk = __builtin_amdgcn_cvt_pk_fp8_f32(e0, e1, 0, false);
            pk = __builtin_amdgcn_cvt_pk_fp8_f32(e2, e3, pk, true);
            const int jl = wj * 64 + nt * 16 + c16;
            const int il = wi * 64 + mt * 16 + g * 4;
            // R23: PT i-axis perm16 within 128B group (matches gemm b128 reads)
            const int il_p = perm16(il >> 3) | (il & 7);
            *(int*)&sp8[jl * 144 + il_p] = pk;
        }
#pragma unroll
        for (int r = 0; r < 4; ++r) {
            float s = rs[r];
            s += __shfl_xor(s, 1, 64);
            s += __shfl_xor(s, 2, 64);
            s += __shfl_xor(s, 4, 64);
            s += __shfl_xor(s, 8, 64);
            if (c16 == 0)
                lsum[wj * 128 + wi * 64 + mt * 16 + g * 4 + r] = s;
        }
    }
    __syncthreads();
    // stream out: 128 rows x 128 B (fp8), NONTEMPORAL (bypass L2 pollution)
    {
        const int chb = tid & 7;     // 16B chunk within row
        const int rb = tid >> 3;     // 32 rows per pass
#pragma unroll
        for (int r = 0; r < 4; ++r) {
            const int jl = r * 32 + rb;
            u32x4 v = *(const u32x4*)&sp8[jl * 144 + chb * 16];
            __builtin_nontemporal_store(v,
                (u32x4*)(PT8 + ((size_t)(b * N_ + jb + jl)) * N_ + ib + chb * 16));
        }
        // per-block row-sum partial: one coalesced 512 B store, no atomics
        if (tid < 128) {
            float tot = lsum[tid] + lsum[128 + tid];
            lpart[((size_t)(b * 32 + (jb >> 7))) * N_ + ib + tid] = tot;
        }
    }
}

// ---------------------------------------------------------------------------
// Fallback Pass A (bf16, R4 structure, atomic l path) — used when ws small.
// ---------------------------------------------------------------------------
__global__ __launch_bounds__(256, 4)
void stats_kernel(const ushort_t* __restrict__ Kt, const ushort_t* __restrict__ Qt,
                  float* __restrict__ l) {
    __shared__ ushort_t smem[16384];
    uchar_t* smem8 = (uchar_t*)smem;
    const int tid = threadIdx.x;
    const int lane = tid & 63, g = lane >> 4, c16 = lane & 15;
    const int w = tid >> 6, wi = w >> 1, wj = w & 1;
    const int b = blockIdx.z;
    const int ib = blockIdx.y * 128, jb = blockIdx.x * 128;
    f32x4 acc[4][4];
#pragma unroll
    for (int mt = 0; mt < 4; ++mt)
#pragma unroll
        for (int nt = 0; nt < 4; ++nt) acc[mt][nt] = (f32x4){0.f, 0.f, 0.f, 0.f};

    const int srow = tid >> 2;
    const int sc = tid & 3;

    auto stage = [&](int kc, int dbase) {
#pragma unroll
        for (int q = 0; q < 2; ++q) {
            const int row = q * 64 + srow;
            const int gc = sc ^ ((row >> 1) & 3);
            const ushort_t* srcA = Kt + ((size_t)(b * N_ + ib + row)) * C_ + kc * 32 + gc * 8;
            const ushort_t* srcB = Qt + ((size_t)(b * N_ + jb + row)) * C_ + kc * 32 + gc * 8;
            __builtin_amdgcn_global_load_lds((gas_t)srcA, (las_t)&smem8[dbase + (q * 256 + tid) * 16], 16, 0, 0);
            __builtin_amdgcn_global_load_lds((gas_t)srcB, (las_t)&smem8[dbase + 8192 + (q * 256 + tid) * 16], 16, 0, 0);
        }
    };

    stage(0, 0);
    __syncthreads();
    for (int t = 0; t < 8; ++t) {
        const int dbase = (t & 1) * 16384;
        if (t < 7) stage(t + 1, 16384 - dbase);
        bf16x8 af[4], bf[4];
#pragma unroll
        for (int mt = 0; mt < 4; ++mt) {
            const int row = wi * 64 + mt * 16 + c16;
            af[mt] = *(const bf16x8*)&smem8[dbase + row * 64 + ((g ^ ((row >> 1) & 3)) * 16)];
        }
#pragma unroll
        for (int nt = 0; nt < 4; ++nt) {
            const int row = wj * 64 + nt * 16 + c16;
            bf[nt] = *(const bf16x8*)&smem8[dbase + 8192 + row * 64 + ((g ^ ((row >> 1) & 3)) * 16)];
        }
#pragma unroll
        for (int mt = 0; mt < 4; ++mt)
#pragma unroll
            for (int nt = 0; nt < 4; ++nt)
                acc[mt][nt] = __builtin_amdgcn_mfma_f32_16x16x32_bf16(af[mt], bf[nt], acc[mt][nt], 0, 0, 0);
        __syncthreads();
    }
#pragma unroll
    for (int mt = 0; mt < 4; ++mt) {
        float rs[4] = {0.f, 0.f, 0.f, 0.f};
#pragma unroll
        for (int nt = 0; nt < 4; ++nt) {
            rs[0] += __builtin_amdgcn_exp2f(acc[mt][nt][0]);
            rs[1] += __builtin_amdgcn_exp2f(acc[mt][nt][1]);
            rs[2] += __builtin_amdgcn_exp2f(acc[mt][nt][2]);
            rs[3] += __builtin_amdgcn_exp2f(acc[mt][nt][3]);
        }
#pragma unroll
        for (int r = 0; r < 4; ++r) {
            float s = rs[r];
            s += __shfl_xor(s, 1, 64);
            s += __shfl_xor(s, 2, 64);
            s += __shfl_xor(s, 4, 64);
            s += __shfl_xor(s, 8, 64);
            if (c16 == 0)
                atomicAdd(l + (size_t)b * N_ + ib + wi * 64 + mt * 16 + g * 4 + r, s);
        }
    }
}

// ---------------------------------------------------------------------------
// l[b][i] = sum_jt lpart[b][jt][i]  (2 MB read, 64 KB write, ~1-2 us)
// ---------------------------------------------------------------------------
__global__ void reduce_l_kernel(const float* __restrict__ lpart, float* __restrict__ l) {
    const int b = blockIdx.y;
    const int i = (blockIdx.x * 256 + threadIdx.x) * 4;
    float4 s = {0.f, 0.f, 0.f, 0.f};
#pragma unroll
    for (int jt = 0; jt < 32; ++jt) {
        float4 p = *(const float4*)(lpart + ((size_t)(b * 32 + jt)) * N_ + i);
        s.x += p.x; s.y += p.y; s.z += p.z; s.w += p.w;
    }
    *(float4*)(l + (size_t)b * N_ + i) = s;
}

// ---------------------------------------------------------------------------
// V'' = V * 2^13 * rcp(l') -> fp8 e4m3.  R23: each thread's 8B slot stored
// at perm16 position within its 128B n-group (matches gemm b128 reads).
// Reads (Vm, l) stay at original i.
// ---------------------------------------------------------------------------
__global__ void scale_v_kernel(const ushort_t* __restrict__ Vm, const float* __restrict__ l,
                               uchar_t* __restrict__ Vs) {
    const int i = (blockIdx.x * 256 + threadIdx.x) * 8;
    const int c = blockIdx.y, b = blockIdx.z;
    float4 l0 = *(const float4*)(l + (size_t)b * N_ + i);
    float4 l1 = *(const float4*)(l + (size_t)b * N_ + i + 4);
    float r[8] = {__builtin_amdgcn_rcpf(l0.x), __builtin_amdgcn_rcpf(l0.y),
                  __builtin_amdgcn_rcpf(l0.z), __builtin_amdgcn_rcpf(l0.w),
                  __builtin_amdgcn_rcpf(l1.x), __builtin_amdgcn_rcpf(l1.y),
                  __builtin_amdgcn_rcpf(l1.z), __builtin_amdgcn_rcpf(l1.w)};
    const size_t off = ((size_t)(b * C_ + c)) * N_ + i;
    uint4 v = *(const uint4*)(Vm + off);
    unsigned vw[4] = {v.x, v.y, v.z, v.w};
    float f[8];
#pragma unroll
    for (int q = 0; q < 4; ++q) {
        union { unsigned u; float fl; } lo, hi;
        lo.u = (vw[q] & 0xffffu) << 16;
        hi.u = vw[q] & 0xffff0000u;
        f[q * 2 + 0] = lo.fl * r[q * 2 + 0] * VSCALE;
        f[q * 2 + 1] = hi.fl * r[q * 2 + 1] * VSCALE;
    }
    int d0 = __builtin_amdgcn_cvt_pk_fp8_f32(f[0], f[1], 0, false);
    d0 = __builtin_amdgcn_cvt_pk_fp8_f32(f[2], f[3], d0, true);
    int d1 = __builtin_amdgcn_cvt_pk_fp8_f32(f[4], f[5], 0, false);
    d1 = __builtin_amdgcn_cvt_pk_fp8_f32(f[6], f[7], d1, true);
    uint2 o; o.x = (unsigned)d0; o.y = (unsigned)d1;
    const int i_p = (i & ~127) | perm16((i >> 3) & 15);
    *(uint2*)(Vs + ((size_t)(b * C_ + c)) * N_ + i_p) = o;
}

// ---------------------------------------------------------------------------
// Pass B v12 (R23): fp8 GEMM with b128 LDS reads.  Vs/PT i-axes are perm16-
// permuted so chunk (p*4+g) ^ (row&7) holds the (ks=2p, 2p+1) fragment pair:
// 8 b128/wave/t (was 16 b64), conflict-free 8-lane phases.  Proven 2-phase
// dbuf skeleton + NT streams unchanged.
// ---------------------------------------------------------------------------
__global__ __launch_bounds__(512, 4)
void gemm_out2_kernel(const uchar_t* __restrict__ A /*Vs fp8 [B][C][N] perm*/,
                      const uchar_t* __restrict__ Bm /*PT fp8 [B][N][N] perm*/,
                      const float* __restrict__ R /*x_s2 as [B][C][N]*/,
                      float* __restrict__ out) {
    __shared__ uchar_t smem[73728];   // 2 x (32 KB A + 4 KB B)
    const int tid = threadIdx.x;
    const int lane = tid & 63, g = lane >> 4, c16 = lane & 15;
    const int w = tid >> 6;
    const int cw = w * 32;              // wave's 32-c band
    const int b = blockIdx.y;
    const int jb = blockIdx.x * 32;

    f32x4 acc[2][2];
#pragma unroll
    for (int mt = 0; mt < 2; ++mt)
#pragma unroll
        for (int nt = 0; nt < 2; ++nt) acc[mt][nt] = (f32x4){0.f, 0.f, 0.f, 0.f};

    const int sch = tid & 7;          // chunk slot within row

    auto stage = [&](int k0, int dbase) {
#pragma unroll
        for (int q = 0; q < 4; ++q) {
            const int slot = q * 512 + tid;
            const int row = slot >> 3;
            const int gc = sch ^ (row & 7);
            const uchar_t* src = A + ((size_t)(b * C_ + row)) * N_ + k0 + gc * 16;
            __builtin_amdgcn_global_load_lds((gas_t)src, (las_t)&smem[dbase + slot * 16], 16, 0, 0);
        }
        if (tid < 256) {
            const int row = tid >> 3;
            const int gc = sch ^ (row & 7);
            const uchar_t* src = Bm + ((size_t)(b * N_ + jb + row)) * N_ + k0 + gc * 16;
            __builtin_amdgcn_global_load_lds((gas_t)src, (las_t)&smem[dbase + 32768 + tid * 16], 16, 0, 2);
        }
    };

    stage(0, 0);
    __syncthreads();                     // pipeline fill
    for (int t = 0; t < 32; ++t) {
        const int dbase = (t & 1) * 36864;
        if (t < 31) stage((t + 1) * 128, 36864 - dbase);   // prefetch other buf
        const uchar_t* sA = &smem[dbase];
        const uchar_t* sB = &smem[dbase + 32768];
        longx2 a2[2][2], b2[2][2];
#pragma unroll
        for (int p = 0; p < 2; ++p) {
#pragma unroll
            for (int mt = 0; mt < 2; ++mt) {
                const int row = cw + mt * 16 + c16;
                a2[mt][p] = *(const longx2*)&sA[row * 128 + (((p * 4 + g) ^ (row & 7)) * 16)];
            }
#pragma unroll
            for (int nt = 0; nt < 2; ++nt) {
                const int row = nt * 16 + c16;
                b2[nt][p] = *(const longx2*)&sB[row * 128 + (((p * 4 + g) ^ (row & 7)) * 16)];
            }
        }
#pragma unroll
        for (int ks = 0; ks < 4; ++ks)
#pragma unroll
            for (int mt = 0; mt < 2; ++mt)
#pragma unroll
                for (int nt = 0; nt < 2; ++nt)
                    acc[mt][nt] = __builtin_amdgcn_mfma_f32_16x16x32_fp8_fp8(
                        a2[mt][ks >> 1][ks & 1], b2[nt][ks >> 1][ks & 1], acc[mt][nt], 0, 0, 0);
        __syncthreads();   // waits prefetch + frees buf for next stage
    }
    // epilogue: out = residual + acc * 2^-13 (nontemporal fp32 stream)
#pragma unroll
    for (int mt = 0; mt < 2; ++mt)
#pragma unroll
        for (int r = 0; r < 4; ++r) {
            const int c = cw + mt * 16 + g * 4 + r;
            const size_t rowoff = ((size_t)(b * C_ + c)) * N_ + jb;
#pragma unroll
            for (int nt = 0; nt < 2; ++nt) {
                const int j = nt * 16 + c16;
                float rv = __builtin_nontemporal_load(&R[rowoff + j]);
                __builtin_nontemporal_store(rv + acc[mt][nt][r] * VSCALE_INV,
                                            &out[rowoff + j]);
            }
        }
}

// ---------------------------------------------------------------------------
// Fallback Pass B (unchanged; used when ws small).  Needs bf16 Kt/Qt/Vm and
// UNSHIFTED l (fallback stats uses sh=0 + atomics).
// ---------------------------------------------------------------------------
__global__ __launch_bounds__(512, 4)
void out_kernel(const ushort_t* __restrict__ Kt, const ushort_t* __restrict__ Qt,
                const ushort_t* __restrict__ V, const float* __restrict__ l,
                float* __restrict__ dout) {
    __shared__ ushort_t sQ[64][264];
    __shared__ ushort_t sP[64][264];
    const int tid = threadIdx.x;
    const int w = tid >> 6, lane = tid & 63, g = lane >> 4, c16 = lane & 15;
    const int b = blockIdx.z;
    const int jb = blockIdx.x * 64;
    const int ibase = blockIdx.y * 2048;
    {
        const int jl = tid >> 3, cp = (tid & 7) * 32;
        const ushort_t* src = Qt + ((size_t)(b * N_ + jb + jl)) * C_ + cp;
        uint4 a0 = *(const uint4*)(src);
        uint4 a1 = *(const uint4*)(src + 8);
        uint4 a2 = *(const uint4*)(src + 16);
        uint4 a3 = *(const uint4*)(src + 24);
        *(uint4*)&sQ[jl][cp + 0]  = a0;
        *(uint4*)&sQ[jl][cp + 8]  = a1;
        *(uint4*)&sQ[jl][cp + 16] = a2;
        *(uint4*)&sQ[jl][cp + 24] = a3;
    }
    f32x4 acc[2][4];
#pragma unroll
    for (int mt = 0; mt < 2; ++mt)
#pragma unroll
        for (int nt = 0; nt < 4; ++nt) acc[mt][nt] = (f32x4){0.f, 0.f, 0.f, 0.f};

    const int bw = w * 32;

    for (int ic = 0; ic < 8; ++ic) {
        const int i0 = ibase + ic * 256;
        float rv[2][4];
#pragma unroll
        for (int mt = 0; mt < 2; ++mt) {
            float4 lr = *(const float4*)(l + (size_t)b * N_ + i0 + bw + mt * 16 + g * 4);
            rv[mt][0] = __builtin_amdgcn_logf(lr.x);
            rv[mt][1] = __builtin_amdgcn_logf(lr.y);
            rv[mt][2] = __builtin_amdgcn_logf(lr.z);
            rv[mt][3] = __builtin_amdgcn_logf(lr.w);
        }
        __syncthreads();
        f32x4 sa[2][4];
#pragma unroll
        for (int mt = 0; mt < 2; ++mt)
#pragma unroll
            for (int nt = 0; nt < 4; ++nt) sa[mt][nt] = (f32x4){0.f, 0.f, 0.f, 0.f};
#pragma unroll
        for (int k = 0; k < 8; ++k) {
            bf16x8 av[2];
#pragma unroll
            for (int mt = 0; mt < 2; ++mt)
                av[mt] = ld_bf8(Kt + ((size_t)(b * N_ + i0 + bw + mt * 16 + c16)) * C_ + k * 32 + g * 8);
#pragma unroll
            for (int nt = 0; nt < 4; ++nt) {
                bf16x8 bv = *(const bf16x8*)&sQ[nt * 16 + c16][k * 32 + g * 8];
#pragma unroll
                for (int mt = 0; mt < 2; ++mt)
                    sa[mt][nt] = __builtin_amdgcn_mfma_f32_16x16x32_bf16(av[mt], bv, sa[mt][nt], 0, 0, 0);
            }
        }
#pragma unroll
        for (int mt = 0; mt < 2; ++mt)
#pragma unroll
            for (int nt = 0; nt < 4; ++nt) {
                const int j = nt * 16 + c16;
                unsigned p0 = f2bf(__builtin_amdgcn_exp2f(sa[mt][nt][0] - rv[mt][0]));
                unsigned p1 = f2bf(__builtin_amdgcn_exp2f(sa[mt][nt][1] - rv[mt][1]));
                unsigned p2 = f2bf(__builtin_amdgcn_exp2f(sa[mt][nt][2] - rv[mt][2]));
                unsigned p3 = f2bf(__builtin_amdgcn_exp2f(sa[mt][nt][3] - rv[mt][3]));
                uint2 pk; pk.x = p0 | (p1 << 16); pk.y = p2 | (p3 << 16);
                *(uint2*)&sP[j][bw + mt * 16 + g * 4] = pk;
            }
        __syncthreads();
#pragma unroll
        for (int ks = 0; ks < 8; ++ks) {
            bf16x8 va[2];
#pragma unroll
            for (int mt = 0; mt < 2; ++mt)
                va[mt] = ld_bf8(V + ((size_t)(b * C_ + bw + mt * 16 + c16)) * N_ + i0 + ks * 32 + g * 8);
#pragma unroll
            for (int nt = 0; nt < 4; ++nt) {
                bf16x8 pb = *(const bf16x8*)&sP[nt * 16 + c16][ks * 32 + g * 8];
#pragma unroll
                for (int mt = 0; mt < 2; ++mt)
                    acc[mt][nt] = __builtin_amdgcn_mfma_f32_16x16x32_bf16(va[mt], pb, acc[mt][nt], 0, 0, 0);
            }
        }
    }
#pragma unroll
    for (int mt = 0; mt < 2; ++mt)
#pragma unroll
        for (int nt = 0; nt < 4; ++nt)
#pragma unroll
            for (int r = 0; r < 4; ++r) {
                const int c = bw + mt * 16 + g * 4 + r;
                const int j = jb + nt * 16 + c16;
                atomicAdd(dout + ((size_t)b * C_ + c) * N_ + j, acc[mt][nt][r]);
            }
}

extern "C" void kernel_launch(void* const* d_in, const int* in_sizes, int n_in,
                              void* d_out, int out_size, void* d_ws, size_t ws_size,
                              hipStream_t stream) {
    const float* x_s2  = (const float*)d_in[0];
    const float* x_dem = (const float*)d_in[1];
    const float* Wq = (const float*)d_in[2];
    const float* bq = (const float*)d_in[3];
    const float* Wk = (const float*)d_in[4];
    const float* bk = (const float*)d_in[5];
    const float* Wv = (const float*)d_in[6];
    const float* bv = (const float*)d_in[7];
    float* out = (float*)d_out;

    const size_t MiB = 1024 * 1024;
    char* ws = (char*)d_ws;
    ushort_t* Qt = (ushort_t*)(ws);               // [B][N][C] bf16 (fallback) /
    uchar_t*  Qt8 = (uchar_t*)(ws);               //   fp8 Q' perm8 (bigws)
    ushort_t* Kt = (ushort_t*)(ws + 8  * MiB);    // [B][N][C] bf16 (fallback) /
    uchar_t*  Kt8 = (uchar_t*)(ws + 8 * MiB);     //   fp8 K' perm8 (bigws)
    ushort_t* Vm = (ushort_t*)(ws + 16 * MiB);    // [B][C][N] bf16, 8 MiB
    uchar_t*  Vs = (uchar_t*) (ws + 24 * MiB);    // [B][C][N] fp8 V'' perm16
    float*    lp = (float*)   (ws + 24 * MiB);    // [B][32][N] partials, 2 MiB
                                                  //   (aliases Vs: dead before
                                                  //    scale_v writes Vs)
    float*    lv = (float*)   (ws + 28 * MiB);    // [B][N] row sums, 64 KiB
    uchar_t*  PT = (uchar_t*) (ws + 29 * MiB);    // [B][N(j)][N(i)] fp8 perm16
    const bool bigws = ws_size >= 93 * MiB;

    if (!bigws) {
        hipMemsetAsync(lv, 0, (size_t)B_ * N_ * sizeof(float), stream);
        hipMemcpyAsync(out, x_s2, (size_t)B_ * C_ * N_ * sizeof(float),
                       hipMemcpyDeviceToDevice, stream);
    }

    proj_q_mfma<<<dim3(N_ / 128, C_ / 64, B_), 256, 0, stream>>>(
        x_s2, Wq, bq, Qt, bigws ? Qt8 : (uchar_t*)nullptr, C_);
    proj_kv_mfma<<<dim3(N_ / 128, C_ / 64, B_), 256, 0, stream>>>(
        x_dem, Wk, bk, Wv, bv, Kt, bigws ? Kt8 : (uchar_t*)nullptr, Vm);
    if (bigws) {
        stats_fp8_kernel<<<dim3(N_ / 128, N_ / 128, B_), 256, 0, stream>>>(Kt8, Qt8, PT, lp);
        reduce_l_kernel<<<dim3(N_ / 1024, B_), 256, 0, stream>>>(lp, lv);
        scale_v_kernel<<<dim3(N_ / 2048, C_, B_), 256, 0, stream>>>(Vm, lv, Vs);
        gemm_out2_kernel<<<dim3(N_ / 32, B_), 512, 0, stream>>>(Vs, PT, x_s2, out);
    } else {
        stats_kernel<<<dim3(N_ / 128, N_ / 128, B_), 256, 0, stream>>>(Kt, Qt, lv);
        out_kernel<<<dim3(N_ / 64, 2, B_), 512, 0, stream>>>(Kt, Qt, Vm, lv, out);
    }
}

// Round 12
// 178.355 us; speedup vs baseline: 1.2187x; 1.0863x over previous
//
#include <hip/hip_runtime.h>
#include <hip/hip_bf16.h>
#include <cstdint>

#define B_  4
#define N_  4096
#define C_  256
#define CD_ 64

typedef unsigned short ushort_t;
typedef unsigned char uchar_t;
typedef __bf16 bf16x8 __attribute__((ext_vector_type(8)));
typedef float f32x4 __attribute__((ext_vector_type(4)));
typedef unsigned int u32x4 __attribute__((ext_vector_type(4)));
typedef long longx2 __attribute__((ext_vector_type(2)));

typedef const __attribute__((address_space(1))) void* gas_t;
typedef __attribute__((address_space(3))) void* las_t;

// (1/sqrt(256)) * log2(e): folded into K projection so S' = S_true * log2(e)
static constexpr float SCALE_LOG2E = 0.09016844005556021f;
// R22 fp8 split: K' = k*(log2e/4), Q' = q/4  ->  K'.Q' = k.q*log2e/16 exactly.
static constexpr float SCALE_K8 = 0.3606737602222408f;   // log2e/4
static constexpr float SCALE_Q8 = 0.25f;
// V' scale 2^13 (undone in gemm epilogue); PT exponent shift -3 cancels via l.
static constexpr float VSCALE = 8192.0f;
static constexpr float VSCALE_INV = 1.0f / 8192.0f;

__device__ __forceinline__ ushort_t f2bf(float x) {
    union { float f; unsigned u; } v; v.f = x;
    unsigned u = v.u;
    unsigned r = (u + 0x7fffu + ((u >> 16) & 1u)) >> 16;  // round-nearest-even
    return (ushort_t)r;
}

__device__ __forceinline__ uchar_t f2fp8(float x) {
    return (uchar_t)(__builtin_amdgcn_cvt_pk_fp8_f32(x, x, 0, false) & 0xff);
}

__device__ __forceinline__ bf16x8 ld_bf8(const ushort_t* p) {
    return *reinterpret_cast<const bf16x8*>(p);
}

// R23 slot permutations (dot products invariant under common k-permutation):
// 128B group, 16 slots of 8B: chunk L=p*4+g holds slots (2p*4+g, (2p+1)*4+g)
// -> one b128 read per lane covers two K=32 MFMA steps, conflict-free.
__device__ __forceinline__ int perm16(int s) {   // slot 0..15 -> byte pos
    return (((s & 3) | ((s >> 1) & 4)) << 4) | ((s & 4) << 1);
}
// 64B group, 8 slots of 8B: chunk g holds slots (g, g+4).
__device__ __forceinline__ int perm8(int s) {    // slot 0..7 -> byte pos
    return ((s & 3) << 4) | ((s & 4) << 1);
}

// ---------------------------------------------------------------------------
// MFMA projection -> TRANSPOSED layout (proven R8).  R22: fp8 epilogue for
// big-ws; R23: fp8 column o stored at perm8 position within each 64B group
// (matches stats_fp8's b128 reads).  bf16 fallback path untouched.
// ---------------------------------------------------------------------------
__global__ __launch_bounds__(256, 4)
void proj_q_mfma(const float* __restrict__ X, const float* __restrict__ W,
                 const float* __restrict__ bias, ushort_t* __restrict__ dst,
                 uchar_t* __restrict__ dst8, int Cin) {
    __shared__ ushort_t sX[128][72];   // [n][c] bf16
    __shared__ ushort_t sW[64][72];    // [o][c] bf16
    const int tid = threadIdx.x;
    const int lane = tid & 63, g = lane >> 4, c16 = lane & 15;
    const int w = tid >> 6, wi = w >> 1, wj = w & 1;   // n-half, o-half
    const int b = blockIdx.z, nb = blockIdx.x * 128, ob = blockIdx.y * 64;
    f32x4 acc[4][2];
#pragma unroll
    for (int nt = 0; nt < 4; ++nt)
#pragma unroll
        for (int ot = 0; ot < 2; ++ot) acc[nt][ot] = (f32x4){0.f, 0.f, 0.f, 0.f};

    const int cr = tid >> 5;
    const int n0 = (tid & 31) * 4;

    for (int k0 = 0; k0 < Cin; k0 += 64) {
#pragma unroll
        for (int p = 0; p < 8; ++p) {
            const int c = p * 8 + cr;
            float4 xv = *(const float4*)(X + ((size_t)b * Cin + k0 + c) * N_ + nb + n0);
            sX[n0 + 0][c] = f2bf(xv.x);
            sX[n0 + 1][c] = f2bf(xv.y);
            sX[n0 + 2][c] = f2bf(xv.z);
            sX[n0 + 3][c] = f2bf(xv.w);
        }
        {
            const int o = tid >> 2, cq = (tid & 3) * 16;
            const float* wsrc = W + (size_t)(ob + o) * Cin + k0 + cq;
            alignas(16) ushort_t tmp[16];
#pragma unroll
            for (int q = 0; q < 16; ++q) tmp[q] = f2bf(wsrc[q]);
            *(uint4*)&sW[o][cq]     = *(uint4*)&tmp[0];
            *(uint4*)&sW[o][cq + 8] = *(uint4*)&tmp[8];
        }
        __syncthreads();
#pragma unroll
        for (int ks = 0; ks < 2; ++ks) {
            bf16x8 af[4], bfr[2];
#pragma unroll
            for (int nt = 0; nt < 4; ++nt)
                af[nt] = *(const bf16x8*)&sX[wi * 64 + nt * 16 + c16][ks * 32 + g * 8];
#pragma unroll
            for (int ot = 0; ot < 2; ++ot)
                bfr[ot] = *(const bf16x8*)&sW[wj * 32 + ot * 16 + c16][ks * 32 + g * 8];
#pragma unroll
            for (int nt = 0; nt < 4; ++nt)
#pragma unroll
                for (int ot = 0; ot < 2; ++ot)
                    acc[nt][ot] = __builtin_amdgcn_mfma_f32_16x16x32_bf16(af[nt], bfr[ot], acc[nt][ot], 0, 0, 0);
        }
        __syncthreads();
    }
#pragma unroll
    for (int ot = 0; ot < 2; ++ot) {
        const int o = ob + wj * 32 + ot * 16 + c16;
        const float bia = bias[o];
        const int o_p = (o & ~63) | perm8((o >> 3) & 7) | (o & 7);
#pragma unroll
        for (int nt = 0; nt < 4; ++nt) {
#pragma unroll
            for (int r = 0; r < 4; ++r) {
                const int n = nb + wi * 64 + nt * 16 + g * 4 + r;
                const float v = acc[nt][ot][r] + bia;
                if (dst8 != nullptr)
                    dst8[((size_t)b * N_ + n) * C_ + o_p] = f2fp8(v * SCALE_Q8);
                else
                    dst[((size_t)b * N_ + n) * C_ + o] = f2bf(v);
            }
        }
    }
}

// ---------------------------------------------------------------------------
// Fused K+V MFMA projection from x_dem (proven R8).  R22/R23: fp8 K path
// with perm8 column placement; V always bf16.
// ---------------------------------------------------------------------------
__global__ __launch_bounds__(256, 4)
void proj_kv_mfma(const float* __restrict__ X, const float* __restrict__ Wk,
                  const float* __restrict__ bk, const float* __restrict__ Wv,
                  const float* __restrict__ bv, ushort_t* __restrict__ Kt,
                  uchar_t* __restrict__ Kt8, ushort_t* __restrict__ Vm) {
    __shared__ ushort_t sX[128][72];   // [n][c]
    __shared__ ushort_t sWk[64][72];   // [o][c]
    __shared__ ushort_t sWv[64][72];
    const int tid = threadIdx.x;
    const int lane = tid & 63, g = lane >> 4, c16 = lane & 15;
    const int w = tid >> 6;
    const int b = blockIdx.z, nb = blockIdx.x * 128, ob = blockIdx.y * 64;

    {
        const int cr = tid >> 5, n0 = (tid & 31) * 4;
#pragma unroll
        for (int p = 0; p < 8; ++p) {
            const int c = p * 8 + cr;
            float4 xv = *(const float4*)(X + ((size_t)b * CD_ + c) * N_ + nb + n0);
            sX[n0 + 0][c] = f2bf(xv.x);
            sX[n0 + 1][c] = f2bf(xv.y);
            sX[n0 + 2][c] = f2bf(xv.z);
            sX[n0 + 3][c] = f2bf(xv.w);
        }
        const int o = tid >> 2, cq = (tid & 3) * 16;
        alignas(16) ushort_t tk[16], tv[16];
        const float* ksrc = Wk + (size_t)(ob + o) * CD_ + cq;
        const float* vsrc = Wv + (size_t)(ob + o) * CD_ + cq;
#pragma unroll
        for (int q = 0; q < 16; ++q) { tk[q] = f2bf(ksrc[q]); tv[q] = f2bf(vsrc[q]); }
        *(uint4*)&sWk[o][cq]     = *(uint4*)&tk[0];
        *(uint4*)&sWk[o][cq + 8] = *(uint4*)&tk[8];
        *(uint4*)&sWv[o][cq]     = *(uint4*)&tv[0];
        *(uint4*)&sWv[o][cq + 8] = *(uint4*)&tv[8];
    }
    __syncthreads();
    // ---- K-part ----
    {
        const int wi = w >> 1, wj = w & 1;
        f32x4 acc[4][2];
#pragma unroll
        for (int nt = 0; nt < 4; ++nt)
#pragma unroll
            for (int ot = 0; ot < 2; ++ot) acc[nt][ot] = (f32x4){0.f, 0.f, 0.f, 0.f};
#pragma unroll
        for (int ks = 0; ks < 2; ++ks) {
            bf16x8 af[4], bfr[2];
#pragma unroll
            for (int nt = 0; nt < 4; ++nt)
                af[nt] = *(const bf16x8*)&sX[wi * 64 + nt * 16 + c16][ks * 32 + g * 8];
#pragma unroll
            for (int ot = 0; ot < 2; ++ot)
                bfr[ot] = *(const bf16x8*)&sWk[wj * 32 + ot * 16 + c16][ks * 32 + g * 8];
#pragma unroll
            for (int nt = 0; nt < 4; ++nt)
#pragma unroll
                for (int ot = 0; ot < 2; ++ot)
                    acc[nt][ot] = __builtin_amdgcn_mfma_f32_16x16x32_bf16(af[nt], bfr[ot], acc[nt][ot], 0, 0, 0);
        }
#pragma unroll
        for (int ot = 0; ot < 2; ++ot) {
            const int o = ob + wj * 32 + ot * 16 + c16;
            const float bia = bk[o];
            const int o_p = (o & ~63) | perm8((o >> 3) & 7) | (o & 7);
#pragma unroll
            for (int nt = 0; nt < 4; ++nt)
#pragma unroll
                for (int r = 0; r < 4; ++r) {
                    const int n = nb + wi * 64 + nt * 16 + g * 4 + r;
                    const float v = acc[nt][ot][r] + bia;
                    if (Kt8 != nullptr)
                        Kt8[((size_t)b * N_ + n) * C_ + o_p] = f2fp8(v * SCALE_K8);
                    else
                        Kt[((size_t)b * N_ + n) * C_ + o] = f2bf(v * SCALE_LOG2E);
                }
        }
    }
    // ---- V-part ----
    {
        const int ow = w & 1, nw = w >> 1;
        f32x4 acc[2][4];
#pragma unroll
        for (int mt = 0; mt < 2; ++mt)
#pragma unroll
            for (int nt = 0; nt < 4; ++nt) acc[mt][nt] = (f32x4){0.f, 0.f, 0.f, 0.f};
#pragma unroll
        for (int ks = 0; ks < 2; ++ks) {
            bf16x8 af[2], bfr[4];
#pragma unroll
            for (int mt = 0; mt < 2; ++mt)
                af[mt] = *(const bf16x8*)&sWv[ow * 32 + mt * 16 + c16][ks * 32 + g * 8];
#pragma unroll
            for (int nt = 0; nt < 4; ++nt)
                bfr[nt] = *(const bf16x8*)&sX[nw * 64 + nt * 16 + c16][ks * 32 + g * 8];
#pragma unroll
            for (int mt = 0; mt < 2; ++mt)
#pragma unroll
                for (int nt = 0; nt < 4; ++nt)
                    acc[mt][nt] = __builtin_amdgcn_mfma_f32_16x16x32_bf16(af[mt], bfr[nt], acc[mt][nt], 0, 0, 0);
        }
#pragma unroll
        for (int mt = 0; mt < 2; ++mt) {
            const float4 bi4 = *(const float4*)(bv + ob + ow * 32 + mt * 16 + g * 4);
            const float bia[4] = {bi4.x, bi4.y, bi4.z, bi4.w};
#pragma unroll
            for (int nt = 0; nt < 4; ++nt) {
                const int n = nb + nw * 64 + nt * 16 + c16;
#pragma unroll
                for (int r = 0; r < 4; ++r) {
                    const int o = ob + ow * 32 + mt * 16 + g * 4 + r;
                    Vm[((size_t)b * C_ + o) * N_ + n] = f2bf(acc[mt][nt][r] + bia[r]);
                }
            }
        }
    }
}

// ---------------------------------------------------------------------------
// Pass A v12 (R24): fp8 QK^T, b128 LDS reads (R23, conflict-free verified).
// PT streamout now PLAIN stores (was NT): R11 showed gemm's PT staging pays
// HBM-miss latency (FETCH 57.5 MB ~= whole PT from HBM) because NT streams
// bypass L3.  Plain stores write back through L2 into the 256 MB L3 ->
// gemm reads PT L3-served.  R3<->R4 A/B proved plain-vs-NT is TIME-NULL for
// stats itself (only WRITE traffic inflates, cosmetic).
// ---------------------------------------------------------------------------
__global__ __launch_bounds__(256, 4)
void stats_fp8_kernel(const uchar_t* __restrict__ Kt8, const uchar_t* __restrict__ Qt8,
                      uchar_t* __restrict__ PT8, float* __restrict__ lpart) {
    __shared__ uchar_t smem8[32768];   // 2 x (8 KB A + 8 KB B); epilogue reuse
    uchar_t* sp8 = smem8;                      // epilogue: [128][144] fp8 tile
    float* lsum = (float*)(smem8 + 18432);     // [2][128] row partials
    const int tid = threadIdx.x;
    const int lane = tid & 63, g = lane >> 4, c16 = lane & 15;
    const int w = tid >> 6, wi = w >> 1, wj = w & 1;
    const int b = blockIdx.z;
    const int ib = blockIdx.y * 128, jb = blockIdx.x * 128;
    f32x4 acc[4][4];
#pragma unroll
    for (int mt = 0; mt < 4; ++mt)
#pragma unroll
        for (int nt = 0; nt < 4; ++nt) acc[mt][nt] = (f32x4){0.f, 0.f, 0.f, 0.f};

    const int srow = tid >> 2;   // 0..63 (row within 64-row half)
    const int sc = tid & 3;      // 16B chunk slot within 64B row

    auto stage = [&](int kc, int dbase) {      // kc: 64-wide K chunk index
#pragma unroll
        for (int q = 0; q < 2; ++q) {
            const int row = q * 64 + srow;
            const int gc = sc ^ ((row >> 1) & 3);
            const uchar_t* srcA = Kt8 + ((size_t)(b * N_ + ib + row)) * C_ + kc * 64 + gc * 16;
            const uchar_t* srcB = Qt8 + ((size_t)(b * N_ + jb + row)) * C_ + kc * 64 + gc * 16;
            __builtin_amdgcn_global_load_lds((gas_t)srcA, (las_t)&smem8[dbase + (q * 256 + tid) * 16], 16, 0, 0);
            __builtin_amdgcn_global_load_lds((gas_t)srcB, (las_t)&smem8[dbase + 8192 + (q * 256 + tid) * 16], 16, 0, 0);
        }
    };

    stage(0, 0);
    __syncthreads();                 // pipeline fill
    for (int t = 0; t < 4; ++t) {
        const int dbase = (t & 1) * 16384;
        if (t < 3) stage(t + 1, 16384 - dbase);   // prefetch other buf
        longx2 a2[4], b2[4];
#pragma unroll
        for (int mt = 0; mt < 4; ++mt) {
            const int row = wi * 64 + mt * 16 + c16;
            a2[mt] = *(const longx2*)&smem8[dbase + row * 64 + ((g ^ ((row >> 1) & 3)) * 16)];
        }
#pragma unroll
        for (int nt = 0; nt < 4; ++nt) {
            const int row = wj * 64 + nt * 16 + c16;
            b2[nt] = *(const longx2*)&smem8[dbase + 8192 + row * 64 + ((g ^ ((row >> 1) & 3)) * 16)];
        }
#pragma unroll
        for (int ks = 0; ks < 2; ++ks)
#pragma unroll
            for (int mt = 0; mt < 4; ++mt)
#pragma unroll
                for (int nt = 0; nt < 4; ++nt)
                    acc[mt][nt] = __builtin_amdgcn_mfma_f32_16x16x32_fp8_fp8(a2[mt][ks], b2[nt][ks], acc[mt][nt], 0, 0, 0);
        __syncthreads();   // waits prefetch (vmcnt) + frees buf for next stage
    }
    const float sh = 3.0f;
#pragma unroll
    for (int mt = 0; mt < 4; ++mt) {
        float rs[4] = {0.f, 0.f, 0.f, 0.f};
#pragma unroll
        for (int nt = 0; nt < 4; ++nt) {
            float e0 = __builtin_amdgcn_exp2f(acc[mt][nt][0] - sh);
            float e1 = __builtin_amdgcn_exp2f(acc[mt][nt][1] - sh);
            float e2 = __builtin_amdgcn_exp2f(acc[mt][nt][2] - sh);
            float e3 = __builtin_amdgcn_exp2f(acc[mt][nt][3] - sh);
            rs[0] += e0; rs[1] += e1; rs[2] += e2; rs[3] += e3;
            int pk = __builtin_amdgcn_cvt_pk_fp8_f32(e0, e1, 0, false);
            pk = __builtin_amdgcn_cvt_pk_fp8_f32(e2, e3, pk, true);
            const int jl = wj * 64 + nt * 16 + c16;
            const int il = wi * 64 + mt * 16 + g * 4;
            // R23: PT i-axis perm16 within 128B group (matches gemm b128 reads)
            const int il_p = perm16(il >> 3) | (il & 7);
            *(int*)&sp8[jl * 144 + il_p] = pk;
        }
#pragma unroll
        for (int r = 0; r < 4; ++r) {
            float s = rs[r];
            s += __shfl_xor(s, 1, 64);
            s += __shfl_xor(s, 2, 64);
            s += __shfl_xor(s, 4, 64);
            s += __shfl_xor(s, 8, 64);
            if (c16 == 0)
                lsum[wj * 128 + wi * 64 + mt * 16 + g * 4 + r] = s;
        }
    }
    __syncthreads();
    // stream out: 128 rows x 128 B (fp8), PLAIN stores -> L3-resident for gemm
    {
        const int chb = tid & 7;     // 16B chunk within row
        const int rb = tid >> 3;     // 32 rows per pass
#pragma unroll
        for (int r = 0; r < 4; ++r) {
            const int jl = r * 32 + rb;
            u32x4 v = *(const u32x4*)&sp8[jl * 144 + chb * 16];
            *(u32x4*)(PT8 + ((size_t)(b * N_ + jb + jl)) * N_ + ib + chb * 16) = v;
        }
        // per-block row-sum partial: one coalesced 512 B store, no atomics
        if (tid < 128) {
            float tot = lsum[tid] + lsum[128 + tid];
            lpart[((size_t)(b * 32 + (jb >> 7))) * N_ + ib + tid] = tot;
        }
    }
}

// ---------------------------------------------------------------------------
// Fallback Pass A (bf16, R4 structure, atomic l path) — used when ws small.
// ---------------------------------------------------------------------------
__global__ __launch_bounds__(256, 4)
void stats_kernel(const ushort_t* __restrict__ Kt, const ushort_t* __restrict__ Qt,
                  float* __restrict__ l) {
    __shared__ ushort_t smem[16384];
    uchar_t* smem8 = (uchar_t*)smem;
    const int tid = threadIdx.x;
    const int lane = tid & 63, g = lane >> 4, c16 = lane & 15;
    const int w = tid >> 6, wi = w >> 1, wj = w & 1;
    const int b = blockIdx.z;
    const int ib = blockIdx.y * 128, jb = blockIdx.x * 128;
    f32x4 acc[4][4];
#pragma unroll
    for (int mt = 0; mt < 4; ++mt)
#pragma unroll
        for (int nt = 0; nt < 4; ++nt) acc[mt][nt] = (f32x4){0.f, 0.f, 0.f, 0.f};

    const int srow = tid >> 2;
    const int sc = tid & 3;

    auto stage = [&](int kc, int dbase) {
#pragma unroll
        for (int q = 0; q < 2; ++q) {
            const int row = q * 64 + srow;
            const int gc = sc ^ ((row >> 1) & 3);
            const ushort_t* srcA = Kt + ((size_t)(b * N_ + ib + row)) * C_ + kc * 32 + gc * 8;
            const ushort_t* srcB = Qt + ((size_t)(b * N_ + jb + row)) * C_ + kc * 32 + gc * 8;
            __builtin_amdgcn_global_load_lds((gas_t)srcA, (las_t)&smem8[dbase + (q * 256 + tid) * 16], 16, 0, 0);
            __builtin_amdgcn_global_load_lds((gas_t)srcB, (las_t)&smem8[dbase + 8192 + (q * 256 + tid) * 16], 16, 0, 0);
        }
    };

    stage(0, 0);
    __syncthreads();
    for (int t = 0; t < 8; ++t) {
        const int dbase = (t & 1) * 16384;
        if (t < 7) stage(t + 1, 16384 - dbase);
        bf16x8 af[4], bf[4];
#pragma unroll
        for (int mt = 0; mt < 4; ++mt) {
            const int row = wi * 64 + mt * 16 + c16;
            af[mt] = *(const bf16x8*)&smem8[dbase + row * 64 + ((g ^ ((row >> 1) & 3)) * 16)];
        }
#pragma unroll
        for (int nt = 0; nt < 4; ++nt) {
            const int row = wj * 64 + nt * 16 + c16;
            bf[nt] = *(const bf16x8*)&smem8[dbase + 8192 + row * 64 + ((g ^ ((row >> 1) & 3)) * 16)];
        }
#pragma unroll
        for (int mt = 0; mt < 4; ++mt)
#pragma unroll
            for (int nt = 0; nt < 4; ++nt)
                acc[mt][nt] = __builtin_amdgcn_mfma_f32_16x16x32_bf16(af[mt], bf[nt], acc[mt][nt], 0, 0, 0);
        __syncthreads();
    }
#pragma unroll
    for (int mt = 0; mt < 4; ++mt) {
        float rs[4] = {0.f, 0.f, 0.f, 0.f};
#pragma unroll
        for (int nt = 0; nt < 4; ++nt) {
            rs[0] += __builtin_amdgcn_exp2f(acc[mt][nt][0]);
            rs[1] += __builtin_amdgcn_exp2f(acc[mt][nt][1]);
            rs[2] += __builtin_amdgcn_exp2f(acc[mt][nt][2]);
            rs[3] += __builtin_amdgcn_exp2f(acc[mt][nt][3]);
        }
#pragma unroll
        for (int r = 0; r < 4; ++r) {
            float s = rs[r];
            s += __shfl_xor(s, 1, 64);
            s += __shfl_xor(s, 2, 64);
            s += __shfl_xor(s, 4, 64);
            s += __shfl_xor(s, 8, 64);
            if (c16 == 0)
                atomicAdd(l + (size_t)b * N_ + ib + wi * 64 + mt * 16 + g * 4 + r, s);
        }
    }
}

// ---------------------------------------------------------------------------
// l[b][i] = sum_jt lpart[b][jt][i]  (2 MB read, 64 KB write, ~1-2 us)
// ---------------------------------------------------------------------------
__global__ void reduce_l_kernel(const float* __restrict__ lpart, float* __restrict__ l) {
    const int b = blockIdx.y;
    const int i = (blockIdx.x * 256 + threadIdx.x) * 4;
    float4 s = {0.f, 0.f, 0.f, 0.f};
#pragma unroll
    for (int jt = 0; jt < 32; ++jt) {
        float4 p = *(const float4*)(lpart + ((size_t)(b * 32 + jt)) * N_ + i);
        s.x += p.x; s.y += p.y; s.z += p.z; s.w += p.w;
    }
    *(float4*)(l + (size_t)b * N_ + i) = s;
}

// ---------------------------------------------------------------------------
// V'' = V * 2^13 * rcp(l') -> fp8 e4m3.  R23: each thread's 8B slot stored
// at perm16 position within its 128B n-group (matches gemm b128 reads).
// Reads (Vm, l) stay at original i.
// ---------------------------------------------------------------------------
__global__ void scale_v_kernel(const ushort_t* __restrict__ Vm, const float* __restrict__ l,
                               uchar_t* __restrict__ Vs) {
    const int i = (blockIdx.x * 256 + threadIdx.x) * 8;
    const int c = blockIdx.y, b = blockIdx.z;
    float4 l0 = *(const float4*)(l + (size_t)b * N_ + i);
    float4 l1 = *(const float4*)(l + (size_t)b * N_ + i + 4);
    float r[8] = {__builtin_amdgcn_rcpf(l0.x), __builtin_amdgcn_rcpf(l0.y),
                  __builtin_amdgcn_rcpf(l0.z), __builtin_amdgcn_rcpf(l0.w),
                  __builtin_amdgcn_rcpf(l1.x), __builtin_amdgcn_rcpf(l1.y),
                  __builtin_amdgcn_rcpf(l1.z), __builtin_amdgcn_rcpf(l1.w)};
    const size_t off = ((size_t)(b * C_ + c)) * N_ + i;
    uint4 v = *(const uint4*)(Vm + off);
    unsigned vw[4] = {v.x, v.y, v.z, v.w};
    float f[8];
#pragma unroll
    for (int q = 0; q < 4; ++q) {
        union { unsigned u; float fl; } lo, hi;
        lo.u = (vw[q] & 0xffffu) << 16;
        hi.u = vw[q] & 0xffff0000u;
        f[q * 2 + 0] = lo.fl * r[q * 2 + 0] * VSCALE;
        f[q * 2 + 1] = hi.fl * r[q * 2 + 1] * VSCALE;
    }
    int d0 = __builtin_amdgcn_cvt_pk_fp8_f32(f[0], f[1], 0, false);
    d0 = __builtin_amdgcn_cvt_pk_fp8_f32(f[2], f[3], d0, true);
    int d1 = __builtin_amdgcn_cvt_pk_fp8_f32(f[4], f[5], 0, false);
    d1 = __builtin_amdgcn_cvt_pk_fp8_f32(f[6], f[7], d1, true);
    uint2 o; o.x = (unsigned)d0; o.y = (unsigned)d1;
    const int i_p = (i & ~127) | perm16((i >> 3) & 15);
    *(uint2*)(Vs + ((size_t)(b * C_ + c)) * N_ + i_p) = o;
}

// ---------------------------------------------------------------------------
// Pass B v12 (R23, conflict-free verified): fp8 GEMM with b128 LDS reads.
// 2-phase dbuf skeleton + NT fp32 epilogue streams unchanged.
// ---------------------------------------------------------------------------
__global__ __launch_bounds__(512, 4)
void gemm_out2_kernel(const uchar_t* __restrict__ A /*Vs fp8 [B][C][N] perm*/,
                      const uchar_t* __restrict__ Bm /*PT fp8 [B][N][N] perm*/,
                      const float* __restrict__ R /*x_s2 as [B][C][N]*/,
                      float* __restrict__ out) {
    __shared__ uchar_t smem[73728];   // 2 x (32 KB A + 4 KB B)
    const int tid = threadIdx.x;
    const int lane = tid & 63, g = lane >> 4, c16 = lane & 15;
    const int w = tid >> 6;
    const int cw = w * 32;              // wave's 32-c band
    const int b = blockIdx.y;
    const int jb = blockIdx.x * 32;

    f32x4 acc[2][2];
#pragma unroll
    for (int mt = 0; mt < 2; ++mt)
#pragma unroll
        for (int nt = 0; nt < 2; ++nt) acc[mt][nt] = (f32x4){0.f, 0.f, 0.f, 0.f};

    const int sch = tid & 7;          // chunk slot within row

    auto stage = [&](int k0, int dbase) {
#pragma unroll
        for (int q = 0; q < 4; ++q) {
            const int slot = q * 512 + tid;
            const int row = slot >> 3;
            const int gc = sch ^ (row & 7);
            const uchar_t* src = A + ((size_t)(b * C_ + row)) * N_ + k0 + gc * 16;
            __builtin_amdgcn_global_load_lds((gas_t)src, (las_t)&smem[dbase + slot * 16], 16, 0, 0);
        }
        if (tid < 256) {
            const int row = tid >> 3;
            const int gc = sch ^ (row & 7);
            const uchar_t* src = Bm + ((size_t)(b * N_ + jb + row)) * N_ + k0 + gc * 16;
            __builtin_amdgcn_global_load_lds((gas_t)src, (las_t)&smem[dbase + 32768 + tid * 16], 16, 0, 2);
        }
    };

    stage(0, 0);
    __syncthreads();                     // pipeline fill
    for (int t = 0; t < 32; ++t) {
        const int dbase = (t & 1) * 36864;
        if (t < 31) stage((t + 1) * 128, 36864 - dbase);   // prefetch other buf
        const uchar_t* sA = &smem[dbase];
        const uchar_t* sB = &smem[dbase + 32768];
        longx2 a2[2][2], b2[2][2];
#pragma unroll
        for (int p = 0; p < 2; ++p) {
#pragma unroll
            for (int mt = 0; mt < 2; ++mt) {
                const int row = cw + mt * 16 + c16;
                a2[mt][p] = *(const longx2*)&sA[row * 128 + (((p * 4 + g) ^ (row & 7)) * 16)];
            }
#pragma unroll
            for (int nt = 0; nt < 2; ++nt) {
                const int row = nt * 16 + c16;
                b2[nt][p] = *(const longx2*)&sB[row * 128 + (((p * 4 + g) ^ (row & 7)) * 16)];
            }
        }
#pragma unroll
        for (int ks = 0; ks < 4; ++ks)
#pragma unroll
            for (int mt = 0; mt < 2; ++mt)
#pragma unroll
                for (int nt = 0; nt < 2; ++nt)
                    acc[mt][nt] = __builtin_amdgcn_mfma_f32_16x16x32_fp8_fp8(
                        a2[mt][ks >> 1][ks & 1], b2[nt][ks >> 1][ks & 1], acc[mt][nt], 0, 0, 0);
        __syncthreads();   // waits prefetch + frees buf for next stage
    }
    // epilogue: out = residual + acc * 2^-13 (nontemporal fp32 stream)
#pragma unroll
    for (int mt = 0; mt < 2; ++mt)
#pragma unroll
        for (int r = 0; r < 4; ++r) {
            const int c = cw + mt * 16 + g * 4 + r;
            const size_t rowoff = ((size_t)(b * C_ + c)) * N_ + jb;
#pragma unroll
            for (int nt = 0; nt < 2; ++nt) {
                const int j = nt * 16 + c16;
                float rv = __builtin_nontemporal_load(&R[rowoff + j]);
                __builtin_nontemporal_store(rv + acc[mt][nt][r] * VSCALE_INV,
                                            &out[rowoff + j]);
            }
        }
}

// ---------------------------------------------------------------------------
// Fallback Pass B (unchanged; used when ws small).  Needs bf16 Kt/Qt/Vm and
// UNSHIFTED l (fallback stats uses sh=0 + atomics).
// ---------------------------------------------------------------------------
__global__ __launch_bounds__(512, 4)
void out_kernel(const ushort_t* __restrict__ Kt, const ushort_t* __restrict__ Qt,
                const ushort_t* __restrict__ V, const float* __restrict__ l,
                float* __restrict__ dout) {
    __shared__ ushort_t sQ[64][264];
    __shared__ ushort_t sP[64][264];
    const int tid = threadIdx.x;
    const int w = tid >> 6, lane = tid & 63, g = lane >> 4, c16 = lane & 15;
    const int b = blockIdx.z;
    const int jb = blockIdx.x * 64;
    const int ibase = blockIdx.y * 2048;
    {
        const int jl = tid >> 3, cp = (tid & 7) * 32;
        const ushort_t* src = Qt + ((size_t)(b * N_ + jb + jl)) * C_ + cp;
        uint4 a0 = *(const uint4*)(src);
        uint4 a1 = *(const uint4*)(src + 8);
        uint4 a2 = *(const uint4*)(src + 16);
        uint4 a3 = *(const uint4*)(src + 24);
        *(uint4*)&sQ[jl][cp + 0]  = a0;
        *(uint4*)&sQ[jl][cp + 8]  = a1;
        *(uint4*)&sQ[jl][cp + 16] = a2;
        *(uint4*)&sQ[jl][cp + 24] = a3;
    }
    f32x4 acc[2][4];
#pragma unroll
    for (int mt = 0; mt < 2; ++mt)
#pragma unroll
        for (int nt = 0; nt < 4; ++nt) acc[mt][nt] = (f32x4){0.f, 0.f, 0.f, 0.f};

    const int bw = w * 32;

    for (int ic = 0; ic < 8; ++ic) {
        const int i0 = ibase + ic * 256;
        float rv[2][4];
#pragma unroll
        for (int mt = 0; mt < 2; ++mt) {
            float4 lr = *(const float4*)(l + (size_t)b * N_ + i0 + bw + mt * 16 + g * 4);
            rv[mt][0] = __builtin_amdgcn_logf(lr.x);
            rv[mt][1] = __builtin_amdgcn_logf(lr.y);
            rv[mt][2] = __builtin_amdgcn_logf(lr.z);
            rv[mt][3] = __builtin_amdgcn_logf(lr.w);
        }
        __syncthreads();
        f32x4 sa[2][4];
#pragma unroll
        for (int mt = 0; mt < 2; ++mt)
#pragma unroll
            for (int nt = 0; nt < 4; ++nt) sa[mt][nt] = (f32x4){0.f, 0.f, 0.f, 0.f};
#pragma unroll
        for (int k = 0; k < 8; ++k) {
            bf16x8 av[2];
#pragma unroll
            for (int mt = 0; mt < 2; ++mt)
                av[mt] = ld_bf8(Kt + ((size_t)(b * N_ + i0 + bw + mt * 16 + c16)) * C_ + k * 32 + g * 8);
#pragma unroll
            for (int nt = 0; nt < 4; ++nt) {
                bf16x8 bv = *(const bf16x8*)&sQ[nt * 16 + c16][k * 32 + g * 8];
#pragma unroll
                for (int mt = 0; mt < 2; ++mt)
                    sa[mt][nt] = __builtin_amdgcn_mfma_f32_16x16x32_bf16(av[mt], bv, sa[mt][nt], 0, 0, 0);
            }
        }
#pragma unroll
        for (int mt = 0; mt < 2; ++mt)
#pragma unroll
            for (int nt = 0; nt < 4; ++nt) {
                const int j = nt * 16 + c16;
                unsigned p0 = f2bf(__builtin_amdgcn_exp2f(sa[mt][nt][0] - rv[mt][0]));
                unsigned p1 = f2bf(__builtin_amdgcn_exp2f(sa[mt][nt][1] - rv[mt][1]));
                unsigned p2 = f2bf(__builtin_amdgcn_exp2f(sa[mt][nt][2] - rv[mt][2]));
                unsigned p3 = f2bf(__builtin_amdgcn_exp2f(sa[mt][nt][3] - rv[mt][3]));
                uint2 pk; pk.x = p0 | (p1 << 16); pk.y = p2 | (p3 << 16);
                *(uint2*)&sP[j][bw + mt * 16 + g * 4] = pk;
            }
        __syncthreads();
#pragma unroll
        for (int ks = 0; ks < 8; ++ks) {
            bf16x8 va[2];
#pragma unroll
            for (int mt = 0; mt < 2; ++mt)
                va[mt] = ld_bf8(V + ((size_t)(b * C_ + bw + mt * 16 + c16)) * N_ + i0 + ks * 32 + g * 8);
#pragma unroll
            for (int nt = 0; nt < 4; ++nt) {
                bf16x8 pb = *(const bf16x8*)&sP[nt * 16 + c16][ks * 32 + g * 8];
#pragma unroll
                for (int mt = 0; mt < 2; ++mt)
                    acc[mt][nt] = __builtin_amdgcn_mfma_f32_16x16x32_bf16(va[mt], pb, acc[mt][nt], 0, 0, 0);
            }
        }
    }
#pragma unroll
    for (int mt = 0; mt < 2; ++mt)
#pragma unroll
        for (int nt = 0; nt < 4; ++nt)
#pragma unroll
            for (int r = 0; r < 4; ++r) {
                const int c = bw + mt * 16 + g * 4 + r;
                const int j = jb + nt * 16 + c16;
                atomicAdd(dout + ((size_t)b * C_ + c) * N_ + j, acc[mt][nt][r]);
            }
}

extern "C" void kernel_launch(void* const* d_in, const int* in_sizes, int n_in,
                              void* d_out, int out_size, void* d_ws, size_t ws_size,
                              hipStream_t stream) {
    const float* x_s2  = (const float*)d_in[0];
    const float* x_dem = (const float*)d_in[1];
    const float* Wq = (const float*)d_in[2];
    const float* bq = (const float*)d_in[3];
    const float* Wk = (const float*)d_in[4];
    const float* bk = (const float*)d_in[5];
    const float* Wv = (const float*)d_in[6];
    const float* bv = (const float*)d_in[7];
    float* out = (float*)d_out;

    const size_t MiB = 1024 * 1024;
    char* ws = (char*)d_ws;
    ushort_t* Qt = (ushort_t*)(ws);               // [B][N][C] bf16 (fallback) /
    uchar_t*  Qt8 = (uchar_t*)(ws);               //   fp8 Q' perm8 (bigws)
    ushort_t* Kt = (ushort_t*)(ws + 8  * MiB);    // [B][N][C] bf16 (fallback) /
    uchar_t*  Kt8 = (uchar_t*)(ws + 8 * MiB);     //   fp8 K' perm8 (bigws)
    ushort_t* Vm = (ushort_t*)(ws + 16 * MiB);    // [B][C][N] bf16, 8 MiB
    uchar_t*  Vs = (uchar_t*) (ws + 24 * MiB);    // [B][C][N] fp8 V'' perm16
    float*    lp = (float*)   (ws + 24 * MiB);    // [B][32][N] partials, 2 MiB
                                                  //   (aliases Vs: dead before
                                                  //    scale_v writes Vs)
    float*    lv = (float*)   (ws + 28 * MiB);    // [B][N] row sums, 64 KiB
    uchar_t*  PT = (uchar_t*) (ws + 29 * MiB);    // [B][N(j)][N(i)] fp8 perm16
    const bool bigws = ws_size >= 93 * MiB;

    if (!bigws) {
        hipMemsetAsync(lv, 0, (size_t)B_ * N_ * sizeof(float), stream);
        hipMemcpyAsync(out, x_s2, (size_t)B_ * C_ * N_ * sizeof(float),
                       hipMemcpyDeviceToDevice, stream);
    }

    proj_q_mfma<<<dim3(N_ / 128, C_ / 64, B_), 256, 0, stream>>>(
        x_s2, Wq, bq, Qt, bigws ? Qt8 : (uchar_t*)nullptr, C_);
    proj_kv_mfma<<<dim3(N_ / 128, C_ / 64, B_), 256, 0, stream>>>(
        x_dem, Wk, bk, Wv, bv, Kt, bigws ? Kt8 : (uchar_t*)nullptr, Vm);
    if (bigws) {
        stats_fp8_kernel<<<dim3(N_ / 128, N_ / 128, B_), 256, 0, stream>>>(Kt8, Qt8, PT, lp);
        reduce_l_kernel<<<dim3(N_ / 1024, B_), 256, 0, stream>>>(lp, lv);
        scale_v_kernel<<<dim3(N_ / 2048, C_, B_), 256, 0, stream>>>(Vm, lv, Vs);
        gemm_out2_kernel<<<dim3(N_ / 32, B_), 512, 0, stream>>>(Vs, PT, x_s2, out);
    } else {
        stats_kernel<<<dim3(N_ / 128, N_ / 128, B_), 256, 0, stream>>>(Kt, Qt, lv);
        out_kernel<<<dim3(N_ / 64, 2, B_), 512, 0, stream>>>(Kt, Qt, Vm, lv, out);
    }
}